// Round 8
// baseline (392.864 us; speedup 1.0000x reference)
//
#include <hip/hip_runtime.h>
#include <hip/hip_bf16.h>

#define N_TOT   150000
#define N_USER  100000
#define E_TOT   1000000
#define B_TOT   4096
#define D_DIM   64

#define NSCAN_PAD   150016          // N_TOT+1 rounded up to multiple of 8
#define BKT_SHIFT   10
#define BKT_ROWS    (1 << BKT_SHIFT)                 // 1024 rows per bucket
#define NBKT        ((N_TOT + BKT_ROWS - 1) / BKT_ROWS)   // 147
#define BKT_CAP     8192
#define BIN_CHUNK   4096
#define NBIN_BLOCKS ((E_TOT + BIN_CHUNK - 1) / BIN_CHUNK) // 245

// ---- bf16 helpers (bit ops; accumulation always f32) ----
__device__ __forceinline__ float b2f(unsigned int lo16)
{
    union { unsigned int u; float f; } c; c.u = lo16 << 16; return c.f;
}
__device__ __forceinline__ unsigned short f2b(float f)
{
    union { float f; unsigned int u; } c; c.f = f;
    unsigned int u = c.u + 0x7FFFu + ((c.u >> 16) & 1u);   // RNE
    return (unsigned short)(u >> 16);
}

// ---------------------------------------------------------------------------
// features f32 -> bf16 (one pass, vectorized)
// ---------------------------------------------------------------------------
__global__ void tobf16_kernel(const float4* __restrict__ in, ushort4* __restrict__ out, int n4)
{
    for (int i = blockIdx.x * blockDim.x + threadIdx.x; i < n4; i += gridDim.x * blockDim.x) {
        float4 v = in[i];
        ushort4 o;
        o.x = f2b(v.x); o.y = f2b(v.y); o.z = f2b(v.z); o.w = f2b(v.w);
        out[i] = o;
    }
}

// ---------------------------------------------------------------------------
// Per-node attention scalars, thread-per-node, bf16 x-row input:
//   a_nb[v]   = relu(x[v]@Wn+bn) . Wa[0:64]
//   a_self[v] = relu(x[v]@Ws+bs) . Wa[64:128]
// h[64] in VGPRs; weight rows via wave-uniform pointer (SMEM path).
// ---------------------------------------------------------------------------
__global__ __launch_bounds__(256, 4)
void node_scalars_kernel(const unsigned short* __restrict__ xb,
                         const float* __restrict__ Wn, const float* __restrict__ bn,
                         const float* __restrict__ Ws, const float* __restrict__ bs,
                         const float* __restrict__ Wa,
                         float* __restrict__ a_nb, float* __restrict__ a_self,
                         int nNodes)
{
    const int v = blockIdx.x * 256 + threadIdx.x;
    if (v >= nNodes) return;

    const uint4* __restrict__ xv4 = (const uint4*)(xb + (size_t)v * 64);

    float h[64];

    // ---- pass 1: h = x @ Wn + bn ----
    #pragma unroll
    for (int d = 0; d < 64; ++d) h[d] = bn[d];
    for (int kk = 0; kk < 8; ++kk) {               // 8 dims per iter
        uint4 q = xv4[kk];
        float x0 = b2f(q.x & 0xFFFF), x1 = b2f(q.x >> 16);
        float x2 = b2f(q.y & 0xFFFF), x3 = b2f(q.y >> 16);
        float x4 = b2f(q.z & 0xFFFF), x5 = b2f(q.z >> 16);
        float x6 = b2f(q.w & 0xFFFF), x7 = b2f(q.w >> 16);
        const float* __restrict__ wrow = Wn + (size_t)kk * 512;   // 8 rows x 64
        #pragma unroll
        for (int d = 0; d < 64; ++d) {
            float acc = h[d];
            acc = fmaf(x0, wrow[d],        acc);
            acc = fmaf(x1, wrow[64  + d],  acc);
            acc = fmaf(x2, wrow[128 + d],  acc);
            acc = fmaf(x3, wrow[192 + d],  acc);
            acc = fmaf(x4, wrow[256 + d],  acc);
            acc = fmaf(x5, wrow[320 + d],  acc);
            acc = fmaf(x6, wrow[384 + d],  acc);
            acc = fmaf(x7, wrow[448 + d],  acc);
            h[d] = acc;
        }
    }
    float an = 0.0f;
    #pragma unroll
    for (int d = 0; d < 64; ++d) an = fmaf(fmaxf(h[d], 0.0f), Wa[d], an);

    // ---- pass 2: h = x @ Ws + bs ----
    #pragma unroll
    for (int d = 0; d < 64; ++d) h[d] = bs[d];
    for (int kk = 0; kk < 8; ++kk) {
        uint4 q = xv4[kk];
        float x0 = b2f(q.x & 0xFFFF), x1 = b2f(q.x >> 16);
        float x2 = b2f(q.y & 0xFFFF), x3 = b2f(q.y >> 16);
        float x4 = b2f(q.z & 0xFFFF), x5 = b2f(q.z >> 16);
        float x6 = b2f(q.w & 0xFFFF), x7 = b2f(q.w >> 16);
        const float* __restrict__ wrow = Ws + (size_t)kk * 512;
        #pragma unroll
        for (int d = 0; d < 64; ++d) {
            float acc = h[d];
            acc = fmaf(x0, wrow[d],        acc);
            acc = fmaf(x1, wrow[64  + d],  acc);
            acc = fmaf(x2, wrow[128 + d],  acc);
            acc = fmaf(x3, wrow[192 + d],  acc);
            acc = fmaf(x4, wrow[256 + d],  acc);
            acc = fmaf(x5, wrow[320 + d],  acc);
            acc = fmaf(x6, wrow[384 + d],  acc);
            acc = fmaf(x7, wrow[448 + d],  acc);
            h[d] = acc;
        }
    }
    float as = 0.0f;
    #pragma unroll
    for (int d = 0; d < 64; ++d) as = fmaf(fmaxf(h[d], 0.0f), Wa[64 + d], as);

    a_nb[v]   = an;
    a_self[v] = as;
}

// ---------------------------------------------------------------------------
// Phase 1: bin edges into NBKT coarse buckets (1024 rows each).
// ---------------------------------------------------------------------------
__global__ __launch_bounds__(256)
void bin_kernel(const int* __restrict__ row, int* __restrict__ bcnt,
                int2* __restrict__ tmp, int nE)
{
    __shared__ int cnt[NBKT];
    __shared__ int base[NBKT];
    for (int i = threadIdx.x; i < NBKT; i += 256) cnt[i] = 0;
    __syncthreads();

    const int e0 = blockIdx.x * BIN_CHUNK + threadIdx.x;
    int r[16];
    #pragma unroll
    for (int k = 0; k < 16; ++k) {
        int e = e0 + k * 256;
        r[k] = (e < nE) ? row[e] : -1;
        if (r[k] >= 0) atomicAdd(&cnt[r[k] >> BKT_SHIFT], 1);
    }
    __syncthreads();

    for (int i = threadIdx.x; i < NBKT; i += 256) {
        int c = cnt[i];
        base[i] = c ? atomicAdd(&bcnt[i], c) : 0;
        cnt[i] = 0;
    }
    __syncthreads();

    #pragma unroll
    for (int k = 0; k < 16; ++k) {
        if (r[k] >= 0) {
            int b   = r[k] >> BKT_SHIFT;
            int loc = atomicAdd(&cnt[b], 1);
            tmp[(size_t)b * BKT_CAP + base[b] + loc] = make_int2(r[k], e0 + k * 256);
        }
    }
}

__global__ void bucket_scan_kernel(const int* __restrict__ bcnt, int* __restrict__ bbase,
                                   int* __restrict__ start)
{
    __shared__ int sh[256];
    int t = threadIdx.x;
    int v = (t < NBKT) ? bcnt[t] : 0;
    sh[t] = v;
    __syncthreads();
    for (int off = 1; off < 256; off <<= 1) {
        int x = sh[t];
        if (t >= off) x += sh[t - off];
        __syncthreads();
        sh[t] = x;
        __syncthreads();
    }
    if (t <= NBKT) bbase[t] = (t == 0) ? 0 : sh[t - 1];
    if (t == 0) start[N_TOT] = E_TOT;
}

// ---------------------------------------------------------------------------
// Phase 2: one block per bucket; LDS counting-sort -> start[] + CSR ei.
// ---------------------------------------------------------------------------
__global__ __launch_bounds__(256)
void scatter2_kernel(const int2* __restrict__ tmp, const int* __restrict__ bcnt,
                     const int* __restrict__ bbase, const int* __restrict__ col,
                     int* __restrict__ start, int2* __restrict__ ei)
{
    __shared__ int pref[BKT_ROWS];
    __shared__ int wsum[256];

    const int b     = blockIdx.x;
    const int rlo   = b << BKT_SHIFT;
    const int nrows = min(BKT_ROWS, N_TOT - rlo);
    const int cntb  = bcnt[b];
    const int baseb = bbase[b];
    const int t     = threadIdx.x;
    const int2* __restrict__ bkt = tmp + (size_t)b * BKT_CAP;

    for (int i = t; i < BKT_ROWS; i += 256) pref[i] = 0;
    __syncthreads();

    for (int j = t; j < cntb; j += 256)
        atomicAdd(&pref[bkt[j].x - rlo], 1);
    __syncthreads();

    const int base4 = t * 4;
    int v0 = pref[base4], v1 = pref[base4 + 1], v2 = pref[base4 + 2], v3 = pref[base4 + 3];
    int s = v0 + v1 + v2 + v3;
    wsum[t] = s;
    __syncthreads();
    for (int off = 1; off < 256; off <<= 1) {
        int x = wsum[t];
        if (t >= off) x += wsum[t - off];
        __syncthreads();
        wsum[t] = x;
        __syncthreads();
    }
    const int pre = wsum[t] - s;
    const int p0 = pre, p1 = pre + v0, p2 = pre + v0 + v1, p3 = pre + v0 + v1 + v2;

    if (base4     < nrows) start[rlo + base4]     = baseb + p0;
    if (base4 + 1 < nrows) start[rlo + base4 + 1] = baseb + p1;
    if (base4 + 2 < nrows) start[rlo + base4 + 2] = baseb + p2;
    if (base4 + 3 < nrows) start[rlo + base4 + 3] = baseb + p3;

    pref[base4] = p0; pref[base4 + 1] = p1; pref[base4 + 2] = p2; pref[base4 + 3] = p3;
    __syncthreads();

    for (int j = t; j < cntb; j += 256) {
        int2 p  = bkt[j];
        int loc = atomicAdd(&pref[p.x - rlo], 1);
        ei[baseb + loc] = make_int2(col[p.y], p.y);
    }
}

// ---------------------------------------------------------------------------
// Edge pass A, node-parallel: sequential msorted write, register rowsum,
// fused d_inv_sqrt.
// ---------------------------------------------------------------------------
__global__ __launch_bounds__(256)
void edge_pass_a_kernel(const int2* __restrict__ ei, const int* __restrict__ start,
                        const float* __restrict__ u,
                        const float* __restrict__ a_nb, const float* __restrict__ a_self,
                        const float* __restrict__ ba_p, const float* __restrict__ temp_p,
                        float* __restrict__ msorted, float* __restrict__ dis,
                        float* __restrict__ l0_accum, int nNodes)
{
    const float ba   = ba_p[0];
    const float t    = temp_p[0];
    const float invt = 1.0f / t;
    const float lt   = logf(0.45f / 1.05f);   // log(-GAMMA/ZETA)
    const float shift = t * lt;

    const int r = blockIdx.x * 256 + threadIdx.x;
    float l0local = 0.0f;

    if (r < nNodes) {
        const int js = start[r], je = start[r + 1];
        const float la_base = a_nb[r] + ba;
        float rs = 0.0f;
        for (int j = js; j < je; ++j) {
            int2 p = ei[j];                       // {col, e}
            float la = la_base + a_self[p.x];
            float uu = u[p.y];
            float noise = logf(uu) - log1pf(-uu);
            float gate  = 1.0f / (1.0f + expf(-(noise + la) * invt));
            float m = fminf(fmaxf(gate * 1.5f - 0.45f, 0.0f), 1.0f);
            msorted[j] = m;
            rs += m;
            l0local += 1.0f / (1.0f + expf(-(la - shift)));
        }
        dis[r] = fminf(1.0f / sqrtf(rs + 1e-6f), 10.0f);
    }

    __shared__ float red[256];
    red[threadIdx.x] = l0local;
    __syncthreads();
    for (int s = 128; s > 0; s >>= 1) {
        if (threadIdx.x < s) red[threadIdx.x] += red[threadIdx.x + s];
        __syncthreads();
    }
    if (threadIdx.x == 0) unsafeAtomicAdd(l0_accum, red[0]);
}

// ---------------------------------------------------------------------------
// Edge gather (bf16 src/dst, f32 accumulate):
//   xnb[r] = bf16( dis[r] * sum_j msorted[j]*dis[c_j]*x[c_j] )
// ---------------------------------------------------------------------------
__global__ void edge_gather_kernel(const float* __restrict__ ms, const int2* __restrict__ ei,
                                   const int* __restrict__ start,
                                   const float* __restrict__ dis,
                                   const unsigned short* __restrict__ xb,
                                   unsigned short* __restrict__ xnb, int nNodes)
{
    const int lane   = threadIdx.x & 63;
    const int wave   = (blockIdx.x * blockDim.x + threadIdx.x) >> 6;
    const int nWaves = (gridDim.x * blockDim.x) >> 6;

    for (int r = wave; r < nNodes; r += nWaves) {
        const int ru = __builtin_amdgcn_readfirstlane(r);
        int js = __builtin_amdgcn_readfirstlane(start[ru]);
        int je = __builtin_amdgcn_readfirstlane(start[ru + 1]);
        float acc = 0.0f;
        int j = js;
        for (; j + 4 <= je; j += 4) {
            float m0 = ms[j],   m1 = ms[j+1], m2 = ms[j+2], m3 = ms[j+3];
            int   c0 = ei[j].x, c1 = ei[j+1].x, c2 = ei[j+2].x, c3 = ei[j+3].x;
            if (m0 > 0.0f) acc = fmaf(m0 * dis[c0], b2f(xb[(size_t)c0 * 64 + lane]), acc);
            if (m1 > 0.0f) acc = fmaf(m1 * dis[c1], b2f(xb[(size_t)c1 * 64 + lane]), acc);
            if (m2 > 0.0f) acc = fmaf(m2 * dis[c2], b2f(xb[(size_t)c2 * 64 + lane]), acc);
            if (m3 > 0.0f) acc = fmaf(m3 * dis[c3], b2f(xb[(size_t)c3 * 64 + lane]), acc);
        }
        for (; j < je; ++j) {
            float m = ms[j];
            if (m > 0.0f) {
                int c = ei[j].x;
                acc = fmaf(m * dis[c], b2f(xb[(size_t)c * 64 + lane]), acc);
            }
        }
        xnb[(size_t)ru * 64 + lane] = f2b(acc * dis[ru]);
    }
}

// ---------------------------------------------------------------------------
// BPR loss: xs = features(f32) + x1(bf16) + x2(bf16)
// ---------------------------------------------------------------------------
__global__ void bpr_kernel(const float* __restrict__ f,
                           const unsigned short* __restrict__ x1b,
                           const unsigned short* __restrict__ x2b,
                           const int* __restrict__ users, const int* __restrict__ items,
                           const int* __restrict__ negs,
                           float* __restrict__ bpr_accum, int B)
{
    const int lane   = threadIdx.x & 63;
    const int wave   = (blockIdx.x * blockDim.x + threadIdx.x) >> 6;
    const int nWaves = (gridDim.x * blockDim.x) >> 6;

    float local = 0.0f;
    for (int b = wave; b < B; b += nWaves) {
        size_t ui = (size_t)users[b] * 64 + lane;
        size_t pi = (size_t)(N_USER + items[b]) * 64 + lane;
        size_t ni = (size_t)(N_USER + negs[b]) * 64 + lane;
        float a = f[ui] + b2f(x1b[ui]) + b2f(x2b[ui]);
        float p = f[pi] + b2f(x1b[pi]) + b2f(x2b[pi]);
        float n = f[ni] + b2f(x1b[ni]) + b2f(x2b[ni]);
        float ps = a * p, ns = a * n;
        #pragma unroll
        for (int off = 32; off; off >>= 1) {
            ps += __shfl_xor(ps, off);
            ns += __shfl_xor(ns, off);
        }
        if (lane == 0) {
            float s = 1.0f / (1.0f + expf(-(ps - ns)));
            local += -logf(s + 1e-5f);
        }
    }
    if (lane == 0) unsafeAtomicAdd(bpr_accum, local);
}

// ---------------------------------------------------------------------------
// L2 regularization on params
// ---------------------------------------------------------------------------
__global__ void reg_kernel(const float* __restrict__ w0, const float* __restrict__ b0,
                           const float* __restrict__ w1, const float* __restrict__ b1,
                           const float* __restrict__ wa0, const float* __restrict__ ba0,
                           const float* __restrict__ w2, const float* __restrict__ b2,
                           const float* __restrict__ w3, const float* __restrict__ b3,
                           const float* __restrict__ wa1, const float* __restrict__ ba1,
                           float* __restrict__ accum)
{
    int t = threadIdx.x;
    float s = 0.0f;
    for (int i = t; i < 4096; i += 256)
        s += w0[i]*w0[i] + w1[i]*w1[i] + w2[i]*w2[i] + w3[i]*w3[i];
    for (int i = t; i < 64; i += 256)
        s += b0[i]*b0[i] + b1[i]*b1[i] + b2[i]*b2[i] + b3[i]*b3[i];
    for (int i = t; i < 128; i += 256)
        s += wa0[i]*wa0[i] + wa1[i]*wa1[i];
    if (t == 0) s += ba0[0]*ba0[0] + ba1[0]*ba1[0];

    __shared__ float red[256];
    red[t] = s;
    __syncthreads();
    for (int st = 128; st > 0; st >>= 1) {
        if (t < st) red[t] += red[t + st];
        __syncthreads();
    }
    if (t == 0) accum[0] = red[0];
}

__global__ void finalize_kernel(const float* __restrict__ scal, float* __restrict__ out)
{
    float bpr = scal[0] / (float)B_TOT;
    float reg = scal[1] * 1e-4f;
    float l0  = (scal[2] + scal[3]) * (1e-4f / (float)E_TOT);
    out[0] = bpr + reg + l0;
}

extern "C" void kernel_launch(void* const* d_in, const int* in_sizes, int n_in,
                              void* d_out, int out_size, void* d_ws, size_t ws_size,
                              hipStream_t stream)
{
    const float* features = (const float*)d_in[0];
    const int*   row      = (const int*)d_in[1];
    const int*   col      = (const int*)d_in[2];
    const int*   users    = (const int*)d_in[3];
    const int*   items    = (const int*)d_in[4];
    const int*   negs     = (const int*)d_in[5];
    const float* u0       = (const float*)d_in[6];
    const float* u1       = (const float*)d_in[7];
    const float* temp     = (const float*)d_in[8];
    const float* W_nb0    = (const float*)d_in[9];
    const float* b_nb0    = (const float*)d_in[10];
    const float* W_self0  = (const float*)d_in[11];
    const float* b_self0  = (const float*)d_in[12];
    const float* W_att0   = (const float*)d_in[13];
    const float* b_att0   = (const float*)d_in[14];
    const float* W_nb1    = (const float*)d_in[15];
    const float* b_nb1    = (const float*)d_in[16];
    const float* W_self1  = (const float*)d_in[17];
    const float* b_self1  = (const float*)d_in[18];
    const float* W_att1   = (const float*)d_in[19];
    const float* b_att1   = (const float*)d_in[20];
    float* out = (float*)d_out;

    // ---- Workspace layout (4B element offsets), ~82 MB total ----
    float* ws = (float*)d_ws;
    unsigned short* fb  = (unsigned short*)ws;               // N*64 bf16 (4.8M floats)
    unsigned short* x1b = (unsigned short*)(ws + 4800000);   // N*64 bf16
    unsigned short* x2b = (unsigned short*)(ws + 9600000);   // N*64 bf16
    // zeroed block: scal + bcnt
    float* scal  = ws + 14400000;                 // 16
    int*   bcnt  = (int*)(scal + 16);             // NBKT (pad 160)
    // end zeroed block
    int*   bbase = bcnt + 160;                    // NBKT+1 (pad 160)
    int*   start = bbase + 160;                   // NSCAN_PAD
    int2*  tmp   = (int2*)(start + NSCAN_PAD);    // NBKT*BKT_CAP int2 (9.6MB)
    int2*  ei    = tmp + (size_t)NBKT * BKT_CAP;  // E int2
    float* msorted = (float*)(ei + E_TOT);        // E
    float* dis     = msorted + E_TOT;             // N_TOT
    float* a_nb    = dis + N_TOT;                 // N_TOT
    float* a_self  = a_nb + N_TOT;                // N_TOT

    hipMemsetAsync(scal, 0, (16 + 160) * sizeof(float), stream);

    const int nNodeBlocks = (N_TOT + 255) / 256;   // 586

    // ---- features -> bf16 ----
    tobf16_kernel<<<1024, 256, 0, stream>>>((const float4*)features, (ushort4*)fb, N_TOT * 16);

    // ---- CSR build: bin -> bucket scan -> per-bucket counting-sort ----
    bin_kernel<<<NBIN_BLOCKS, 256, 0, stream>>>(row, bcnt, tmp, E_TOT);
    bucket_scan_kernel<<<1, 256, 0, stream>>>(bcnt, bbase, start);
    scatter2_kernel<<<NBKT, 256, 0, stream>>>(tmp, bcnt, bbase, col, start, ei);

    // ---- Layer 0 ----
    node_scalars_kernel<<<nNodeBlocks, 256, 0, stream>>>(fb, W_nb0, b_nb0, W_self0, b_self0,
                                                         W_att0, a_nb, a_self, N_TOT);
    edge_pass_a_kernel<<<nNodeBlocks, 256, 0, stream>>>(ei, start, u0, a_nb, a_self, b_att0, temp,
                                                        msorted, dis, &scal[2], N_TOT);
    edge_gather_kernel<<<2048, 256, 0, stream>>>(msorted, ei, start, dis, fb, x1b, N_TOT);

    // ---- Layer 1 ----
    node_scalars_kernel<<<nNodeBlocks, 256, 0, stream>>>(x1b, W_nb1, b_nb1, W_self1, b_self1,
                                                         W_att1, a_nb, a_self, N_TOT);
    edge_pass_a_kernel<<<nNodeBlocks, 256, 0, stream>>>(ei, start, u1, a_nb, a_self, b_att1, temp,
                                                        msorted, dis, &scal[3], N_TOT);
    edge_gather_kernel<<<2048, 256, 0, stream>>>(msorted, ei, start, dis, x1b, x2b, N_TOT);

    // ---- Losses ----
    bpr_kernel<<<64, 256, 0, stream>>>(features, x1b, x2b, users, items, negs, &scal[0], B_TOT);
    reg_kernel<<<1, 256, 0, stream>>>(W_nb0, b_nb0, W_self0, b_self0, W_att0, b_att0,
                                      W_nb1, b_nb1, W_self1, b_self1, W_att1, b_att1, &scal[1]);
    finalize_kernel<<<1, 1, 0, stream>>>(scal, out);
}

// Round 9
// 310.165 us; speedup vs baseline: 1.2666x; 1.2666x over previous
//
#include <hip/hip_runtime.h>
#include <hip/hip_bf16.h>

#define N_TOT   150000
#define N_USER  100000
#define E_TOT   1000000
#define B_TOT   4096
#define D_DIM   64

#define NSCAN_PAD   150016          // N_TOT+1 rounded up to multiple of 8
#define BKT_SHIFT   10
#define BKT_ROWS    (1 << BKT_SHIFT)                 // 1024 rows per bucket
#define NBKT        ((N_TOT + BKT_ROWS - 1) / BKT_ROWS)   // 147
#define BKT_CAP     8192
#define BIN_CHUNK   4096
#define NBIN_BLOCKS ((E_TOT + BIN_CHUNK - 1) / BIN_CHUNK) // 245

typedef short short8v  __attribute__((ext_vector_type(8)));
typedef float float4v  __attribute__((ext_vector_type(4)));

// ---- bf16 helpers (bit ops; accumulation always f32) ----
__device__ __forceinline__ float b2f(unsigned int lo16)
{
    union { unsigned int u; float f; } c; c.u = lo16 << 16; return c.f;
}
__device__ __forceinline__ unsigned short f2b(float f)
{
    union { float f; unsigned int u; } c; c.f = f;
    unsigned int u = c.u + 0x7FFFu + ((c.u >> 16) & 1u);   // RNE
    return (unsigned short)(u >> 16);
}

// ---------------------------------------------------------------------------
// features f32 -> bf16 (one pass, vectorized)
// ---------------------------------------------------------------------------
__global__ void tobf16_kernel(const float4* __restrict__ in, ushort4* __restrict__ out, int n4)
{
    for (int i = blockIdx.x * blockDim.x + threadIdx.x; i < n4; i += gridDim.x * blockDim.x) {
        float4 v = in[i];
        ushort4 o;
        o.x = f2b(v.x); o.y = f2b(v.y); o.z = f2b(v.z); o.w = f2b(v.w);
        out[i] = o;
    }
}

// ---------------------------------------------------------------------------
// Pack the 4 weight matrices into MFMA B-fragment order, bf16:
// wpk[m][kb][nt][lane][j] = W_m[32*kb + (lane>>4)*8 + j][16*nt + (lane&15)]
// (m: 0=Wn0 1=Ws0 2=Wn1 3=Ws1; 2048 lane-frags x 8 elems = 32KB)
// ---------------------------------------------------------------------------
__global__ void wpack_kernel(const float* __restrict__ Wn0, const float* __restrict__ Ws0,
                             const float* __restrict__ Wn1, const float* __restrict__ Ws1,
                             unsigned short* __restrict__ wpk)
{
    int f = blockIdx.x * blockDim.x + threadIdx.x;   // [0, 2048)
    if (f >= 2048) return;
    const float* W[4] = {Wn0, Ws0, Wn1, Ws1};
    int m   = f >> 9;
    int rem = f & 511;
    int kb  = rem >> 8;
    int nt  = (rem >> 6) & 3;
    int l   = rem & 63;
    const float* Wm = W[m];
    int kbase = 32 * kb + ((l >> 4) << 3);
    int n     = 16 * nt + (l & 15);
    unsigned short o[8];
    #pragma unroll
    for (int j = 0; j < 8; ++j) o[j] = f2b(Wm[(kbase + j) * 64 + n]);
    ushort4* dst = (ushort4*)(wpk + (size_t)f * 8);
    dst[0] = make_ushort4(o[0], o[1], o[2], o[3]);
    dst[1] = make_ushort4(o[4], o[5], o[6], o[7]);
}

// ---------------------------------------------------------------------------
// Node scalars via MFMA: one wave per 16 nodes.
//   H = relu(X@W + b);  a = H . Wa_half
// A-frag: lane holds X[node16 + (lane&15)][32*kb + (lane>>4)*8 + j]
// C-frag: lane holds C[(lane>>4)*4 + r][lane&15]   [m89-verified layout]
// ---------------------------------------------------------------------------
__global__ __launch_bounds__(256)
void node_scalars_mfma_kernel(const unsigned short* __restrict__ xb,
                              const unsigned short* __restrict__ wpack, // this layer: [2][2][4][64][8]
                              const float* __restrict__ bn, const float* __restrict__ bs,
                              const float* __restrict__ Wa,
                              float* __restrict__ a_nb, float* __restrict__ a_self,
                              int nNodes)
{
    const int lane = threadIdx.x & 63;
    const int wid  = (blockIdx.x * blockDim.x + threadIdx.x) >> 6;
    const int nodeBase = wid * 16;
    if (nodeBase >= nNodes) return;

    // B fragments (shared by all waves -> L1/L2 hot)
    short8v bfrag[2][2][4];
    #pragma unroll
    for (int m = 0; m < 2; ++m)
        #pragma unroll
        for (int kb = 0; kb < 2; ++kb)
            #pragma unroll
            for (int nt = 0; nt < 4; ++nt)
                bfrag[m][kb][nt] =
                    *(const short8v*)(wpack + (size_t)((((m * 2 + kb) * 4 + nt) * 64 + lane)) * 8);

    // A fragments (coalesced: wave reads a contiguous 16x128B block)
    const size_t rowOff = (size_t)(nodeBase + (lane & 15)) * 64 + ((lane >> 4) << 3);
    short8v a0 = *(const short8v*)(xb + rowOff);
    short8v a1 = *(const short8v*)(xb + rowOff + 32);

    float4v acc[2][4];
    #pragma unroll
    for (int m = 0; m < 2; ++m)
        #pragma unroll
        for (int nt = 0; nt < 4; ++nt) {
            float4v z = {0.f, 0.f, 0.f, 0.f};
            z = __builtin_amdgcn_mfma_f32_16x16x32_bf16(a0, bfrag[m][0][nt], z, 0, 0, 0);
            z = __builtin_amdgcn_mfma_f32_16x16x32_bf16(a1, bfrag[m][1][nt], z, 0, 0, 0);
            acc[m][nt] = z;
        }

    // epilogue: bias + relu + dot(Wa); lane's col j = lane&15, rows g*4+r
    const int j = lane & 15;
    float pn[4] = {0.f, 0.f, 0.f, 0.f};
    float ps[4] = {0.f, 0.f, 0.f, 0.f};
    #pragma unroll
    for (int nt = 0; nt < 4; ++nt) {
        float bnv = bn[nt * 16 + j], bsv = bs[nt * 16 + j];
        float wan = Wa[nt * 16 + j], was = Wa[64 + nt * 16 + j];
        #pragma unroll
        for (int r = 0; r < 4; ++r) {
            pn[r] = fmaf(fmaxf(acc[0][nt][r] + bnv, 0.f), wan, pn[r]);
            ps[r] = fmaf(fmaxf(acc[1][nt][r] + bsv, 0.f), was, ps[r]);
        }
    }
    // reduce across the 16 lanes of each group (lane>>4 fixed)
    #pragma unroll
    for (int off = 1; off < 16; off <<= 1) {
        #pragma unroll
        for (int r = 0; r < 4; ++r) {
            pn[r] += __shfl_xor(pn[r], off);
            ps[r] += __shfl_xor(ps[r], off);
        }
    }
    if (j == 0) {
        const int g = lane >> 4;
        #pragma unroll
        for (int r = 0; r < 4; ++r) {
            int node = nodeBase + g * 4 + r;
            a_nb[node]   = pn[r];
            a_self[node] = ps[r];
        }
    }
}

// ---------------------------------------------------------------------------
// Phase 1: bin edges into NBKT coarse buckets (1024 rows each).
// ---------------------------------------------------------------------------
__global__ __launch_bounds__(256)
void bin_kernel(const int* __restrict__ row, int* __restrict__ bcnt,
                int2* __restrict__ tmp, int nE)
{
    __shared__ int cnt[NBKT];
    __shared__ int base[NBKT];
    for (int i = threadIdx.x; i < NBKT; i += 256) cnt[i] = 0;
    __syncthreads();

    const int e0 = blockIdx.x * BIN_CHUNK + threadIdx.x;
    int r[16];
    #pragma unroll
    for (int k = 0; k < 16; ++k) {
        int e = e0 + k * 256;
        r[k] = (e < nE) ? row[e] : -1;
        if (r[k] >= 0) atomicAdd(&cnt[r[k] >> BKT_SHIFT], 1);
    }
    __syncthreads();

    for (int i = threadIdx.x; i < NBKT; i += 256) {
        int c = cnt[i];
        base[i] = c ? atomicAdd(&bcnt[i], c) : 0;
        cnt[i] = 0;
    }
    __syncthreads();

    #pragma unroll
    for (int k = 0; k < 16; ++k) {
        if (r[k] >= 0) {
            int b   = r[k] >> BKT_SHIFT;
            int loc = atomicAdd(&cnt[b], 1);
            tmp[(size_t)b * BKT_CAP + base[b] + loc] = make_int2(r[k], e0 + k * 256);
        }
    }
}

__global__ void bucket_scan_kernel(const int* __restrict__ bcnt, int* __restrict__ bbase,
                                   int* __restrict__ start)
{
    __shared__ int sh[256];
    int t = threadIdx.x;
    int v = (t < NBKT) ? bcnt[t] : 0;
    sh[t] = v;
    __syncthreads();
    for (int off = 1; off < 256; off <<= 1) {
        int x = sh[t];
        if (t >= off) x += sh[t - off];
        __syncthreads();
        sh[t] = x;
        __syncthreads();
    }
    if (t <= NBKT) bbase[t] = (t == 0) ? 0 : sh[t - 1];
    if (t == 0) start[N_TOT] = E_TOT;
}

// ---------------------------------------------------------------------------
// Phase 2: one block per bucket; LDS counting-sort -> start[] + CSR ei.
// ---------------------------------------------------------------------------
__global__ __launch_bounds__(256)
void scatter2_kernel(const int2* __restrict__ tmp, const int* __restrict__ bcnt,
                     const int* __restrict__ bbase, const int* __restrict__ col,
                     int* __restrict__ start, int2* __restrict__ ei)
{
    __shared__ int pref[BKT_ROWS];
    __shared__ int wsum[256];

    const int b     = blockIdx.x;
    const int rlo   = b << BKT_SHIFT;
    const int nrows = min(BKT_ROWS, N_TOT - rlo);
    const int cntb  = bcnt[b];
    const int baseb = bbase[b];
    const int t     = threadIdx.x;
    const int2* __restrict__ bkt = tmp + (size_t)b * BKT_CAP;

    for (int i = t; i < BKT_ROWS; i += 256) pref[i] = 0;
    __syncthreads();

    for (int j = t; j < cntb; j += 256)
        atomicAdd(&pref[bkt[j].x - rlo], 1);
    __syncthreads();

    const int base4 = t * 4;
    int v0 = pref[base4], v1 = pref[base4 + 1], v2 = pref[base4 + 2], v3 = pref[base4 + 3];
    int s = v0 + v1 + v2 + v3;
    wsum[t] = s;
    __syncthreads();
    for (int off = 1; off < 256; off <<= 1) {
        int x = wsum[t];
        if (t >= off) x += wsum[t - off];
        __syncthreads();
        wsum[t] = x;
        __syncthreads();
    }
    const int pre = wsum[t] - s;
    const int p0 = pre, p1 = pre + v0, p2 = pre + v0 + v1, p3 = pre + v0 + v1 + v2;

    if (base4     < nrows) start[rlo + base4]     = baseb + p0;
    if (base4 + 1 < nrows) start[rlo + base4 + 1] = baseb + p1;
    if (base4 + 2 < nrows) start[rlo + base4 + 2] = baseb + p2;
    if (base4 + 3 < nrows) start[rlo + base4 + 3] = baseb + p3;

    pref[base4] = p0; pref[base4 + 1] = p1; pref[base4 + 2] = p2; pref[base4 + 3] = p3;
    __syncthreads();

    for (int j = t; j < cntb; j += 256) {
        int2 p  = bkt[j];
        int loc = atomicAdd(&pref[p.x - rlo], 1);
        ei[baseb + loc] = make_int2(col[p.y], p.y);
    }
}

// ---------------------------------------------------------------------------
// Edge pass A, node-parallel: sequential msorted write, register rowsum,
// fused d_inv_sqrt.
// ---------------------------------------------------------------------------
__global__ __launch_bounds__(256)
void edge_pass_a_kernel(const int2* __restrict__ ei, const int* __restrict__ start,
                        const float* __restrict__ u,
                        const float* __restrict__ a_nb, const float* __restrict__ a_self,
                        const float* __restrict__ ba_p, const float* __restrict__ temp_p,
                        float* __restrict__ msorted, float* __restrict__ dis,
                        float* __restrict__ l0_accum, int nNodes)
{
    const float ba   = ba_p[0];
    const float t    = temp_p[0];
    const float invt = 1.0f / t;
    const float lt   = logf(0.45f / 1.05f);   // log(-GAMMA/ZETA)
    const float shift = t * lt;

    const int r = blockIdx.x * 256 + threadIdx.x;
    float l0local = 0.0f;

    if (r < nNodes) {
        const int js = start[r], je = start[r + 1];
        const float la_base = a_nb[r] + ba;
        float rs = 0.0f;
        for (int j = js; j < je; ++j) {
            int2 p = ei[j];                       // {col, e}
            float la = la_base + a_self[p.x];
            float uu = u[p.y];
            float noise = logf(uu) - log1pf(-uu);
            float gate  = 1.0f / (1.0f + expf(-(noise + la) * invt));
            float m = fminf(fmaxf(gate * 1.5f - 0.45f, 0.0f), 1.0f);
            msorted[j] = m;
            rs += m;
            l0local += 1.0f / (1.0f + expf(-(la - shift)));
        }
        dis[r] = fminf(1.0f / sqrtf(rs + 1e-6f), 10.0f);
    }

    __shared__ float red[256];
    red[threadIdx.x] = l0local;
    __syncthreads();
    for (int s = 128; s > 0; s >>= 1) {
        if (threadIdx.x < s) red[threadIdx.x] += red[threadIdx.x + s];
        __syncthreads();
    }
    if (threadIdx.x == 0) unsafeAtomicAdd(l0_accum, red[0]);
}

// ---------------------------------------------------------------------------
// Edge gather (bf16 src/dst, f32 accumulate):
//   xnb[r] = bf16( dis[r] * sum_j msorted[j]*dis[c_j]*x[c_j] )
// ---------------------------------------------------------------------------
__global__ void edge_gather_kernel(const float* __restrict__ ms, const int2* __restrict__ ei,
                                   const int* __restrict__ start,
                                   const float* __restrict__ dis,
                                   const unsigned short* __restrict__ xb,
                                   unsigned short* __restrict__ xnb, int nNodes)
{
    const int lane   = threadIdx.x & 63;
    const int wave   = (blockIdx.x * blockDim.x + threadIdx.x) >> 6;
    const int nWaves = (gridDim.x * blockDim.x) >> 6;

    for (int r = wave; r < nNodes; r += nWaves) {
        const int ru = __builtin_amdgcn_readfirstlane(r);
        int js = __builtin_amdgcn_readfirstlane(start[ru]);
        int je = __builtin_amdgcn_readfirstlane(start[ru + 1]);
        float acc = 0.0f;
        int j = js;
        for (; j + 4 <= je; j += 4) {
            float m0 = ms[j],   m1 = ms[j+1], m2 = ms[j+2], m3 = ms[j+3];
            int   c0 = ei[j].x, c1 = ei[j+1].x, c2 = ei[j+2].x, c3 = ei[j+3].x;
            if (m0 > 0.0f) acc = fmaf(m0 * dis[c0], b2f(xb[(size_t)c0 * 64 + lane]), acc);
            if (m1 > 0.0f) acc = fmaf(m1 * dis[c1], b2f(xb[(size_t)c1 * 64 + lane]), acc);
            if (m2 > 0.0f) acc = fmaf(m2 * dis[c2], b2f(xb[(size_t)c2 * 64 + lane]), acc);
            if (m3 > 0.0f) acc = fmaf(m3 * dis[c3], b2f(xb[(size_t)c3 * 64 + lane]), acc);
        }
        for (; j < je; ++j) {
            float m = ms[j];
            if (m > 0.0f) {
                int c = ei[j].x;
                acc = fmaf(m * dis[c], b2f(xb[(size_t)c * 64 + lane]), acc);
            }
        }
        xnb[(size_t)ru * 64 + lane] = f2b(acc * dis[ru]);
    }
}

// ---------------------------------------------------------------------------
// BPR loss: xs = features(f32) + x1(bf16) + x2(bf16)
// ---------------------------------------------------------------------------
__global__ void bpr_kernel(const float* __restrict__ f,
                           const unsigned short* __restrict__ x1b,
                           const unsigned short* __restrict__ x2b,
                           const int* __restrict__ users, const int* __restrict__ items,
                           const int* __restrict__ negs,
                           float* __restrict__ bpr_accum, int B)
{
    const int lane   = threadIdx.x & 63;
    const int wave   = (blockIdx.x * blockDim.x + threadIdx.x) >> 6;
    const int nWaves = (gridDim.x * blockDim.x) >> 6;

    float local = 0.0f;
    for (int b = wave; b < B; b += nWaves) {
        size_t ui = (size_t)users[b] * 64 + lane;
        size_t pi = (size_t)(N_USER + items[b]) * 64 + lane;
        size_t ni = (size_t)(N_USER + negs[b]) * 64 + lane;
        float a = f[ui] + b2f(x1b[ui]) + b2f(x2b[ui]);
        float p = f[pi] + b2f(x1b[pi]) + b2f(x2b[pi]);
        float n = f[ni] + b2f(x1b[ni]) + b2f(x2b[ni]);
        float ps = a * p, ns = a * n;
        #pragma unroll
        for (int off = 32; off; off >>= 1) {
            ps += __shfl_xor(ps, off);
            ns += __shfl_xor(ns, off);
        }
        if (lane == 0) {
            float s = 1.0f / (1.0f + expf(-(ps - ns)));
            local += -logf(s + 1e-5f);
        }
    }
    if (lane == 0) unsafeAtomicAdd(bpr_accum, local);
}

// ---------------------------------------------------------------------------
// L2 regularization on params
// ---------------------------------------------------------------------------
__global__ void reg_kernel(const float* __restrict__ w0, const float* __restrict__ b0,
                           const float* __restrict__ w1, const float* __restrict__ b1,
                           const float* __restrict__ wa0, const float* __restrict__ ba0,
                           const float* __restrict__ w2, const float* __restrict__ b2,
                           const float* __restrict__ w3, const float* __restrict__ b3,
                           const float* __restrict__ wa1, const float* __restrict__ ba1,
                           float* __restrict__ accum)
{
    int t = threadIdx.x;
    float s = 0.0f;
    for (int i = t; i < 4096; i += 256)
        s += w0[i]*w0[i] + w1[i]*w1[i] + w2[i]*w2[i] + w3[i]*w3[i];
    for (int i = t; i < 64; i += 256)
        s += b0[i]*b0[i] + b1[i]*b1[i] + b2[i]*b2[i] + b3[i]*b3[i];
    for (int i = t; i < 128; i += 256)
        s += wa0[i]*wa0[i] + wa1[i]*wa1[i];
    if (t == 0) s += ba0[0]*ba0[0] + ba1[0]*ba1[0];

    __shared__ float red[256];
    red[t] = s;
    __syncthreads();
    for (int st = 128; st > 0; st >>= 1) {
        if (t < st) red[t] += red[t + st];
        __syncthreads();
    }
    if (t == 0) accum[0] = red[0];
}

__global__ void finalize_kernel(const float* __restrict__ scal, float* __restrict__ out)
{
    float bpr = scal[0] / (float)B_TOT;
    float reg = scal[1] * 1e-4f;
    float l0  = (scal[2] + scal[3]) * (1e-4f / (float)E_TOT);
    out[0] = bpr + reg + l0;
}

extern "C" void kernel_launch(void* const* d_in, const int* in_sizes, int n_in,
                              void* d_out, int out_size, void* d_ws, size_t ws_size,
                              hipStream_t stream)
{
    const float* features = (const float*)d_in[0];
    const int*   row      = (const int*)d_in[1];
    const int*   col      = (const int*)d_in[2];
    const int*   users    = (const int*)d_in[3];
    const int*   items    = (const int*)d_in[4];
    const int*   negs     = (const int*)d_in[5];
    const float* u0       = (const float*)d_in[6];
    const float* u1       = (const float*)d_in[7];
    const float* temp     = (const float*)d_in[8];
    const float* W_nb0    = (const float*)d_in[9];
    const float* b_nb0    = (const float*)d_in[10];
    const float* W_self0  = (const float*)d_in[11];
    const float* b_self0  = (const float*)d_in[12];
    const float* W_att0   = (const float*)d_in[13];
    const float* b_att0   = (const float*)d_in[14];
    const float* W_nb1    = (const float*)d_in[15];
    const float* b_nb1    = (const float*)d_in[16];
    const float* W_self1  = (const float*)d_in[17];
    const float* b_self1  = (const float*)d_in[18];
    const float* W_att1   = (const float*)d_in[19];
    const float* b_att1   = (const float*)d_in[20];
    float* out = (float*)d_out;

    // ---- Workspace layout (4B element offsets), ~82 MB total ----
    float* ws = (float*)d_ws;
    unsigned short* fb  = (unsigned short*)ws;               // N*64 bf16
    unsigned short* x1b = (unsigned short*)(ws + 4800000);   // N*64 bf16
    unsigned short* x2b = (unsigned short*)(ws + 9600000);   // N*64 bf16
    // zeroed block: scal + bcnt
    float* scal  = ws + 14400000;                 // 16
    int*   bcnt  = (int*)(scal + 16);             // NBKT (pad 160)
    // end zeroed block
    int*   bbase = bcnt + 160;                    // NBKT+1 (pad 160)
    int*   start = bbase + 160;                   // NSCAN_PAD
    int2*  tmp   = (int2*)(start + NSCAN_PAD);    // NBKT*BKT_CAP int2 (9.6MB)
    int2*  ei    = tmp + (size_t)NBKT * BKT_CAP;  // E int2
    float* msorted = (float*)(ei + E_TOT);        // E
    float* dis     = msorted + E_TOT;             // N_TOT
    float* a_nb    = dis + N_TOT;                 // N_TOT
    float* a_self  = a_nb + N_TOT;                // N_TOT
    unsigned short* wpk =
        (unsigned short*)(((uintptr_t)(a_self + N_TOT) + 15) & ~(uintptr_t)15);  // 16384 bf16 (32KB)

    hipMemsetAsync(scal, 0, (16 + 160) * sizeof(float), stream);

    const int nNodeBlocks = (N_TOT + 255) / 256;   // 586
    const int nMfmaBlocks = (N_TOT / 16 + 3) / 4;  // 9375 waves, 4 per block -> 2344

    // ---- features -> bf16, weights -> packed bf16 frags ----
    tobf16_kernel<<<1024, 256, 0, stream>>>((const float4*)features, (ushort4*)fb, N_TOT * 16);
    wpack_kernel<<<8, 256, 0, stream>>>(W_nb0, W_self0, W_nb1, W_self1, wpk);

    // ---- CSR build: bin -> bucket scan -> per-bucket counting-sort ----
    bin_kernel<<<NBIN_BLOCKS, 256, 0, stream>>>(row, bcnt, tmp, E_TOT);
    bucket_scan_kernel<<<1, 256, 0, stream>>>(bcnt, bbase, start);
    scatter2_kernel<<<NBKT, 256, 0, stream>>>(tmp, bcnt, bbase, col, start, ei);

    // ---- Layer 0 ----
    node_scalars_mfma_kernel<<<nMfmaBlocks, 256, 0, stream>>>(fb, wpk, b_nb0, b_self0, W_att0,
                                                              a_nb, a_self, N_TOT);
    edge_pass_a_kernel<<<nNodeBlocks, 256, 0, stream>>>(ei, start, u0, a_nb, a_self, b_att0, temp,
                                                        msorted, dis, &scal[2], N_TOT);
    edge_gather_kernel<<<2048, 256, 0, stream>>>(msorted, ei, start, dis, fb, x1b, N_TOT);

    // ---- Layer 1 ----
    node_scalars_mfma_kernel<<<nMfmaBlocks, 256, 0, stream>>>(x1b, wpk + 8192, b_nb1, b_self1, W_att1,
                                                              a_nb, a_self, N_TOT);
    edge_pass_a_kernel<<<nNodeBlocks, 256, 0, stream>>>(ei, start, u1, a_nb, a_self, b_att1, temp,
                                                        msorted, dis, &scal[3], N_TOT);
    edge_gather_kernel<<<2048, 256, 0, stream>>>(msorted, ei, start, dis, x1b, x2b, N_TOT);

    // ---- Losses ----
    bpr_kernel<<<64, 256, 0, stream>>>(features, x1b, x2b, users, items, negs, &scal[0], B_TOT);
    reg_kernel<<<1, 256, 0, stream>>>(W_nb0, b_nb0, W_self0, b_self0, W_att0, b_att0,
                                      W_nb1, b_nb1, W_self1, b_self1, W_att1, b_att1, &scal[1]);
    finalize_kernel<<<1, 1, 0, stream>>>(scal, out);
}

// Round 10
// 278.955 us; speedup vs baseline: 1.4083x; 1.1119x over previous
//
#include <hip/hip_runtime.h>
#include <hip/hip_bf16.h>

#define N_TOT   150000
#define N_USER  100000
#define E_TOT   1000000
#define B_TOT   4096
#define D_DIM   64

#define NSCAN_PAD   150016          // N_TOT+1 rounded up to multiple of 8
#define BKT_SHIFT   10
#define BKT_ROWS    (1 << BKT_SHIFT)                 // 1024 rows per bucket
#define NBKT        ((N_TOT + BKT_ROWS - 1) / BKT_ROWS)   // 147
#define BKT_CAP     8192
#define BIN_CHUNK   4096
#define NBIN_BLOCKS ((E_TOT + BIN_CHUNK - 1) / BIN_CHUNK) // 245

typedef short short8v  __attribute__((ext_vector_type(8)));
typedef float float4v  __attribute__((ext_vector_type(4)));

// ---- bf16 helpers (bit ops; accumulation always f32) ----
__device__ __forceinline__ float b2f(unsigned int lo16)
{
    union { unsigned int u; float f; } c; c.u = lo16 << 16; return c.f;
}
__device__ __forceinline__ unsigned short f2b(float f)
{
    union { float f; unsigned int u; } c; c.f = f;
    unsigned int u = c.u + 0x7FFFu + ((c.u >> 16) & 1u);   // RNE
    return (unsigned short)(u >> 16);
}
__device__ __forceinline__ int   f_as_i(float f) { union { float f; int i; } c; c.f = f; return c.i; }
__device__ __forceinline__ float i_as_f(int i)   { union { int i; float f; } c; c.i = i; return c.f; }

// ---------------------------------------------------------------------------
// features f32 -> bf16
// ---------------------------------------------------------------------------
__global__ void tobf16_kernel(const float4* __restrict__ in, ushort4* __restrict__ out, int n4)
{
    for (int i = blockIdx.x * blockDim.x + threadIdx.x; i < n4; i += gridDim.x * blockDim.x) {
        float4 v = in[i];
        ushort4 o;
        o.x = f2b(v.x); o.y = f2b(v.y); o.z = f2b(v.z); o.w = f2b(v.w);
        out[i] = o;
    }
}

// ---------------------------------------------------------------------------
// Pack the 4 weight matrices into MFMA B-fragment order, bf16:
// wpk[m][kb][nt][lane][j] = W_m[32*kb + (lane>>4)*8 + j][16*nt + (lane&15)]
// ---------------------------------------------------------------------------
__global__ void wpack_kernel(const float* __restrict__ Wn0, const float* __restrict__ Ws0,
                             const float* __restrict__ Wn1, const float* __restrict__ Ws1,
                             unsigned short* __restrict__ wpk)
{
    int f = blockIdx.x * blockDim.x + threadIdx.x;   // [0, 2048)
    if (f >= 2048) return;
    const float* W[4] = {Wn0, Ws0, Wn1, Ws1};
    int m   = f >> 9;
    int rem = f & 511;
    int kb  = rem >> 8;
    int nt  = (rem >> 6) & 3;
    int l   = rem & 63;
    const float* Wm = W[m];
    int kbase = 32 * kb + ((l >> 4) << 3);
    int n     = 16 * nt + (l & 15);
    unsigned short o[8];
    #pragma unroll
    for (int j = 0; j < 8; ++j) o[j] = f2b(Wm[(kbase + j) * 64 + n]);
    ushort4* dst = (ushort4*)(wpk + (size_t)f * 8);
    dst[0] = make_ushort4(o[0], o[1], o[2], o[3]);
    dst[1] = make_ushort4(o[4], o[5], o[6], o[7]);
}

// ---------------------------------------------------------------------------
// Node scalars via MFMA: one wave per 16 nodes.
// ---------------------------------------------------------------------------
__global__ __launch_bounds__(256)
void node_scalars_mfma_kernel(const unsigned short* __restrict__ xb,
                              const unsigned short* __restrict__ wpack, // [2][2][4][64][8]
                              const float* __restrict__ bn, const float* __restrict__ bs,
                              const float* __restrict__ Wa,
                              float* __restrict__ a_nb, float* __restrict__ a_self,
                              int nNodes)
{
    const int lane = threadIdx.x & 63;
    const int wid  = (blockIdx.x * blockDim.x + threadIdx.x) >> 6;
    const int nodeBase = wid * 16;
    if (nodeBase >= nNodes) return;

    short8v bfrag[2][2][4];
    #pragma unroll
    for (int m = 0; m < 2; ++m)
        #pragma unroll
        for (int kb = 0; kb < 2; ++kb)
            #pragma unroll
            for (int nt = 0; nt < 4; ++nt)
                bfrag[m][kb][nt] =
                    *(const short8v*)(wpack + (size_t)((((m * 2 + kb) * 4 + nt) * 64 + lane)) * 8);

    const size_t rowOff = (size_t)(nodeBase + (lane & 15)) * 64 + ((lane >> 4) << 3);
    short8v a0 = *(const short8v*)(xb + rowOff);
    short8v a1 = *(const short8v*)(xb + rowOff + 32);

    float4v acc[2][4];
    #pragma unroll
    for (int m = 0; m < 2; ++m)
        #pragma unroll
        for (int nt = 0; nt < 4; ++nt) {
            float4v z = {0.f, 0.f, 0.f, 0.f};
            z = __builtin_amdgcn_mfma_f32_16x16x32_bf16(a0, bfrag[m][0][nt], z, 0, 0, 0);
            z = __builtin_amdgcn_mfma_f32_16x16x32_bf16(a1, bfrag[m][1][nt], z, 0, 0, 0);
            acc[m][nt] = z;
        }

    const int j = lane & 15;
    float pn[4] = {0.f, 0.f, 0.f, 0.f};
    float ps[4] = {0.f, 0.f, 0.f, 0.f};
    #pragma unroll
    for (int nt = 0; nt < 4; ++nt) {
        float bnv = bn[nt * 16 + j], bsv = bs[nt * 16 + j];
        float wan = Wa[nt * 16 + j], was = Wa[64 + nt * 16 + j];
        #pragma unroll
        for (int r = 0; r < 4; ++r) {
            pn[r] = fmaf(fmaxf(acc[0][nt][r] + bnv, 0.f), wan, pn[r]);
            ps[r] = fmaf(fmaxf(acc[1][nt][r] + bsv, 0.f), was, ps[r]);
        }
    }
    #pragma unroll
    for (int off = 1; off < 16; off <<= 1) {
        #pragma unroll
        for (int r = 0; r < 4; ++r) {
            pn[r] += __shfl_xor(pn[r], off);
            ps[r] += __shfl_xor(ps[r], off);
        }
    }
    if (j == 0) {
        const int g = lane >> 4;
        #pragma unroll
        for (int r = 0; r < 4; ++r) {
            int node = nodeBase + g * 4 + r;
            a_nb[node]   = pn[r];
            a_self[node] = ps[r];
        }
    }
}

// ---------------------------------------------------------------------------
// Phase 1: bin edges into NBKT coarse buckets (1024 rows each).
// ---------------------------------------------------------------------------
__global__ __launch_bounds__(256)
void bin_kernel(const int* __restrict__ row, int* __restrict__ bcnt,
                int2* __restrict__ tmp, int nE)
{
    __shared__ int cnt[NBKT];
    __shared__ int base[NBKT];
    for (int i = threadIdx.x; i < NBKT; i += 256) cnt[i] = 0;
    __syncthreads();

    const int e0 = blockIdx.x * BIN_CHUNK + threadIdx.x;
    int r[16];
    #pragma unroll
    for (int k = 0; k < 16; ++k) {
        int e = e0 + k * 256;
        r[k] = (e < nE) ? row[e] : -1;
        if (r[k] >= 0) atomicAdd(&cnt[r[k] >> BKT_SHIFT], 1);
    }
    __syncthreads();

    for (int i = threadIdx.x; i < NBKT; i += 256) {
        int c = cnt[i];
        base[i] = c ? atomicAdd(&bcnt[i], c) : 0;
        cnt[i] = 0;
    }
    __syncthreads();

    #pragma unroll
    for (int k = 0; k < 16; ++k) {
        if (r[k] >= 0) {
            int b   = r[k] >> BKT_SHIFT;
            int loc = atomicAdd(&cnt[b], 1);
            tmp[(size_t)b * BKT_CAP + base[b] + loc] = make_int2(r[k], e0 + k * 256);
        }
    }
}

__global__ void bucket_scan_kernel(const int* __restrict__ bcnt, int* __restrict__ bbase,
                                   int* __restrict__ start)
{
    __shared__ int sh[256];
    int t = threadIdx.x;
    int v = (t < NBKT) ? bcnt[t] : 0;
    sh[t] = v;
    __syncthreads();
    for (int off = 1; off < 256; off <<= 1) {
        int x = sh[t];
        if (t >= off) x += sh[t - off];
        __syncthreads();
        sh[t] = x;
        __syncthreads();
    }
    if (t <= NBKT) bbase[t] = (t == 0) ? 0 : sh[t - 1];
    if (t == 0) start[N_TOT] = E_TOT;
}

// ---------------------------------------------------------------------------
// Phase 2: one block per bucket; LDS counting-sort -> start[] + col/u-sorted.
// Also gathers u0/u1 per edge ONCE (random reads), so both edge_pass_a's
// read u purely sequentially.
// ---------------------------------------------------------------------------
__global__ __launch_bounds__(256)
void scatter2_kernel(const int2* __restrict__ tmp, const int* __restrict__ bcnt,
                     const int* __restrict__ bbase, const int* __restrict__ col,
                     const float* __restrict__ u0, const float* __restrict__ u1,
                     int* __restrict__ start, int* __restrict__ colsorted,
                     float* __restrict__ us0, float* __restrict__ us1)
{
    __shared__ int pref[BKT_ROWS];
    __shared__ int wsum[256];

    const int b     = blockIdx.x;
    const int rlo   = b << BKT_SHIFT;
    const int nrows = min(BKT_ROWS, N_TOT - rlo);
    const int cntb  = bcnt[b];
    const int baseb = bbase[b];
    const int t     = threadIdx.x;
    const int2* __restrict__ bkt = tmp + (size_t)b * BKT_CAP;

    for (int i = t; i < BKT_ROWS; i += 256) pref[i] = 0;
    __syncthreads();

    for (int j = t; j < cntb; j += 256)
        atomicAdd(&pref[bkt[j].x - rlo], 1);
    __syncthreads();

    const int base4 = t * 4;
    int v0 = pref[base4], v1 = pref[base4 + 1], v2 = pref[base4 + 2], v3 = pref[base4 + 3];
    int s = v0 + v1 + v2 + v3;
    wsum[t] = s;
    __syncthreads();
    for (int off = 1; off < 256; off <<= 1) {
        int x = wsum[t];
        if (t >= off) x += wsum[t - off];
        __syncthreads();
        wsum[t] = x;
        __syncthreads();
    }
    const int pre = wsum[t] - s;
    const int p0 = pre, p1 = pre + v0, p2 = pre + v0 + v1, p3 = pre + v0 + v1 + v2;

    if (base4     < nrows) start[rlo + base4]     = baseb + p0;
    if (base4 + 1 < nrows) start[rlo + base4 + 1] = baseb + p1;
    if (base4 + 2 < nrows) start[rlo + base4 + 2] = baseb + p2;
    if (base4 + 3 < nrows) start[rlo + base4 + 3] = baseb + p3;

    pref[base4] = p0; pref[base4 + 1] = p1; pref[base4 + 2] = p2; pref[base4 + 3] = p3;
    __syncthreads();

    for (int j = t; j < cntb; j += 256) {
        int2 p  = bkt[j];
        int loc = atomicAdd(&pref[p.x - rlo], 1);
        int pos = baseb + loc;
        colsorted[pos] = col[p.y];
        us0[pos] = u0[p.y];
        us1[pos] = u1[p.y];
    }
}

// ---------------------------------------------------------------------------
// Edge pass A, node-parallel, fully sequential reads: colsorted + us in CSR
// order. Writes COMPACTED {m, col} records (only m>0) + endc[r]; fused dis.
// ---------------------------------------------------------------------------
__global__ __launch_bounds__(256)
void edge_pass_a_kernel(const int* __restrict__ colsorted, const int* __restrict__ start,
                        const float* __restrict__ us,
                        const float* __restrict__ a_nb, const float* __restrict__ a_self,
                        const float* __restrict__ ba_p, const float* __restrict__ temp_p,
                        float2* __restrict__ wc, int* __restrict__ endc,
                        float* __restrict__ dis,
                        float* __restrict__ l0_accum, int nNodes)
{
    const float ba   = ba_p[0];
    const float t    = temp_p[0];
    const float invt = 1.0f / t;
    const float lt   = logf(0.45f / 1.05f);   // log(-GAMMA/ZETA)
    const float shift = t * lt;

    const int r = blockIdx.x * 256 + threadIdx.x;
    float l0local = 0.0f;

    if (r < nNodes) {
        const int js = start[r], je = start[r + 1];
        const float la_base = a_nb[r] + ba;
        float rs = 0.0f;
        int k = js;
        for (int j = js; j < je; ++j) {
            int c = colsorted[j];
            float la = la_base + a_self[c];
            float uu = us[j];
            float noise = logf(uu) - log1pf(-uu);
            float gate  = 1.0f / (1.0f + expf(-(noise + la) * invt));
            float m = fminf(fmaxf(gate * 1.5f - 0.45f, 0.0f), 1.0f);
            rs += m;
            l0local += 1.0f / (1.0f + expf(-(la - shift)));
            if (m > 0.0f) { wc[k] = make_float2(m, i_as_f(c)); ++k; }
        }
        endc[r] = k;
        dis[r] = fminf(1.0f / sqrtf(rs + 1e-6f), 10.0f);
    }

    __shared__ float red[256];
    red[threadIdx.x] = l0local;
    __syncthreads();
    for (int s = 128; s > 0; s >>= 1) {
        if (threadIdx.x < s) red[threadIdx.x] += red[threadIdx.x + s];
        __syncthreads();
    }
    if (threadIdx.x == 0) unsafeAtomicAdd(l0_accum, red[0]);
}

// ---------------------------------------------------------------------------
// Edge gather (compacted, branch-free): unconditional row loads pipeline.
//   xnb[r] = bf16( dis[r] * sum_j wc[j].m * dis[c_j] * x[c_j] )
// ---------------------------------------------------------------------------
__global__ void edge_gather_kernel(const float2* __restrict__ wc, const int* __restrict__ start,
                                   const int* __restrict__ endc,
                                   const float* __restrict__ dis,
                                   const unsigned short* __restrict__ xb,
                                   unsigned short* __restrict__ xnb, int nNodes)
{
    const int lane   = threadIdx.x & 63;
    const int wave   = (blockIdx.x * blockDim.x + threadIdx.x) >> 6;
    const int nWaves = (gridDim.x * blockDim.x) >> 6;

    for (int r = wave; r < nNodes; r += nWaves) {
        const int ru = __builtin_amdgcn_readfirstlane(r);
        int js = __builtin_amdgcn_readfirstlane(start[ru]);
        int je = __builtin_amdgcn_readfirstlane(endc[ru]);
        float acc = 0.0f;
        int j = js;
        for (; j + 4 <= je; j += 4) {
            float2 w0 = wc[j], w1 = wc[j + 1], w2 = wc[j + 2], w3 = wc[j + 3];
            int c0 = f_as_i(w0.y), c1 = f_as_i(w1.y), c2 = f_as_i(w2.y), c3 = f_as_i(w3.y);
            float s0 = w0.x * dis[c0], s1 = w1.x * dis[c1];
            float s2 = w2.x * dis[c2], s3 = w3.x * dis[c3];
            float x0 = b2f(xb[(size_t)c0 * 64 + lane]);
            float x1 = b2f(xb[(size_t)c1 * 64 + lane]);
            float x2 = b2f(xb[(size_t)c2 * 64 + lane]);
            float x3 = b2f(xb[(size_t)c3 * 64 + lane]);
            acc = fmaf(s0, x0, acc);
            acc = fmaf(s1, x1, acc);
            acc = fmaf(s2, x2, acc);
            acc = fmaf(s3, x3, acc);
        }
        for (; j < je; ++j) {
            float2 w = wc[j];
            int c = f_as_i(w.y);
            acc = fmaf(w.x * dis[c], b2f(xb[(size_t)c * 64 + lane]), acc);
        }
        xnb[(size_t)ru * 64 + lane] = f2b(acc * dis[ru]);
    }
}

// ---------------------------------------------------------------------------
// BPR loss: xs = features(f32) + x1(bf16) + x2(bf16)
// ---------------------------------------------------------------------------
__global__ void bpr_kernel(const float* __restrict__ f,
                           const unsigned short* __restrict__ x1b,
                           const unsigned short* __restrict__ x2b,
                           const int* __restrict__ users, const int* __restrict__ items,
                           const int* __restrict__ negs,
                           float* __restrict__ bpr_accum, int B)
{
    const int lane   = threadIdx.x & 63;
    const int wave   = (blockIdx.x * blockDim.x + threadIdx.x) >> 6;
    const int nWaves = (gridDim.x * blockDim.x) >> 6;

    float local = 0.0f;
    for (int b = wave; b < B; b += nWaves) {
        size_t ui = (size_t)users[b] * 64 + lane;
        size_t pi = (size_t)(N_USER + items[b]) * 64 + lane;
        size_t ni = (size_t)(N_USER + negs[b]) * 64 + lane;
        float a = f[ui] + b2f(x1b[ui]) + b2f(x2b[ui]);
        float p = f[pi] + b2f(x1b[pi]) + b2f(x2b[pi]);
        float n = f[ni] + b2f(x1b[ni]) + b2f(x2b[ni]);
        float ps = a * p, ns = a * n;
        #pragma unroll
        for (int off = 32; off; off >>= 1) {
            ps += __shfl_xor(ps, off);
            ns += __shfl_xor(ns, off);
        }
        if (lane == 0) {
            float s = 1.0f / (1.0f + expf(-(ps - ns)));
            local += -logf(s + 1e-5f);
        }
    }
    if (lane == 0) unsafeAtomicAdd(bpr_accum, local);
}

// ---------------------------------------------------------------------------
// L2 regularization on params
// ---------------------------------------------------------------------------
__global__ void reg_kernel(const float* __restrict__ w0, const float* __restrict__ b0,
                           const float* __restrict__ w1, const float* __restrict__ b1,
                           const float* __restrict__ wa0, const float* __restrict__ ba0,
                           const float* __restrict__ w2, const float* __restrict__ b2,
                           const float* __restrict__ w3, const float* __restrict__ b3,
                           const float* __restrict__ wa1, const float* __restrict__ ba1,
                           float* __restrict__ accum)
{
    int t = threadIdx.x;
    float s = 0.0f;
    for (int i = t; i < 4096; i += 256)
        s += w0[i]*w0[i] + w1[i]*w1[i] + w2[i]*w2[i] + w3[i]*w3[i];
    for (int i = t; i < 64; i += 256)
        s += b0[i]*b0[i] + b1[i]*b1[i] + b2[i]*b2[i] + b3[i]*b3[i];
    for (int i = t; i < 128; i += 256)
        s += wa0[i]*wa0[i] + wa1[i]*wa1[i];
    if (t == 0) s += ba0[0]*ba0[0] + ba1[0]*ba1[0];

    __shared__ float red[256];
    red[t] = s;
    __syncthreads();
    for (int st = 128; st > 0; st >>= 1) {
        if (t < st) red[t] += red[t + st];
        __syncthreads();
    }
    if (t == 0) accum[0] = red[0];
}

__global__ void finalize_kernel(const float* __restrict__ scal, float* __restrict__ out)
{
    float bpr = scal[0] / (float)B_TOT;
    float reg = scal[1] * 1e-4f;
    float l0  = (scal[2] + scal[3]) * (1e-4f / (float)E_TOT);
    out[0] = bpr + reg + l0;
}

extern "C" void kernel_launch(void* const* d_in, const int* in_sizes, int n_in,
                              void* d_out, int out_size, void* d_ws, size_t ws_size,
                              hipStream_t stream)
{
    const float* features = (const float*)d_in[0];
    const int*   row      = (const int*)d_in[1];
    const int*   col      = (const int*)d_in[2];
    const int*   users    = (const int*)d_in[3];
    const int*   items    = (const int*)d_in[4];
    const int*   negs     = (const int*)d_in[5];
    const float* u0       = (const float*)d_in[6];
    const float* u1       = (const float*)d_in[7];
    const float* temp     = (const float*)d_in[8];
    const float* W_nb0    = (const float*)d_in[9];
    const float* b_nb0    = (const float*)d_in[10];
    const float* W_self0  = (const float*)d_in[11];
    const float* b_self0  = (const float*)d_in[12];
    const float* W_att0   = (const float*)d_in[13];
    const float* b_att0   = (const float*)d_in[14];
    const float* W_nb1    = (const float*)d_in[15];
    const float* b_nb1    = (const float*)d_in[16];
    const float* W_self1  = (const float*)d_in[17];
    const float* b_self1  = (const float*)d_in[18];
    const float* W_att1   = (const float*)d_in[19];
    const float* b_att1   = (const float*)d_in[20];
    float* out = (float*)d_out;

    // ---- Workspace layout (4B element offsets), ~90 MB total ----
    float* ws = (float*)d_ws;
    unsigned short* fb  = (unsigned short*)ws;               // N*64 bf16
    unsigned short* x1b = (unsigned short*)(ws + 4800000);   // N*64 bf16
    unsigned short* x2b = (unsigned short*)(ws + 9600000);   // N*64 bf16
    // zeroed block: scal + bcnt
    float* scal  = ws + 14400000;                 // 16
    int*   bcnt  = (int*)(scal + 16);             // NBKT (pad 160)
    // end zeroed block
    int*   bbase = bcnt + 160;                    // NBKT+1 (pad 160)
    int*   start = bbase + 160;                   // NSCAN_PAD
    int2*  tmp   = (int2*)(start + NSCAN_PAD);    // NBKT*BKT_CAP int2 (9.6MB)
    int*   colsorted = (int*)(tmp + (size_t)NBKT * BKT_CAP);  // E
    float* us0   = (float*)(colsorted + E_TOT);   // E
    float* us1   = us0 + E_TOT;                   // E
    float2* wc   = (float2*)(us1 + E_TOT);        // E float2 (8B-aligned: even offset)
    int*   endc  = (int*)(wc + E_TOT);            // N_TOT
    float* dis   = (float*)(endc + N_TOT);        // N_TOT
    float* a_nb  = dis + N_TOT;                   // N_TOT
    float* a_self= a_nb + N_TOT;                  // N_TOT
    unsigned short* wpk =
        (unsigned short*)(((uintptr_t)(a_self + N_TOT) + 15) & ~(uintptr_t)15);  // 32KB

    hipMemsetAsync(scal, 0, (16 + 160) * sizeof(float), stream);

    const int nNodeBlocks = (N_TOT + 255) / 256;   // 586
    const int nMfmaBlocks = (N_TOT / 16 + 3) / 4;  // 2344

    // ---- features -> bf16, weights -> packed bf16 frags ----
    tobf16_kernel<<<1024, 256, 0, stream>>>((const float4*)features, (ushort4*)fb, N_TOT * 16);
    wpack_kernel<<<8, 256, 0, stream>>>(W_nb0, W_self0, W_nb1, W_self1, wpk);

    // ---- CSR build: bin -> bucket scan -> per-bucket counting-sort ----
    bin_kernel<<<NBIN_BLOCKS, 256, 0, stream>>>(row, bcnt, tmp, E_TOT);
    bucket_scan_kernel<<<1, 256, 0, stream>>>(bcnt, bbase, start);
    scatter2_kernel<<<NBKT, 256, 0, stream>>>(tmp, bcnt, bbase, col, u0, u1,
                                              start, colsorted, us0, us1);

    // ---- Layer 0 ----
    node_scalars_mfma_kernel<<<nMfmaBlocks, 256, 0, stream>>>(fb, wpk, b_nb0, b_self0, W_att0,
                                                              a_nb, a_self, N_TOT);
    edge_pass_a_kernel<<<nNodeBlocks, 256, 0, stream>>>(colsorted, start, us0, a_nb, a_self,
                                                        b_att0, temp, wc, endc, dis,
                                                        &scal[2], N_TOT);
    edge_gather_kernel<<<2048, 256, 0, stream>>>(wc, start, endc, dis, fb, x1b, N_TOT);

    // ---- Layer 1 ----
    node_scalars_mfma_kernel<<<nMfmaBlocks, 256, 0, stream>>>(x1b, wpk + 8192, b_nb1, b_self1,
                                                              W_att1, a_nb, a_self, N_TOT);
    edge_pass_a_kernel<<<nNodeBlocks, 256, 0, stream>>>(colsorted, start, us1, a_nb, a_self,
                                                        b_att1, temp, wc, endc, dis,
                                                        &scal[3], N_TOT);
    edge_gather_kernel<<<2048, 256, 0, stream>>>(wc, start, endc, dis, x1b, x2b, N_TOT);

    // ---- Losses ----
    bpr_kernel<<<64, 256, 0, stream>>>(features, x1b, x2b, users, items, negs, &scal[0], B_TOT);
    reg_kernel<<<1, 256, 0, stream>>>(W_nb0, b_nb0, W_self0, b_self0, W_att0, b_att0,
                                      W_nb1, b_nb1, W_self1, b_self1, W_att1, b_att1, &scal[1]);
    finalize_kernel<<<1, 1, 0, stream>>>(scal, out);
}

// Round 11
// 253.070 us; speedup vs baseline: 1.5524x; 1.1023x over previous
//
#include <hip/hip_runtime.h>
#include <hip/hip_bf16.h>

#define N_TOT   150000
#define N_USER  100000
#define E_TOT   1000000
#define B_TOT   4096
#define D_DIM   64

#define NSCAN_PAD   150016          // N_TOT+1 rounded up to multiple of 8
#define BKT_SHIFT   10
#define BKT_ROWS    (1 << BKT_SHIFT)                 // 1024 rows per bucket
#define NBKT        ((N_TOT + BKT_ROWS - 1) / BKT_ROWS)   // 147
#define BKT_CAP     8192
#define BIN_CHUNK   4096
#define NBIN_BLOCKS ((E_TOT + BIN_CHUNK - 1) / BIN_CHUNK) // 245

typedef short short8v  __attribute__((ext_vector_type(8)));
typedef float float4v  __attribute__((ext_vector_type(4)));

// ---- bf16 helpers (bit ops; accumulation always f32) ----
__device__ __forceinline__ float b2f(unsigned int lo16)
{
    union { unsigned int u; float f; } c; c.u = lo16 << 16; return c.f;
}
__device__ __forceinline__ unsigned short f2b(float f)
{
    union { float f; unsigned int u; } c; c.f = f;
    unsigned int u = c.u + 0x7FFFu + ((c.u >> 16) & 1u);   // RNE
    return (unsigned short)(u >> 16);
}
__device__ __forceinline__ int   f_as_i(float f) { union { float f; int i; } c; c.f = f; return c.i; }
__device__ __forceinline__ float i_as_f(int i)   { union { int i; float f; } c; c.i = i; return c.f; }

// ---------------------------------------------------------------------------
// features f32 -> bf16
// ---------------------------------------------------------------------------
__global__ void tobf16_kernel(const float4* __restrict__ in, ushort4* __restrict__ out, int n4)
{
    for (int i = blockIdx.x * blockDim.x + threadIdx.x; i < n4; i += gridDim.x * blockDim.x) {
        float4 v = in[i];
        ushort4 o;
        o.x = f2b(v.x); o.y = f2b(v.y); o.z = f2b(v.z); o.w = f2b(v.w);
        out[i] = o;
    }
}

// ---------------------------------------------------------------------------
// Pack the 4 weight matrices into MFMA B-fragment order, bf16:
// wpk[m][kb][nt][lane][j] = W_m[32*kb + (lane>>4)*8 + j][16*nt + (lane&15)]
// ---------------------------------------------------------------------------
__global__ void wpack_kernel(const float* __restrict__ Wn0, const float* __restrict__ Ws0,
                             const float* __restrict__ Wn1, const float* __restrict__ Ws1,
                             unsigned short* __restrict__ wpk)
{
    int f = blockIdx.x * blockDim.x + threadIdx.x;   // [0, 2048)
    if (f >= 2048) return;
    const float* W[4] = {Wn0, Ws0, Wn1, Ws1};
    int m   = f >> 9;
    int rem = f & 511;
    int kb  = rem >> 8;
    int nt  = (rem >> 6) & 3;
    int l   = rem & 63;
    const float* Wm = W[m];
    int kbase = 32 * kb + ((l >> 4) << 3);
    int n     = 16 * nt + (l & 15);
    unsigned short o[8];
    #pragma unroll
    for (int j = 0; j < 8; ++j) o[j] = f2b(Wm[(kbase + j) * 64 + n]);
    ushort4* dst = (ushort4*)(wpk + (size_t)f * 8);
    dst[0] = make_ushort4(o[0], o[1], o[2], o[3]);
    dst[1] = make_ushort4(o[4], o[5], o[6], o[7]);
}

// ---------------------------------------------------------------------------
// Node scalars via MFMA: one wave per 16 nodes.
// ---------------------------------------------------------------------------
__global__ __launch_bounds__(256)
void node_scalars_mfma_kernel(const unsigned short* __restrict__ xb,
                              const unsigned short* __restrict__ wpack, // [2][2][4][64][8]
                              const float* __restrict__ bn, const float* __restrict__ bs,
                              const float* __restrict__ Wa,
                              float* __restrict__ a_nb, float* __restrict__ a_self,
                              int nNodes)
{
    const int lane = threadIdx.x & 63;
    const int wid  = (blockIdx.x * blockDim.x + threadIdx.x) >> 6;
    const int nodeBase = wid * 16;
    if (nodeBase >= nNodes) return;

    short8v bfrag[2][2][4];
    #pragma unroll
    for (int m = 0; m < 2; ++m)
        #pragma unroll
        for (int kb = 0; kb < 2; ++kb)
            #pragma unroll
            for (int nt = 0; nt < 4; ++nt)
                bfrag[m][kb][nt] =
                    *(const short8v*)(wpack + (size_t)((((m * 2 + kb) * 4 + nt) * 64 + lane)) * 8);

    const size_t rowOff = (size_t)(nodeBase + (lane & 15)) * 64 + ((lane >> 4) << 3);
    short8v a0 = *(const short8v*)(xb + rowOff);
    short8v a1 = *(const short8v*)(xb + rowOff + 32);

    float4v acc[2][4];
    #pragma unroll
    for (int m = 0; m < 2; ++m)
        #pragma unroll
        for (int nt = 0; nt < 4; ++nt) {
            float4v z = {0.f, 0.f, 0.f, 0.f};
            z = __builtin_amdgcn_mfma_f32_16x16x32_bf16(a0, bfrag[m][0][nt], z, 0, 0, 0);
            z = __builtin_amdgcn_mfma_f32_16x16x32_bf16(a1, bfrag[m][1][nt], z, 0, 0, 0);
            acc[m][nt] = z;
        }

    const int j = lane & 15;
    float pn[4] = {0.f, 0.f, 0.f, 0.f};
    float ps[4] = {0.f, 0.f, 0.f, 0.f};
    #pragma unroll
    for (int nt = 0; nt < 4; ++nt) {
        float bnv = bn[nt * 16 + j], bsv = bs[nt * 16 + j];
        float wan = Wa[nt * 16 + j], was = Wa[64 + nt * 16 + j];
        #pragma unroll
        for (int r = 0; r < 4; ++r) {
            pn[r] = fmaf(fmaxf(acc[0][nt][r] + bnv, 0.f), wan, pn[r]);
            ps[r] = fmaf(fmaxf(acc[1][nt][r] + bsv, 0.f), was, ps[r]);
        }
    }
    #pragma unroll
    for (int off = 1; off < 16; off <<= 1) {
        #pragma unroll
        for (int r = 0; r < 4; ++r) {
            pn[r] += __shfl_xor(pn[r], off);
            ps[r] += __shfl_xor(ps[r], off);
        }
    }
    if (j == 0) {
        const int g = lane >> 4;
        #pragma unroll
        for (int r = 0; r < 4; ++r) {
            int node = nodeBase + g * 4 + r;
            a_nb[node]   = pn[r];
            a_self[node] = ps[r];
        }
    }
}

// ---------------------------------------------------------------------------
// Phase 1: bin edges into NBKT coarse buckets, carrying {row, col, u0, u1}.
// All input reads sequential/coalesced; one 16B store per edge into ~220B
// contiguous runs per (block,bucket).
// ---------------------------------------------------------------------------
__global__ __launch_bounds__(256)
void bin_kernel(const int* __restrict__ row, const int* __restrict__ col,
                const float* __restrict__ u0, const float* __restrict__ u1,
                int* __restrict__ bcnt, int4* __restrict__ tmp, int nE)
{
    __shared__ int cnt[NBKT];
    __shared__ int base[NBKT];
    for (int i = threadIdx.x; i < NBKT; i += 256) cnt[i] = 0;
    __syncthreads();

    const int e0 = blockIdx.x * BIN_CHUNK + threadIdx.x;
    int r[16], c[16], ua[16], ub[16];
    #pragma unroll
    for (int k = 0; k < 16; ++k) {
        int e = e0 + k * 256;
        r[k] = (e < nE) ? row[e] : -1;
        if (r[k] >= 0) {
            c[k]  = col[e];
            ua[k] = f_as_i(u0[e]);
            ub[k] = f_as_i(u1[e]);
            atomicAdd(&cnt[r[k] >> BKT_SHIFT], 1);
        }
    }
    __syncthreads();

    for (int i = threadIdx.x; i < NBKT; i += 256) {
        int cc = cnt[i];
        base[i] = cc ? atomicAdd(&bcnt[i], cc) : 0;
        cnt[i] = 0;
    }
    __syncthreads();

    #pragma unroll
    for (int k = 0; k < 16; ++k) {
        if (r[k] >= 0) {
            int b   = r[k] >> BKT_SHIFT;
            int loc = atomicAdd(&cnt[b], 1);
            tmp[(size_t)b * BKT_CAP + base[b] + loc] = make_int4(r[k], c[k], ua[k], ub[k]);
        }
    }
}

__global__ void bucket_scan_kernel(const int* __restrict__ bcnt, int* __restrict__ bbase,
                                   int* __restrict__ start)
{
    __shared__ int sh[256];
    int t = threadIdx.x;
    int v = (t < NBKT) ? bcnt[t] : 0;
    sh[t] = v;
    __syncthreads();
    for (int off = 1; off < 256; off <<= 1) {
        int x = sh[t];
        if (t >= off) x += sh[t - off];
        __syncthreads();
        sh[t] = x;
        __syncthreads();
    }
    if (t <= NBKT) bbase[t] = (t == 0) ? 0 : sh[t - 1];
    if (t == 0) start[N_TOT] = E_TOT;
}

// ---------------------------------------------------------------------------
// Phase 2: one block per bucket; LDS counting-sort -> start[] + CSR rec[].
// ZERO random reads; one 16B store per edge into one L2-resident window.
// ---------------------------------------------------------------------------
__global__ __launch_bounds__(256)
void scatter2_kernel(const int4* __restrict__ tmp, const int* __restrict__ bcnt,
                     const int* __restrict__ bbase,
                     int* __restrict__ start, int4* __restrict__ rec)
{
    __shared__ int pref[BKT_ROWS];
    __shared__ int wsum[256];

    const int b     = blockIdx.x;
    const int rlo   = b << BKT_SHIFT;
    const int nrows = min(BKT_ROWS, N_TOT - rlo);
    const int cntb  = bcnt[b];
    const int baseb = bbase[b];
    const int t     = threadIdx.x;
    const int4* __restrict__ bkt = tmp + (size_t)b * BKT_CAP;

    for (int i = t; i < BKT_ROWS; i += 256) pref[i] = 0;
    __syncthreads();

    for (int j = t; j < cntb; j += 256)
        atomicAdd(&pref[bkt[j].x - rlo], 1);
    __syncthreads();

    const int base4 = t * 4;
    int v0 = pref[base4], v1 = pref[base4 + 1], v2 = pref[base4 + 2], v3 = pref[base4 + 3];
    int s = v0 + v1 + v2 + v3;
    wsum[t] = s;
    __syncthreads();
    for (int off = 1; off < 256; off <<= 1) {
        int x = wsum[t];
        if (t >= off) x += wsum[t - off];
        __syncthreads();
        wsum[t] = x;
        __syncthreads();
    }
    const int pre = wsum[t] - s;
    const int p0 = pre, p1 = pre + v0, p2 = pre + v0 + v1, p3 = pre + v0 + v1 + v2;

    if (base4     < nrows) start[rlo + base4]     = baseb + p0;
    if (base4 + 1 < nrows) start[rlo + base4 + 1] = baseb + p1;
    if (base4 + 2 < nrows) start[rlo + base4 + 2] = baseb + p2;
    if (base4 + 3 < nrows) start[rlo + base4 + 3] = baseb + p3;

    pref[base4] = p0; pref[base4 + 1] = p1; pref[base4 + 2] = p2; pref[base4 + 3] = p3;
    __syncthreads();

    for (int j = t; j < cntb; j += 256) {
        int4 q  = bkt[j];
        int loc = atomicAdd(&pref[q.x - rlo], 1);
        rec[baseb + loc] = make_int4(q.y, q.z, q.w, 0);
    }
}

// ---------------------------------------------------------------------------
// Edge pass A, node-parallel, fully sequential reads of rec {col,u0,u1}.
// Writes COMPACTED {m, col} records (only m>0) + endc[r]; fused dis.
// ---------------------------------------------------------------------------
__global__ __launch_bounds__(256)
void edge_pass_a_kernel(const int4* __restrict__ rec, const int* __restrict__ start,
                        const int uSel,
                        const float* __restrict__ a_nb, const float* __restrict__ a_self,
                        const float* __restrict__ ba_p, const float* __restrict__ temp_p,
                        float2* __restrict__ wc, int* __restrict__ endc,
                        float* __restrict__ dis,
                        float* __restrict__ l0_accum, int nNodes)
{
    const float ba   = ba_p[0];
    const float t    = temp_p[0];
    const float invt = 1.0f / t;
    const float lt   = logf(0.45f / 1.05f);   // log(-GAMMA/ZETA)
    const float shift = t * lt;

    const int r = blockIdx.x * 256 + threadIdx.x;
    float l0local = 0.0f;

    if (r < nNodes) {
        const int js = start[r], je = start[r + 1];
        const float la_base = a_nb[r] + ba;
        float rs = 0.0f;
        int k = js;
        for (int j = js; j < je; ++j) {
            int4 q = rec[j];                     // {col, u0, u1, -}
            int c = q.x;
            float la = la_base + a_self[c];
            float uu = i_as_f(uSel ? q.z : q.y);
            float noise = logf(uu) - log1pf(-uu);
            float gate  = 1.0f / (1.0f + expf(-(noise + la) * invt));
            float m = fminf(fmaxf(gate * 1.5f - 0.45f, 0.0f), 1.0f);
            rs += m;
            l0local += 1.0f / (1.0f + expf(-(la - shift)));
            if (m > 0.0f) { wc[k] = make_float2(m, i_as_f(c)); ++k; }
        }
        endc[r] = k;
        dis[r] = fminf(1.0f / sqrtf(rs + 1e-6f), 10.0f);
    }

    __shared__ float red[256];
    red[threadIdx.x] = l0local;
    __syncthreads();
    for (int s = 128; s > 0; s >>= 1) {
        if (threadIdx.x < s) red[threadIdx.x] += red[threadIdx.x + s];
        __syncthreads();
    }
    if (threadIdx.x == 0) unsafeAtomicAdd(l0_accum, red[0]);
}

// ---------------------------------------------------------------------------
// Edge gather (compacted, branch-free): unconditional row loads pipeline.
// ---------------------------------------------------------------------------
__global__ void edge_gather_kernel(const float2* __restrict__ wc, const int* __restrict__ start,
                                   const int* __restrict__ endc,
                                   const float* __restrict__ dis,
                                   const unsigned short* __restrict__ xb,
                                   unsigned short* __restrict__ xnb, int nNodes)
{
    const int lane   = threadIdx.x & 63;
    const int wave   = (blockIdx.x * blockDim.x + threadIdx.x) >> 6;
    const int nWaves = (gridDim.x * blockDim.x) >> 6;

    for (int r = wave; r < nNodes; r += nWaves) {
        const int ru = __builtin_amdgcn_readfirstlane(r);
        int js = __builtin_amdgcn_readfirstlane(start[ru]);
        int je = __builtin_amdgcn_readfirstlane(endc[ru]);
        float acc = 0.0f;
        int j = js;
        for (; j + 4 <= je; j += 4) {
            float2 w0 = wc[j], w1 = wc[j + 1], w2 = wc[j + 2], w3 = wc[j + 3];
            int c0 = f_as_i(w0.y), c1 = f_as_i(w1.y), c2 = f_as_i(w2.y), c3 = f_as_i(w3.y);
            float s0 = w0.x * dis[c0], s1 = w1.x * dis[c1];
            float s2 = w2.x * dis[c2], s3 = w3.x * dis[c3];
            float x0 = b2f(xb[(size_t)c0 * 64 + lane]);
            float x1 = b2f(xb[(size_t)c1 * 64 + lane]);
            float x2 = b2f(xb[(size_t)c2 * 64 + lane]);
            float x3 = b2f(xb[(size_t)c3 * 64 + lane]);
            acc = fmaf(s0, x0, acc);
            acc = fmaf(s1, x1, acc);
            acc = fmaf(s2, x2, acc);
            acc = fmaf(s3, x3, acc);
        }
        for (; j < je; ++j) {
            float2 w = wc[j];
            int c = f_as_i(w.y);
            acc = fmaf(w.x * dis[c], b2f(xb[(size_t)c * 64 + lane]), acc);
        }
        xnb[(size_t)ru * 64 + lane] = f2b(acc * dis[ru]);
    }
}

// ---------------------------------------------------------------------------
// BPR loss: xs = features(f32) + x1(bf16) + x2(bf16)
// ---------------------------------------------------------------------------
__global__ void bpr_kernel(const float* __restrict__ f,
                           const unsigned short* __restrict__ x1b,
                           const unsigned short* __restrict__ x2b,
                           const int* __restrict__ users, const int* __restrict__ items,
                           const int* __restrict__ negs,
                           float* __restrict__ bpr_accum, int B)
{
    const int lane   = threadIdx.x & 63;
    const int wave   = (blockIdx.x * blockDim.x + threadIdx.x) >> 6;
    const int nWaves = (gridDim.x * blockDim.x) >> 6;

    float local = 0.0f;
    for (int b = wave; b < B; b += nWaves) {
        size_t ui = (size_t)users[b] * 64 + lane;
        size_t pi = (size_t)(N_USER + items[b]) * 64 + lane;
        size_t ni = (size_t)(N_USER + negs[b]) * 64 + lane;
        float a = f[ui] + b2f(x1b[ui]) + b2f(x2b[ui]);
        float p = f[pi] + b2f(x1b[pi]) + b2f(x2b[pi]);
        float n = f[ni] + b2f(x1b[ni]) + b2f(x2b[ni]);
        float ps = a * p, ns = a * n;
        #pragma unroll
        for (int off = 32; off; off >>= 1) {
            ps += __shfl_xor(ps, off);
            ns += __shfl_xor(ns, off);
        }
        if (lane == 0) {
            float s = 1.0f / (1.0f + expf(-(ps - ns)));
            local += -logf(s + 1e-5f);
        }
    }
    if (lane == 0) unsafeAtomicAdd(bpr_accum, local);
}

// ---------------------------------------------------------------------------
// L2 regularization on params
// ---------------------------------------------------------------------------
__global__ void reg_kernel(const float* __restrict__ w0, const float* __restrict__ b0,
                           const float* __restrict__ w1, const float* __restrict__ b1,
                           const float* __restrict__ wa0, const float* __restrict__ ba0,
                           const float* __restrict__ w2, const float* __restrict__ b2,
                           const float* __restrict__ w3, const float* __restrict__ b3,
                           const float* __restrict__ wa1, const float* __restrict__ ba1,
                           float* __restrict__ accum)
{
    int t = threadIdx.x;
    float s = 0.0f;
    for (int i = t; i < 4096; i += 256)
        s += w0[i]*w0[i] + w1[i]*w1[i] + w2[i]*w2[i] + w3[i]*w3[i];
    for (int i = t; i < 64; i += 256)
        s += b0[i]*b0[i] + b1[i]*b1[i] + b2[i]*b2[i] + b3[i]*b3[i];
    for (int i = t; i < 128; i += 256)
        s += wa0[i]*wa0[i] + wa1[i]*wa1[i];
    if (t == 0) s += ba0[0]*ba0[0] + ba1[0]*ba1[0];

    __shared__ float red[256];
    red[t] = s;
    __syncthreads();
    for (int st = 128; st > 0; st >>= 1) {
        if (t < st) red[t] += red[t + st];
        __syncthreads();
    }
    if (t == 0) accum[0] = red[0];
}

__global__ void finalize_kernel(const float* __restrict__ scal, float* __restrict__ out)
{
    float bpr = scal[0] / (float)B_TOT;
    float reg = scal[1] * 1e-4f;
    float l0  = (scal[2] + scal[3]) * (1e-4f / (float)E_TOT);
    out[0] = bpr + reg + l0;
}

extern "C" void kernel_launch(void* const* d_in, const int* in_sizes, int n_in,
                              void* d_out, int out_size, void* d_ws, size_t ws_size,
                              hipStream_t stream)
{
    const float* features = (const float*)d_in[0];
    const int*   row      = (const int*)d_in[1];
    const int*   col      = (const int*)d_in[2];
    const int*   users    = (const int*)d_in[3];
    const int*   items    = (const int*)d_in[4];
    const int*   negs     = (const int*)d_in[5];
    const float* u0       = (const float*)d_in[6];
    const float* u1       = (const float*)d_in[7];
    const float* temp     = (const float*)d_in[8];
    const float* W_nb0    = (const float*)d_in[9];
    const float* b_nb0    = (const float*)d_in[10];
    const float* W_self0  = (const float*)d_in[11];
    const float* b_self0  = (const float*)d_in[12];
    const float* W_att0   = (const float*)d_in[13];
    const float* b_att0   = (const float*)d_in[14];
    const float* W_nb1    = (const float*)d_in[15];
    const float* b_nb1    = (const float*)d_in[16];
    const float* W_self1  = (const float*)d_in[17];
    const float* b_self1  = (const float*)d_in[18];
    const float* W_att1   = (const float*)d_in[19];
    const float* b_att1   = (const float*)d_in[20];
    float* out = (float*)d_out;

    // ---- Workspace layout (4B element offsets), ~96 MB total ----
    float* ws = (float*)d_ws;
    unsigned short* fb  = (unsigned short*)ws;               // N*64 bf16
    unsigned short* x1b = (unsigned short*)(ws + 4800000);   // N*64 bf16
    unsigned short* x2b = (unsigned short*)(ws + 9600000);   // N*64 bf16
    // zeroed block: scal + bcnt
    float* scal  = ws + 14400000;                 // 16
    int*   bcnt  = (int*)(scal + 16);             // NBKT (pad 160)
    // end zeroed block
    int*   bbase = bcnt + 160;                    // NBKT+1 (pad 160)
    int*   start = bbase + 160;                   // NSCAN_PAD
    int4*  tmp   = (int4*)(start + NSCAN_PAD);    // NBKT*BKT_CAP int4 (19.3MB), 16B-aligned
    float2* wc   = (float2*)tmp;                  // ALIAS: E float2 (8MB) — tmp dead after scatter2
    int4*  rec   = tmp + (size_t)NBKT * BKT_CAP;  // E int4 (16MB)
    int*   endc  = (int*)(rec + E_TOT);           // N_TOT
    float* dis   = (float*)(endc + N_TOT);        // N_TOT
    float* a_nb  = dis + N_TOT;                   // N_TOT
    float* a_self= a_nb + N_TOT;                  // N_TOT
    unsigned short* wpk =
        (unsigned short*)(((uintptr_t)(a_self + N_TOT) + 15) & ~(uintptr_t)15);  // 32KB

    hipMemsetAsync(scal, 0, (16 + 160) * sizeof(float), stream);

    const int nNodeBlocks = (N_TOT + 255) / 256;   // 586
    const int nMfmaBlocks = (N_TOT / 16 + 3) / 4;  // 2344

    // ---- features -> bf16, weights -> packed bf16 frags ----
    tobf16_kernel<<<1024, 256, 0, stream>>>((const float4*)features, (ushort4*)fb, N_TOT * 16);
    wpack_kernel<<<8, 256, 0, stream>>>(W_nb0, W_self0, W_nb1, W_self1, wpk);

    // ---- CSR build: bin (carrying col+u0+u1) -> bucket scan -> counting-sort ----
    bin_kernel<<<NBIN_BLOCKS, 256, 0, stream>>>(row, col, u0, u1, bcnt, tmp, E_TOT);
    bucket_scan_kernel<<<1, 256, 0, stream>>>(bcnt, bbase, start);
    scatter2_kernel<<<NBKT, 256, 0, stream>>>(tmp, bcnt, bbase, start, rec);

    // ---- Layer 0 ----
    node_scalars_mfma_kernel<<<nMfmaBlocks, 256, 0, stream>>>(fb, wpk, b_nb0, b_self0, W_att0,
                                                              a_nb, a_self, N_TOT);
    edge_pass_a_kernel<<<nNodeBlocks, 256, 0, stream>>>(rec, start, 0, a_nb, a_self,
                                                        b_att0, temp, wc, endc, dis,
                                                        &scal[2], N_TOT);
    edge_gather_kernel<<<2048, 256, 0, stream>>>(wc, start, endc, dis, fb, x1b, N_TOT);

    // ---- Layer 1 ----
    node_scalars_mfma_kernel<<<nMfmaBlocks, 256, 0, stream>>>(x1b, wpk + 8192, b_nb1, b_self1,
                                                              W_att1, a_nb, a_self, N_TOT);
    edge_pass_a_kernel<<<nNodeBlocks, 256, 0, stream>>>(rec, start, 1, a_nb, a_self,
                                                        b_att1, temp, wc, endc, dis,
                                                        &scal[3], N_TOT);
    edge_gather_kernel<<<2048, 256, 0, stream>>>(wc, start, endc, dis, x1b, x2b, N_TOT);

    // ---- Losses ----
    bpr_kernel<<<64, 256, 0, stream>>>(features, x1b, x2b, users, items, negs, &scal[0], B_TOT);
    reg_kernel<<<1, 256, 0, stream>>>(W_nb0, b_nb0, W_self0, b_self0, W_att0, b_att0,
                                      W_nb1, b_nb1, W_self1, b_self1, W_att1, b_att1, &scal[1]);
    finalize_kernel<<<1, 1, 0, stream>>>(scal, out);
}

// Round 12
// 231.820 us; speedup vs baseline: 1.6947x; 1.0917x over previous
//
#include <hip/hip_runtime.h>
#include <hip/hip_bf16.h>

#define N_TOT   150000
#define N_USER  100000
#define E_TOT   1000000
#define B_TOT   4096
#define D_DIM   64

#define NSCAN_PAD   150016          // N_TOT+1 rounded up to multiple of 8
#define BKT_SHIFT   10
#define BKT_ROWS    (1 << BKT_SHIFT)                 // 1024 rows per bucket
#define NBKT        ((N_TOT + BKT_ROWS - 1) / BKT_ROWS)   // 147
#define BKT_CAP     8192
#define BIN_CHUNK   4096
#define NBIN_BLOCKS ((E_TOT + BIN_CHUNK - 1) / BIN_CHUNK) // 245

typedef short short8v  __attribute__((ext_vector_type(8)));
typedef float float4v  __attribute__((ext_vector_type(4)));

// ---- bf16 helpers (bit ops; accumulation always f32) ----
__device__ __forceinline__ float b2f(unsigned int lo16)
{
    union { unsigned int u; float f; } c; c.u = lo16 << 16; return c.f;
}
__device__ __forceinline__ unsigned short f2b(float f)
{
    union { float f; unsigned int u; } c; c.f = f;
    unsigned int u = c.u + 0x7FFFu + ((c.u >> 16) & 1u);   // RNE
    return (unsigned short)(u >> 16);
}
__device__ __forceinline__ int   f_as_i(float f) { union { float f; int i; } c; c.f = f; return c.i; }
__device__ __forceinline__ float i_as_f(int i)   { union { int i; float f; } c; c.i = i; return c.f; }

// ---------------------------------------------------------------------------
// features f32 -> bf16
// ---------------------------------------------------------------------------
__global__ void tobf16_kernel(const float4* __restrict__ in, ushort4* __restrict__ out, int n4)
{
    for (int i = blockIdx.x * blockDim.x + threadIdx.x; i < n4; i += gridDim.x * blockDim.x) {
        float4 v = in[i];
        ushort4 o;
        o.x = f2b(v.x); o.y = f2b(v.y); o.z = f2b(v.z); o.w = f2b(v.w);
        out[i] = o;
    }
}

// ---------------------------------------------------------------------------
// Pack the 4 weight matrices into MFMA B-fragment order, bf16:
// wpk[m][kb][nt][lane][j] = W_m[32*kb + (lane>>4)*8 + j][16*nt + (lane&15)]
// ---------------------------------------------------------------------------
__global__ void wpack_kernel(const float* __restrict__ Wn0, const float* __restrict__ Ws0,
                             const float* __restrict__ Wn1, const float* __restrict__ Ws1,
                             unsigned short* __restrict__ wpk)
{
    int f = blockIdx.x * blockDim.x + threadIdx.x;   // [0, 2048)
    if (f >= 2048) return;
    const float* W[4] = {Wn0, Ws0, Wn1, Ws1};
    int m   = f >> 9;
    int rem = f & 511;
    int kb  = rem >> 8;
    int nt  = (rem >> 6) & 3;
    int l   = rem & 63;
    const float* Wm = W[m];
    int kbase = 32 * kb + ((l >> 4) << 3);
    int n     = 16 * nt + (l & 15);
    unsigned short o[8];
    #pragma unroll
    for (int j = 0; j < 8; ++j) o[j] = f2b(Wm[(kbase + j) * 64 + n]);
    ushort4* dst = (ushort4*)(wpk + (size_t)f * 8);
    dst[0] = make_ushort4(o[0], o[1], o[2], o[3]);
    dst[1] = make_ushort4(o[4], o[5], o[6], o[7]);
}

// ---------------------------------------------------------------------------
// Node scalars via MFMA: one wave per 16 nodes.
// ---------------------------------------------------------------------------
__global__ __launch_bounds__(256)
void node_scalars_mfma_kernel(const unsigned short* __restrict__ xb,
                              const unsigned short* __restrict__ wpack, // [2][2][4][64][8]
                              const float* __restrict__ bn, const float* __restrict__ bs,
                              const float* __restrict__ Wa,
                              float* __restrict__ a_nb, float* __restrict__ a_self,
                              int nNodes)
{
    const int lane = threadIdx.x & 63;
    const int wid  = (blockIdx.x * blockDim.x + threadIdx.x) >> 6;
    const int nodeBase = wid * 16;
    if (nodeBase >= nNodes) return;

    short8v bfrag[2][2][4];
    #pragma unroll
    for (int m = 0; m < 2; ++m)
        #pragma unroll
        for (int kb = 0; kb < 2; ++kb)
            #pragma unroll
            for (int nt = 0; nt < 4; ++nt)
                bfrag[m][kb][nt] =
                    *(const short8v*)(wpack + (size_t)((((m * 2 + kb) * 4 + nt) * 64 + lane)) * 8);

    const size_t rowOff = (size_t)(nodeBase + (lane & 15)) * 64 + ((lane >> 4) << 3);
    short8v a0 = *(const short8v*)(xb + rowOff);
    short8v a1 = *(const short8v*)(xb + rowOff + 32);

    float4v acc[2][4];
    #pragma unroll
    for (int m = 0; m < 2; ++m)
        #pragma unroll
        for (int nt = 0; nt < 4; ++nt) {
            float4v z = {0.f, 0.f, 0.f, 0.f};
            z = __builtin_amdgcn_mfma_f32_16x16x32_bf16(a0, bfrag[m][0][nt], z, 0, 0, 0);
            z = __builtin_amdgcn_mfma_f32_16x16x32_bf16(a1, bfrag[m][1][nt], z, 0, 0, 0);
            acc[m][nt] = z;
        }

    const int j = lane & 15;
    float pn[4] = {0.f, 0.f, 0.f, 0.f};
    float ps[4] = {0.f, 0.f, 0.f, 0.f};
    #pragma unroll
    for (int nt = 0; nt < 4; ++nt) {
        float bnv = bn[nt * 16 + j], bsv = bs[nt * 16 + j];
        float wan = Wa[nt * 16 + j], was = Wa[64 + nt * 16 + j];
        #pragma unroll
        for (int r = 0; r < 4; ++r) {
            pn[r] = fmaf(fmaxf(acc[0][nt][r] + bnv, 0.f), wan, pn[r]);
            ps[r] = fmaf(fmaxf(acc[1][nt][r] + bsv, 0.f), was, ps[r]);
        }
    }
    #pragma unroll
    for (int off = 1; off < 16; off <<= 1) {
        #pragma unroll
        for (int r = 0; r < 4; ++r) {
            pn[r] += __shfl_xor(pn[r], off);
            ps[r] += __shfl_xor(ps[r], off);
        }
    }
    if (j == 0) {
        const int g = lane >> 4;
        #pragma unroll
        for (int r = 0; r < 4; ++r) {
            int node = nodeBase + g * 4 + r;
            a_nb[node]   = pn[r];
            a_self[node] = ps[r];
        }
    }
}

// ---------------------------------------------------------------------------
// Phase 1: bin edges into NBKT coarse buckets, carrying {row, col, u0, u1}.
// ---------------------------------------------------------------------------
__global__ __launch_bounds__(256)
void bin_kernel(const int* __restrict__ row, const int* __restrict__ col,
                const float* __restrict__ u0, const float* __restrict__ u1,
                int* __restrict__ bcnt, int4* __restrict__ tmp, int nE)
{
    __shared__ int cnt[NBKT];
    __shared__ int base[NBKT];
    for (int i = threadIdx.x; i < NBKT; i += 256) cnt[i] = 0;
    __syncthreads();

    const int e0 = blockIdx.x * BIN_CHUNK + threadIdx.x;
    int r[16], c[16], ua[16], ub[16];
    #pragma unroll
    for (int k = 0; k < 16; ++k) {
        int e = e0 + k * 256;
        r[k] = (e < nE) ? row[e] : -1;
        if (r[k] >= 0) {
            c[k]  = col[e];
            ua[k] = f_as_i(u0[e]);
            ub[k] = f_as_i(u1[e]);
            atomicAdd(&cnt[r[k] >> BKT_SHIFT], 1);
        }
    }
    __syncthreads();

    for (int i = threadIdx.x; i < NBKT; i += 256) {
        int cc = cnt[i];
        base[i] = cc ? atomicAdd(&bcnt[i], cc) : 0;
        cnt[i] = 0;
    }
    __syncthreads();

    #pragma unroll
    for (int k = 0; k < 16; ++k) {
        if (r[k] >= 0) {
            int b   = r[k] >> BKT_SHIFT;
            int loc = atomicAdd(&cnt[b], 1);
            tmp[(size_t)b * BKT_CAP + base[b] + loc] = make_int4(r[k], c[k], ua[k], ub[k]);
        }
    }
}

__global__ void bucket_scan_kernel(const int* __restrict__ bcnt, int* __restrict__ bbase,
                                   int* __restrict__ start)
{
    __shared__ int sh[256];
    int t = threadIdx.x;
    int v = (t < NBKT) ? bcnt[t] : 0;
    sh[t] = v;
    __syncthreads();
    for (int off = 1; off < 256; off <<= 1) {
        int x = sh[t];
        if (t >= off) x += sh[t - off];
        __syncthreads();
        sh[t] = x;
        __syncthreads();
    }
    if (t <= NBKT) bbase[t] = (t == 0) ? 0 : sh[t - 1];
    if (t == 0) start[N_TOT] = E_TOT;
}

// ---------------------------------------------------------------------------
// Phase 2: one block per bucket; LDS counting-sort -> start[] + CSR rec[].
// ---------------------------------------------------------------------------
__global__ __launch_bounds__(256)
void scatter2_kernel(const int4* __restrict__ tmp, const int* __restrict__ bcnt,
                     const int* __restrict__ bbase,
                     int* __restrict__ start, int4* __restrict__ rec)
{
    __shared__ int pref[BKT_ROWS];
    __shared__ int wsum[256];

    const int b     = blockIdx.x;
    const int rlo   = b << BKT_SHIFT;
    const int nrows = min(BKT_ROWS, N_TOT - rlo);
    const int cntb  = bcnt[b];
    const int baseb = bbase[b];
    const int t     = threadIdx.x;
    const int4* __restrict__ bkt = tmp + (size_t)b * BKT_CAP;

    for (int i = t; i < BKT_ROWS; i += 256) pref[i] = 0;
    __syncthreads();

    for (int j = t; j < cntb; j += 256)
        atomicAdd(&pref[bkt[j].x - rlo], 1);
    __syncthreads();

    const int base4 = t * 4;
    int v0 = pref[base4], v1 = pref[base4 + 1], v2 = pref[base4 + 2], v3 = pref[base4 + 3];
    int s = v0 + v1 + v2 + v3;
    wsum[t] = s;
    __syncthreads();
    for (int off = 1; off < 256; off <<= 1) {
        int x = wsum[t];
        if (t >= off) x += wsum[t - off];
        __syncthreads();
        wsum[t] = x;
        __syncthreads();
    }
    const int pre = wsum[t] - s;
    const int p0 = pre, p1 = pre + v0, p2 = pre + v0 + v1, p3 = pre + v0 + v1 + v2;

    if (base4     < nrows) start[rlo + base4]     = baseb + p0;
    if (base4 + 1 < nrows) start[rlo + base4 + 1] = baseb + p1;
    if (base4 + 2 < nrows) start[rlo + base4 + 2] = baseb + p2;
    if (base4 + 3 < nrows) start[rlo + base4 + 3] = baseb + p3;

    pref[base4] = p0; pref[base4 + 1] = p1; pref[base4 + 2] = p2; pref[base4 + 3] = p3;
    __syncthreads();

    for (int j = t; j < cntb; j += 256) {
        int4 q  = bkt[j];
        int loc = atomicAdd(&pref[q.x - rlo], 1);
        rec[baseb + loc] = make_int4(q.y, q.z, q.w, 0);
    }
}

// ---------------------------------------------------------------------------
// Edge pass A, node-parallel, fully sequential reads of rec {col,u0,u1}.
// Writes COMPACTED {m, col} records (only m>0) + fused int2 range + dis.
// ---------------------------------------------------------------------------
__global__ __launch_bounds__(256)
void edge_pass_a_kernel(const int4* __restrict__ rec, const int* __restrict__ start,
                        const int uSel,
                        const float* __restrict__ a_nb, const float* __restrict__ a_self,
                        const float* __restrict__ ba_p, const float* __restrict__ temp_p,
                        float2* __restrict__ wc, int2* __restrict__ range,
                        float* __restrict__ dis,
                        float* __restrict__ l0_accum, int nNodes)
{
    const float ba   = ba_p[0];
    const float t    = temp_p[0];
    const float invt = 1.0f / t;
    const float lt   = logf(0.45f / 1.05f);   // log(-GAMMA/ZETA)
    const float shift = t * lt;

    const int r = blockIdx.x * 256 + threadIdx.x;
    float l0local = 0.0f;

    if (r < nNodes) {
        const int js = start[r], je = start[r + 1];
        const float la_base = a_nb[r] + ba;
        float rs = 0.0f;
        int k = js;
        for (int j = js; j < je; ++j) {
            int4 q = rec[j];                     // {col, u0, u1, -}
            int c = q.x;
            float la = la_base + a_self[c];
            float uu = i_as_f(uSel ? q.z : q.y);
            float noise = logf(uu) - log1pf(-uu);
            float gate  = 1.0f / (1.0f + expf(-(noise + la) * invt));
            float m = fminf(fmaxf(gate * 1.5f - 0.45f, 0.0f), 1.0f);
            rs += m;
            l0local += 1.0f / (1.0f + expf(-(la - shift)));
            if (m > 0.0f) { wc[k] = make_float2(m, i_as_f(c)); ++k; }
        }
        range[r] = make_int2(js, k);
        dis[r] = fminf(1.0f / sqrtf(rs + 1e-6f), 10.0f);
    }

    __shared__ float red[256];
    red[threadIdx.x] = l0local;
    __syncthreads();
    for (int s = 128; s > 0; s >>= 1) {
        if (threadIdx.x < s) red[threadIdx.x] += red[threadIdx.x + s];
        __syncthreads();
    }
    if (threadIdx.x == 0) unsafeAtomicAdd(l0_accum, red[0]);
}

// ---------------------------------------------------------------------------
// Edge gather v3: HALF-WAVE per node, ushort2 (2 dims) per lane.
// - one x-load instruction fetches TWO rows (256B)
// - two independent per-node chains per wave (double MLP)
// - rows 2p,2p+1 adjacent -> one contiguous 256B output store
// ---------------------------------------------------------------------------
__global__ void edge_gather_kernel(const float2* __restrict__ wc, const int2* __restrict__ range,
                                   const float* __restrict__ dis,
                                   const unsigned short* __restrict__ xb,
                                   unsigned short* __restrict__ xnb, int nNodes)
{
    const int lane = threadIdx.x & 63;
    const int half = lane >> 5;
    const int sub  = lane & 31;
    const int wave   = (blockIdx.x * blockDim.x + threadIdx.x) >> 6;
    const int nWaves = (gridDim.x * blockDim.x) >> 6;
    const int nPairs = (nNodes + 1) >> 1;

    for (int p = wave; p < nPairs; p += nWaves) {
        const int r = 2 * p + half;
        const bool valid = r < nNodes;
        const int rr = valid ? r : nNodes - 1;
        int2 rg  = range[rr];
        float dr = dis[rr];
        int j  = rg.x;
        int je = valid ? rg.y : rg.x;
        float ax = 0.0f, ay = 0.0f;
        for (; j + 2 <= je; j += 2) {
            float2 w0 = wc[j], w1 = wc[j + 1];
            int c0 = f_as_i(w0.y), c1 = f_as_i(w1.y);
            float s0 = w0.x * dis[c0], s1 = w1.x * dis[c1];
            unsigned int q0 = *(const unsigned int*)(xb + (size_t)c0 * 64 + sub * 2);
            unsigned int q1 = *(const unsigned int*)(xb + (size_t)c1 * 64 + sub * 2);
            ax = fmaf(s0, b2f(q0 & 0xFFFFu), ax);
            ay = fmaf(s0, b2f(q0 >> 16),     ay);
            ax = fmaf(s1, b2f(q1 & 0xFFFFu), ax);
            ay = fmaf(s1, b2f(q1 >> 16),     ay);
        }
        if (j < je) {
            float2 w0 = wc[j];
            int c0 = f_as_i(w0.y);
            float s0 = w0.x * dis[c0];
            unsigned int q0 = *(const unsigned int*)(xb + (size_t)c0 * 64 + sub * 2);
            ax = fmaf(s0, b2f(q0 & 0xFFFFu), ax);
            ay = fmaf(s0, b2f(q0 >> 16),     ay);
        }
        if (valid) {
            unsigned int o = ((unsigned int)f2b(ay * dr) << 16) | (unsigned int)f2b(ax * dr);
            *(unsigned int*)(xnb + (size_t)r * 64 + sub * 2) = o;
        }
    }
}

// ---------------------------------------------------------------------------
// BPR loss: xs = features(f32) + x1(bf16) + x2(bf16)
// ---------------------------------------------------------------------------
__global__ void bpr_kernel(const float* __restrict__ f,
                           const unsigned short* __restrict__ x1b,
                           const unsigned short* __restrict__ x2b,
                           const int* __restrict__ users, const int* __restrict__ items,
                           const int* __restrict__ negs,
                           float* __restrict__ bpr_accum, int B)
{
    const int lane   = threadIdx.x & 63;
    const int wave   = (blockIdx.x * blockDim.x + threadIdx.x) >> 6;
    const int nWaves = (gridDim.x * blockDim.x) >> 6;

    float local = 0.0f;
    for (int b = wave; b < B; b += nWaves) {
        size_t ui = (size_t)users[b] * 64 + lane;
        size_t pi = (size_t)(N_USER + items[b]) * 64 + lane;
        size_t ni = (size_t)(N_USER + negs[b]) * 64 + lane;
        float a = f[ui] + b2f(x1b[ui]) + b2f(x2b[ui]);
        float p = f[pi] + b2f(x1b[pi]) + b2f(x2b[pi]);
        float n = f[ni] + b2f(x1b[ni]) + b2f(x2b[ni]);
        float ps = a * p, ns = a * n;
        #pragma unroll
        for (int off = 32; off; off >>= 1) {
            ps += __shfl_xor(ps, off);
            ns += __shfl_xor(ns, off);
        }
        if (lane == 0) {
            float s = 1.0f / (1.0f + expf(-(ps - ns)));
            local += -logf(s + 1e-5f);
        }
    }
    if (lane == 0) unsafeAtomicAdd(bpr_accum, local);
}

// ---------------------------------------------------------------------------
// L2 regularization on params
// ---------------------------------------------------------------------------
__global__ void reg_kernel(const float* __restrict__ w0, const float* __restrict__ b0,
                           const float* __restrict__ w1, const float* __restrict__ b1,
                           const float* __restrict__ wa0, const float* __restrict__ ba0,
                           const float* __restrict__ w2, const float* __restrict__ b2,
                           const float* __restrict__ w3, const float* __restrict__ b3,
                           const float* __restrict__ wa1, const float* __restrict__ ba1,
                           float* __restrict__ accum)
{
    int t = threadIdx.x;
    float s = 0.0f;
    for (int i = t; i < 4096; i += 256)
        s += w0[i]*w0[i] + w1[i]*w1[i] + w2[i]*w2[i] + w3[i]*w3[i];
    for (int i = t; i < 64; i += 256)
        s += b0[i]*b0[i] + b1[i]*b1[i] + b2[i]*b2[i] + b3[i]*b3[i];
    for (int i = t; i < 128; i += 256)
        s += wa0[i]*wa0[i] + wa1[i]*wa1[i];
    if (t == 0) s += ba0[0]*ba0[0] + ba1[0]*ba1[0];

    __shared__ float red[256];
    red[t] = s;
    __syncthreads();
    for (int st = 128; st > 0; st >>= 1) {
        if (t < st) red[t] += red[t + st];
        __syncthreads();
    }
    if (t == 0) accum[0] = red[0];
}

__global__ void finalize_kernel(const float* __restrict__ scal, float* __restrict__ out)
{
    float bpr = scal[0] / (float)B_TOT;
    float reg = scal[1] * 1e-4f;
    float l0  = (scal[2] + scal[3]) * (1e-4f / (float)E_TOT);
    out[0] = bpr + reg + l0;
}

extern "C" void kernel_launch(void* const* d_in, const int* in_sizes, int n_in,
                              void* d_out, int out_size, void* d_ws, size_t ws_size,
                              hipStream_t stream)
{
    const float* features = (const float*)d_in[0];
    const int*   row      = (const int*)d_in[1];
    const int*   col      = (const int*)d_in[2];
    const int*   users    = (const int*)d_in[3];
    const int*   items    = (const int*)d_in[4];
    const int*   negs     = (const int*)d_in[5];
    const float* u0       = (const float*)d_in[6];
    const float* u1       = (const float*)d_in[7];
    const float* temp     = (const float*)d_in[8];
    const float* W_nb0    = (const float*)d_in[9];
    const float* b_nb0    = (const float*)d_in[10];
    const float* W_self0  = (const float*)d_in[11];
    const float* b_self0  = (const float*)d_in[12];
    const float* W_att0   = (const float*)d_in[13];
    const float* b_att0   = (const float*)d_in[14];
    const float* W_nb1    = (const float*)d_in[15];
    const float* b_nb1    = (const float*)d_in[16];
    const float* W_self1  = (const float*)d_in[17];
    const float* b_self1  = (const float*)d_in[18];
    const float* W_att1   = (const float*)d_in[19];
    const float* b_att1   = (const float*)d_in[20];
    float* out = (float*)d_out;

    // ---- Workspace layout (4B element offsets), ~97 MB total ----
    float* ws = (float*)d_ws;
    unsigned short* fb  = (unsigned short*)ws;               // N*64 bf16
    unsigned short* x1b = (unsigned short*)(ws + 4800000);   // N*64 bf16
    unsigned short* x2b = (unsigned short*)(ws + 9600000);   // N*64 bf16
    // zeroed block: scal + bcnt
    float* scal  = ws + 14400000;                 // 16
    int*   bcnt  = (int*)(scal + 16);             // NBKT (pad 160)
    // end zeroed block
    int*   bbase = bcnt + 160;                    // NBKT+1 (pad 160)
    int*   start = bbase + 160;                   // NSCAN_PAD
    int4*  tmp   = (int4*)(start + NSCAN_PAD);    // NBKT*BKT_CAP int4 (19.3MB), 16B-aligned
    float2* wc   = (float2*)tmp;                  // ALIAS: E float2 (8MB) — tmp dead after scatter2
    int4*  rec   = tmp + (size_t)NBKT * BKT_CAP;  // E int4 (16MB)
    int2*  range = (int2*)(rec + E_TOT);          // N_TOT int2
    float* dis   = (float*)(range + N_TOT);       // N_TOT
    float* a_nb  = dis + N_TOT;                   // N_TOT
    float* a_self= a_nb + N_TOT;                  // N_TOT
    unsigned short* wpk =
        (unsigned short*)(((uintptr_t)(a_self + N_TOT) + 15) & ~(uintptr_t)15);  // 32KB

    hipMemsetAsync(scal, 0, (16 + 160) * sizeof(float), stream);

    const int nNodeBlocks = (N_TOT + 255) / 256;   // 586
    const int nMfmaBlocks = (N_TOT / 16 + 3) / 4;  // 2344

    // ---- features -> bf16, weights -> packed bf16 frags ----
    tobf16_kernel<<<1024, 256, 0, stream>>>((const float4*)features, (ushort4*)fb, N_TOT * 16);
    wpack_kernel<<<8, 256, 0, stream>>>(W_nb0, W_self0, W_nb1, W_self1, wpk);

    // ---- CSR build: bin (carrying col+u0+u1) -> bucket scan -> counting-sort ----
    bin_kernel<<<NBIN_BLOCKS, 256, 0, stream>>>(row, col, u0, u1, bcnt, tmp, E_TOT);
    bucket_scan_kernel<<<1, 256, 0, stream>>>(bcnt, bbase, start);
    scatter2_kernel<<<NBKT, 256, 0, stream>>>(tmp, bcnt, bbase, start, rec);

    // ---- Layer 0 ----
    node_scalars_mfma_kernel<<<nMfmaBlocks, 256, 0, stream>>>(fb, wpk, b_nb0, b_self0, W_att0,
                                                              a_nb, a_self, N_TOT);
    edge_pass_a_kernel<<<nNodeBlocks, 256, 0, stream>>>(rec, start, 0, a_nb, a_self,
                                                        b_att0, temp, wc, range, dis,
                                                        &scal[2], N_TOT);
    edge_gather_kernel<<<2048, 256, 0, stream>>>(wc, range, dis, fb, x1b, N_TOT);

    // ---- Layer 1 ----
    node_scalars_mfma_kernel<<<nMfmaBlocks, 256, 0, stream>>>(x1b, wpk + 8192, b_nb1, b_self1,
                                                              W_att1, a_nb, a_self, N_TOT);
    edge_pass_a_kernel<<<nNodeBlocks, 256, 0, stream>>>(rec, start, 1, a_nb, a_self,
                                                        b_att1, temp, wc, range, dis,
                                                        &scal[3], N_TOT);
    edge_gather_kernel<<<2048, 256, 0, stream>>>(wc, range, dis, x1b, x2b, N_TOT);

    // ---- Losses ----
    bpr_kernel<<<64, 256, 0, stream>>>(features, x1b, x2b, users, items, negs, &scal[0], B_TOT);
    reg_kernel<<<1, 256, 0, stream>>>(W_nb0, b_nb0, W_self0, b_self0, W_att0, b_att0,
                                      W_nb1, b_nb1, W_self1, b_self1, W_att1, b_att1, &scal[1]);
    finalize_kernel<<<1, 1, 0, stream>>>(scal, out);
}

// Round 13
// 206.935 us; speedup vs baseline: 1.8985x; 1.1203x over previous
//
#include <hip/hip_runtime.h>
#include <hip/hip_bf16.h>

#define N_TOT   150000
#define N_USER  100000
#define E_TOT   1000000
#define B_TOT   4096
#define D_DIM   64

#define NSCAN_PAD   150016          // N_TOT+1 rounded up to multiple of 8
#define BKT_SHIFT   10
#define BKT_ROWS    (1 << BKT_SHIFT)                 // 1024 rows per bucket
#define NBKT        ((N_TOT + BKT_ROWS - 1) / BKT_ROWS)   // 147
#define BKT_CAP     8192
#define BIN_CHUNK   4096
#define NBIN_BLOCKS ((E_TOT + BIN_CHUNK - 1) / BIN_CHUNK) // 245

typedef short short8v  __attribute__((ext_vector_type(8)));
typedef float float4v  __attribute__((ext_vector_type(4)));

// ---- bf16 / f16 helpers (bit ops; accumulation always f32) ----
__device__ __forceinline__ float b2f(unsigned int lo16)
{
    union { unsigned int u; float f; } c; c.u = lo16 << 16; return c.f;
}
__device__ __forceinline__ unsigned short f2b(float f)
{
    union { float f; unsigned int u; } c; c.f = f;
    unsigned int u = c.u + 0x7FFFu + ((c.u >> 16) & 1u);   // RNE
    return (unsigned short)(u >> 16);
}
__device__ __forceinline__ unsigned short f2h(float f)
{
    union { _Float16 h; unsigned short u; } c; c.h = (_Float16)f; return c.u;
}
__device__ __forceinline__ float h2f(unsigned short u)
{
    union { unsigned short u; _Float16 h; } c; c.u = u; return (float)c.h;
}
__device__ __forceinline__ int   f_as_i(float f) { union { float f; int i; } c; c.f = f; return c.i; }
__device__ __forceinline__ float i_as_f(int i)   { union { int i; float f; } c; c.i = i; return c.f; }

// ---------------------------------------------------------------------------
// features f32 -> bf16
// ---------------------------------------------------------------------------
__global__ void tobf16_kernel(const float4* __restrict__ in, ushort4* __restrict__ out, int n4)
{
    for (int i = blockIdx.x * blockDim.x + threadIdx.x; i < n4; i += gridDim.x * blockDim.x) {
        float4 v = in[i];
        ushort4 o;
        o.x = f2b(v.x); o.y = f2b(v.y); o.z = f2b(v.z); o.w = f2b(v.w);
        out[i] = o;
    }
}

// ---------------------------------------------------------------------------
// Pack the 4 weight matrices into MFMA B-fragment order, bf16.
// ---------------------------------------------------------------------------
__global__ void wpack_kernel(const float* __restrict__ Wn0, const float* __restrict__ Ws0,
                             const float* __restrict__ Wn1, const float* __restrict__ Ws1,
                             unsigned short* __restrict__ wpk)
{
    int f = blockIdx.x * blockDim.x + threadIdx.x;   // [0, 2048)
    if (f >= 2048) return;
    const float* W[4] = {Wn0, Ws0, Wn1, Ws1};
    int m   = f >> 9;
    int rem = f & 511;
    int kb  = rem >> 8;
    int nt  = (rem >> 6) & 3;
    int l   = rem & 63;
    const float* Wm = W[m];
    int kbase = 32 * kb + ((l >> 4) << 3);
    int n     = 16 * nt + (l & 15);
    unsigned short o[8];
    #pragma unroll
    for (int j = 0; j < 8; ++j) o[j] = f2b(Wm[(kbase + j) * 64 + n]);
    ushort4* dst = (ushort4*)(wpk + (size_t)f * 8);
    dst[0] = make_ushort4(o[0], o[1], o[2], o[3]);
    dst[1] = make_ushort4(o[4], o[5], o[6], o[7]);
}

// ---------------------------------------------------------------------------
// Node scalars via MFMA: one wave per 16 nodes.
// ---------------------------------------------------------------------------
__global__ __launch_bounds__(256)
void node_scalars_mfma_kernel(const unsigned short* __restrict__ xb,
                              const unsigned short* __restrict__ wpack, // [2][2][4][64][8]
                              const float* __restrict__ bn, const float* __restrict__ bs,
                              const float* __restrict__ Wa,
                              float* __restrict__ a_nb, float* __restrict__ a_self,
                              int nNodes)
{
    const int lane = threadIdx.x & 63;
    const int wid  = (blockIdx.x * blockDim.x + threadIdx.x) >> 6;
    const int nodeBase = wid * 16;
    if (nodeBase >= nNodes) return;

    short8v bfrag[2][2][4];
    #pragma unroll
    for (int m = 0; m < 2; ++m)
        #pragma unroll
        for (int kb = 0; kb < 2; ++kb)
            #pragma unroll
            for (int nt = 0; nt < 4; ++nt)
                bfrag[m][kb][nt] =
                    *(const short8v*)(wpack + (size_t)((((m * 2 + kb) * 4 + nt) * 64 + lane)) * 8);

    const size_t rowOff = (size_t)(nodeBase + (lane & 15)) * 64 + ((lane >> 4) << 3);
    short8v a0 = *(const short8v*)(xb + rowOff);
    short8v a1 = *(const short8v*)(xb + rowOff + 32);

    float4v acc[2][4];
    #pragma unroll
    for (int m = 0; m < 2; ++m)
        #pragma unroll
        for (int nt = 0; nt < 4; ++nt) {
            float4v z = {0.f, 0.f, 0.f, 0.f};
            z = __builtin_amdgcn_mfma_f32_16x16x32_bf16(a0, bfrag[m][0][nt], z, 0, 0, 0);
            z = __builtin_amdgcn_mfma_f32_16x16x32_bf16(a1, bfrag[m][1][nt], z, 0, 0, 0);
            acc[m][nt] = z;
        }

    const int j = lane & 15;
    float pn[4] = {0.f, 0.f, 0.f, 0.f};
    float ps[4] = {0.f, 0.f, 0.f, 0.f};
    #pragma unroll
    for (int nt = 0; nt < 4; ++nt) {
        float bnv = bn[nt * 16 + j], bsv = bs[nt * 16 + j];
        float wan = Wa[nt * 16 + j], was = Wa[64 + nt * 16 + j];
        #pragma unroll
        for (int r = 0; r < 4; ++r) {
            pn[r] = fmaf(fmaxf(acc[0][nt][r] + bnv, 0.f), wan, pn[r]);
            ps[r] = fmaf(fmaxf(acc[1][nt][r] + bsv, 0.f), was, ps[r]);
        }
    }
    #pragma unroll
    for (int off = 1; off < 16; off <<= 1) {
        #pragma unroll
        for (int r = 0; r < 4; ++r) {
            pn[r] += __shfl_xor(pn[r], off);
            ps[r] += __shfl_xor(ps[r], off);
        }
    }
    if (j == 0) {
        const int g = lane >> 4;
        #pragma unroll
        for (int r = 0; r < 4; ++r) {
            int node = nodeBase + g * 4 + r;
            a_nb[node]   = pn[r];
            a_self[node] = ps[r];
        }
    }
}

// ---------------------------------------------------------------------------
// Phase 1: bin edges, carrying {row, col, packed_noise(f16 x2)}.
// noise = log(u/(1-u)) computed HERE (u read sequentially), so pass_a never
// touches u and needs no logf.
// ---------------------------------------------------------------------------
__global__ __launch_bounds__(256)
void bin_kernel(const int* __restrict__ row, const int* __restrict__ col,
                const float* __restrict__ u0, const float* __restrict__ u1,
                int* __restrict__ bcnt, int4* __restrict__ tmp, int nE)
{
    __shared__ int cnt[NBKT];
    __shared__ int base[NBKT];
    for (int i = threadIdx.x; i < NBKT; i += 256) cnt[i] = 0;
    __syncthreads();

    const int e0 = blockIdx.x * BIN_CHUNK + threadIdx.x;
    int r[16], c[16], pk[16];
    #pragma unroll
    for (int k = 0; k < 16; ++k) {
        int e = e0 + k * 256;
        r[k] = (e < nE) ? row[e] : -1;
        if (r[k] >= 0) {
            c[k]  = col[e];
            float ua = u0[e], ub = u1[e];
            float n0 = __logf(__fdividef(ua, 1.0f - ua));
            float n1 = __logf(__fdividef(ub, 1.0f - ub));
            pk[k] = (int)(((unsigned int)f2h(n1) << 16) | (unsigned int)f2h(n0));
            atomicAdd(&cnt[r[k] >> BKT_SHIFT], 1);
        }
    }
    __syncthreads();

    for (int i = threadIdx.x; i < NBKT; i += 256) {
        int cc = cnt[i];
        base[i] = cc ? atomicAdd(&bcnt[i], cc) : 0;
        cnt[i] = 0;
    }
    __syncthreads();

    #pragma unroll
    for (int k = 0; k < 16; ++k) {
        if (r[k] >= 0) {
            int b   = r[k] >> BKT_SHIFT;
            int loc = atomicAdd(&cnt[b], 1);
            tmp[(size_t)b * BKT_CAP + base[b] + loc] = make_int4(r[k], c[k], pk[k], 0);
        }
    }
}

__global__ void bucket_scan_kernel(const int* __restrict__ bcnt, int* __restrict__ bbase,
                                   int* __restrict__ start)
{
    __shared__ int sh[256];
    int t = threadIdx.x;
    int v = (t < NBKT) ? bcnt[t] : 0;
    sh[t] = v;
    __syncthreads();
    for (int off = 1; off < 256; off <<= 1) {
        int x = sh[t];
        if (t >= off) x += sh[t - off];
        __syncthreads();
        sh[t] = x;
        __syncthreads();
    }
    if (t <= NBKT) bbase[t] = (t == 0) ? 0 : sh[t - 1];
    if (t == 0) start[N_TOT] = E_TOT;
}

// ---------------------------------------------------------------------------
// Phase 2: one block per bucket; LDS counting-sort -> start[] + CSR rec[]
// (int2 {col, packed_noise} = 8B/edge).
// ---------------------------------------------------------------------------
__global__ __launch_bounds__(256)
void scatter2_kernel(const int4* __restrict__ tmp, const int* __restrict__ bcnt,
                     const int* __restrict__ bbase,
                     int* __restrict__ start, int2* __restrict__ rec)
{
    __shared__ int pref[BKT_ROWS];
    __shared__ int wsum[256];

    const int b     = blockIdx.x;
    const int rlo   = b << BKT_SHIFT;
    const int nrows = min(BKT_ROWS, N_TOT - rlo);
    const int cntb  = bcnt[b];
    const int baseb = bbase[b];
    const int t     = threadIdx.x;
    const int4* __restrict__ bkt = tmp + (size_t)b * BKT_CAP;

    for (int i = t; i < BKT_ROWS; i += 256) pref[i] = 0;
    __syncthreads();

    for (int j = t; j < cntb; j += 256)
        atomicAdd(&pref[bkt[j].x - rlo], 1);
    __syncthreads();

    const int base4 = t * 4;
    int v0 = pref[base4], v1 = pref[base4 + 1], v2 = pref[base4 + 2], v3 = pref[base4 + 3];
    int s = v0 + v1 + v2 + v3;
    wsum[t] = s;
    __syncthreads();
    for (int off = 1; off < 256; off <<= 1) {
        int x = wsum[t];
        if (t >= off) x += wsum[t - off];
        __syncthreads();
        wsum[t] = x;
        __syncthreads();
    }
    const int pre = wsum[t] - s;
    const int p0 = pre, p1 = pre + v0, p2 = pre + v0 + v1, p3 = pre + v0 + v1 + v2;

    if (base4     < nrows) start[rlo + base4]     = baseb + p0;
    if (base4 + 1 < nrows) start[rlo + base4 + 1] = baseb + p1;
    if (base4 + 2 < nrows) start[rlo + base4 + 2] = baseb + p2;
    if (base4 + 3 < nrows) start[rlo + base4 + 3] = baseb + p3;

    pref[base4] = p0; pref[base4 + 1] = p1; pref[base4 + 2] = p2; pref[base4 + 3] = p3;
    __syncthreads();

    for (int j = t; j < cntb; j += 256) {
        int4 q  = bkt[j];
        int loc = atomicAdd(&pref[q.x - rlo], 1);
        rec[baseb + loc] = make_int2(q.y, q.z);
    }
}

// ---------------------------------------------------------------------------
// Edge pass A, node-parallel: noise precomputed (f16), __expf sigmoids.
// Writes COMPACTED {m, col} records (only m>0) + fused int2 range + dis.
// ---------------------------------------------------------------------------
__global__ __launch_bounds__(256)
void edge_pass_a_kernel(const int2* __restrict__ rec, const int* __restrict__ start,
                        const int uSel,
                        const float* __restrict__ a_nb, const float* __restrict__ a_self,
                        const float* __restrict__ ba_p, const float* __restrict__ temp_p,
                        float2* __restrict__ wc, int2* __restrict__ range,
                        float* __restrict__ dis,
                        float* __restrict__ l0_accum, int nNodes)
{
    const float ba   = ba_p[0];
    const float t    = temp_p[0];
    const float invt = 1.0f / t;
    const float lt   = logf(0.45f / 1.05f);   // log(-GAMMA/ZETA)
    const float shift = t * lt;

    const int r = blockIdx.x * 256 + threadIdx.x;
    float l0local = 0.0f;

    if (r < nNodes) {
        const int js = start[r], je = start[r + 1];
        const float la_base = a_nb[r] + ba;
        float rs = 0.0f;
        int k = js;
        for (int j = js; j < je; ++j) {
            int2 q = rec[j];                     // {col, packed_noise}
            int c = q.x;
            float la = la_base + a_self[c];
            unsigned int pk = (unsigned int)q.y;
            float noise = h2f((unsigned short)(uSel ? (pk >> 16) : (pk & 0xFFFFu)));
            float gate  = 1.0f / (1.0f + __expf(-(noise + la) * invt));
            float m = fminf(fmaxf(gate * 1.5f - 0.45f, 0.0f), 1.0f);
            rs += m;
            l0local += 1.0f / (1.0f + __expf(-(la - shift)));
            if (m > 0.0f) { wc[k] = make_float2(m, i_as_f(c)); ++k; }
        }
        range[r] = make_int2(js, k);
        dis[r] = fminf(1.0f / sqrtf(rs + 1e-6f), 10.0f);
    }

    __shared__ float red[256];
    red[threadIdx.x] = l0local;
    __syncthreads();
    for (int s = 128; s > 0; s >>= 1) {
        if (threadIdx.x < s) red[threadIdx.x] += red[threadIdx.x + s];
        __syncthreads();
    }
    if (threadIdx.x == 0) unsafeAtomicAdd(l0_accum, red[0]);
}

// ---------------------------------------------------------------------------
// Edge gather v4: QUARTER-WAVE per node, ushort4 (4 dims) per lane via 8B
// loads. 4 independent per-node chains per wave; 512B contiguous output.
// ---------------------------------------------------------------------------
__global__ void edge_gather_kernel(const float2* __restrict__ wc, const int2* __restrict__ range,
                                   const float* __restrict__ dis,
                                   const unsigned short* __restrict__ xb,
                                   unsigned short* __restrict__ xnb, int nNodes)
{
    const int lane = threadIdx.x & 63;
    const int qtr  = lane >> 4;        // 0..3
    const int sub  = lane & 15;        // dim group: dims sub*4 .. sub*4+3
    const int wave   = (blockIdx.x * blockDim.x + threadIdx.x) >> 6;
    const int nWaves = (gridDim.x * blockDim.x) >> 6;
    const int nQuads = (nNodes + 3) >> 2;

    for (int p = wave; p < nQuads; p += nWaves) {
        const int r = 4 * p + qtr;
        const bool valid = r < nNodes;
        const int rr = valid ? r : nNodes - 1;
        int2 rg  = range[rr];
        float dr = dis[rr];
        int j  = rg.x;
        int je = valid ? rg.y : rg.x;
        float a0 = 0.f, a1 = 0.f, a2 = 0.f, a3 = 0.f;
        for (; j + 2 <= je; j += 2) {
            float2 w0 = wc[j], w1 = wc[j + 1];
            int c0 = f_as_i(w0.y), c1 = f_as_i(w1.y);
            float s0 = w0.x * dis[c0], s1 = w1.x * dis[c1];
            uint2 q0 = *(const uint2*)(xb + (size_t)c0 * 64 + sub * 4);
            uint2 q1 = *(const uint2*)(xb + (size_t)c1 * 64 + sub * 4);
            a0 = fmaf(s0, b2f(q0.x & 0xFFFFu), a0);
            a1 = fmaf(s0, b2f(q0.x >> 16),     a1);
            a2 = fmaf(s0, b2f(q0.y & 0xFFFFu), a2);
            a3 = fmaf(s0, b2f(q0.y >> 16),     a3);
            a0 = fmaf(s1, b2f(q1.x & 0xFFFFu), a0);
            a1 = fmaf(s1, b2f(q1.x >> 16),     a1);
            a2 = fmaf(s1, b2f(q1.y & 0xFFFFu), a2);
            a3 = fmaf(s1, b2f(q1.y >> 16),     a3);
        }
        if (j < je) {
            float2 w0 = wc[j];
            int c0 = f_as_i(w0.y);
            float s0 = w0.x * dis[c0];
            uint2 q0 = *(const uint2*)(xb + (size_t)c0 * 64 + sub * 4);
            a0 = fmaf(s0, b2f(q0.x & 0xFFFFu), a0);
            a1 = fmaf(s0, b2f(q0.x >> 16),     a1);
            a2 = fmaf(s0, b2f(q0.y & 0xFFFFu), a2);
            a3 = fmaf(s0, b2f(q0.y >> 16),     a3);
        }
        if (valid) {
            uint2 o;
            o.x = ((unsigned int)f2b(a1 * dr) << 16) | (unsigned int)f2b(a0 * dr);
            o.y = ((unsigned int)f2b(a3 * dr) << 16) | (unsigned int)f2b(a2 * dr);
            *(uint2*)(xnb + (size_t)r * 64 + sub * 4) = o;
        }
    }
}

// ---------------------------------------------------------------------------
// BPR loss: xs = features(f32) + x1(bf16) + x2(bf16)
// ---------------------------------------------------------------------------
__global__ void bpr_kernel(const float* __restrict__ f,
                           const unsigned short* __restrict__ x1b,
                           const unsigned short* __restrict__ x2b,
                           const int* __restrict__ users, const int* __restrict__ items,
                           const int* __restrict__ negs,
                           float* __restrict__ bpr_accum, int B)
{
    const int lane   = threadIdx.x & 63;
    const int wave   = (blockIdx.x * blockDim.x + threadIdx.x) >> 6;
    const int nWaves = (gridDim.x * blockDim.x) >> 6;

    float local = 0.0f;
    for (int b = wave; b < B; b += nWaves) {
        size_t ui = (size_t)users[b] * 64 + lane;
        size_t pi = (size_t)(N_USER + items[b]) * 64 + lane;
        size_t ni = (size_t)(N_USER + negs[b]) * 64 + lane;
        float a = f[ui] + b2f(x1b[ui]) + b2f(x2b[ui]);
        float p = f[pi] + b2f(x1b[pi]) + b2f(x2b[pi]);
        float n = f[ni] + b2f(x1b[ni]) + b2f(x2b[ni]);
        float ps = a * p, ns = a * n;
        #pragma unroll
        for (int off = 32; off; off >>= 1) {
            ps += __shfl_xor(ps, off);
            ns += __shfl_xor(ns, off);
        }
        if (lane == 0) {
            float s = 1.0f / (1.0f + expf(-(ps - ns)));
            local += -logf(s + 1e-5f);
        }
    }
    if (lane == 0) unsafeAtomicAdd(bpr_accum, local);
}

// ---------------------------------------------------------------------------
// L2 regularization on params
// ---------------------------------------------------------------------------
__global__ void reg_kernel(const float* __restrict__ w0, const float* __restrict__ b0,
                           const float* __restrict__ w1, const float* __restrict__ b1,
                           const float* __restrict__ wa0, const float* __restrict__ ba0,
                           const float* __restrict__ w2, const float* __restrict__ b2,
                           const float* __restrict__ w3, const float* __restrict__ b3,
                           const float* __restrict__ wa1, const float* __restrict__ ba1,
                           float* __restrict__ accum)
{
    int t = threadIdx.x;
    float s = 0.0f;
    for (int i = t; i < 4096; i += 256)
        s += w0[i]*w0[i] + w1[i]*w1[i] + w2[i]*w2[i] + w3[i]*w3[i];
    for (int i = t; i < 64; i += 256)
        s += b0[i]*b0[i] + b1[i]*b1[i] + b2[i]*b2[i] + b3[i]*b3[i];
    for (int i = t; i < 128; i += 256)
        s += wa0[i]*wa0[i] + wa1[i]*wa1[i];
    if (t == 0) s += ba0[0]*ba0[0] + ba1[0]*ba1[0];

    __shared__ float red[256];
    red[t] = s;
    __syncthreads();
    for (int st = 128; st > 0; st >>= 1) {
        if (t < st) red[t] += red[t + st];
        __syncthreads();
    }
    if (t == 0) accum[0] = red[0];
}

__global__ void finalize_kernel(const float* __restrict__ scal, float* __restrict__ out)
{
    float bpr = scal[0] / (float)B_TOT;
    float reg = scal[1] * 1e-4f;
    float l0  = (scal[2] + scal[3]) * (1e-4f / (float)E_TOT);
    out[0] = bpr + reg + l0;
}

extern "C" void kernel_launch(void* const* d_in, const int* in_sizes, int n_in,
                              void* d_out, int out_size, void* d_ws, size_t ws_size,
                              hipStream_t stream)
{
    const float* features = (const float*)d_in[0];
    const int*   row      = (const int*)d_in[1];
    const int*   col      = (const int*)d_in[2];
    const int*   users    = (const int*)d_in[3];
    const int*   items    = (const int*)d_in[4];
    const int*   negs     = (const int*)d_in[5];
    const float* u0       = (const float*)d_in[6];
    const float* u1       = (const float*)d_in[7];
    const float* temp     = (const float*)d_in[8];
    const float* W_nb0    = (const float*)d_in[9];
    const float* b_nb0    = (const float*)d_in[10];
    const float* W_self0  = (const float*)d_in[11];
    const float* b_self0  = (const float*)d_in[12];
    const float* W_att0   = (const float*)d_in[13];
    const float* b_att0   = (const float*)d_in[14];
    const float* W_nb1    = (const float*)d_in[15];
    const float* b_nb1    = (const float*)d_in[16];
    const float* W_self1  = (const float*)d_in[17];
    const float* b_self1  = (const float*)d_in[18];
    const float* W_att1   = (const float*)d_in[19];
    const float* b_att1   = (const float*)d_in[20];
    float* out = (float*)d_out;

    // ---- Workspace layout (4B element offsets), ~90 MB total ----
    float* ws = (float*)d_ws;
    unsigned short* fb  = (unsigned short*)ws;               // N*64 bf16
    unsigned short* x1b = (unsigned short*)(ws + 4800000);   // N*64 bf16
    unsigned short* x2b = (unsigned short*)(ws + 9600000);   // N*64 bf16
    // zeroed block: scal + bcnt
    float* scal  = ws + 14400000;                 // 16
    int*   bcnt  = (int*)(scal + 16);             // NBKT (pad 160)
    // end zeroed block
    int*   bbase = bcnt + 160;                    // NBKT+1 (pad 160)
    int*   start = bbase + 160;                   // NSCAN_PAD
    int4*  tmp   = (int4*)(start + NSCAN_PAD);    // NBKT*BKT_CAP int4 (19.3MB), 16B-aligned
    float2* wc   = (float2*)tmp;                  // ALIAS: E float2 (8MB) — tmp dead after scatter2
    int2*  rec   = (int2*)(tmp + (size_t)NBKT * BKT_CAP);  // E int2 (8MB)
    int2*  range = rec + E_TOT;                   // N_TOT int2
    float* dis   = (float*)(range + N_TOT);       // N_TOT
    float* a_nb  = dis + N_TOT;                   // N_TOT
    float* a_self= a_nb + N_TOT;                  // N_TOT
    unsigned short* wpk =
        (unsigned short*)(((uintptr_t)(a_self + N_TOT) + 15) & ~(uintptr_t)15);  // 32KB

    hipMemsetAsync(scal, 0, (16 + 160) * sizeof(float), stream);

    const int nNodeBlocks = (N_TOT + 255) / 256;   // 586
    const int nMfmaBlocks = (N_TOT / 16 + 3) / 4;  // 2344

    // ---- features -> bf16, weights -> packed bf16 frags ----
    tobf16_kernel<<<1024, 256, 0, stream>>>((const float4*)features, (ushort4*)fb, N_TOT * 16);
    wpack_kernel<<<8, 256, 0, stream>>>(W_nb0, W_self0, W_nb1, W_self1, wpk);

    // ---- CSR build: bin (carrying col + f16-packed noise) -> scan -> sort ----
    bin_kernel<<<NBIN_BLOCKS, 256, 0, stream>>>(row, col, u0, u1, bcnt, tmp, E_TOT);
    bucket_scan_kernel<<<1, 256, 0, stream>>>(bcnt, bbase, start);
    scatter2_kernel<<<NBKT, 256, 0, stream>>>(tmp, bcnt, bbase, start, rec);

    // ---- Layer 0 ----
    node_scalars_mfma_kernel<<<nMfmaBlocks, 256, 0, stream>>>(fb, wpk, b_nb0, b_self0, W_att0,
                                                              a_nb, a_self, N_TOT);
    edge_pass_a_kernel<<<nNodeBlocks, 256, 0, stream>>>(rec, start, 0, a_nb, a_self,
                                                        b_att0, temp, wc, range, dis,
                                                        &scal[2], N_TOT);
    edge_gather_kernel<<<2048, 256, 0, stream>>>(wc, range, dis, fb, x1b, N_TOT);

    // ---- Layer 1 ----
    node_scalars_mfma_kernel<<<nMfmaBlocks, 256, 0, stream>>>(x1b, wpk + 8192, b_nb1, b_self1,
                                                              W_att1, a_nb, a_self, N_TOT);
    edge_pass_a_kernel<<<nNodeBlocks, 256, 0, stream>>>(rec, start, 1, a_nb, a_self,
                                                        b_att1, temp, wc, range, dis,
                                                        &scal[3], N_TOT);
    edge_gather_kernel<<<2048, 256, 0, stream>>>(wc, range, dis, x1b, x2b, N_TOT);

    // ---- Losses ----
    bpr_kernel<<<64, 256, 0, stream>>>(features, x1b, x2b, users, items, negs, &scal[0], B_TOT);
    reg_kernel<<<1, 256, 0, stream>>>(W_nb0, b_nb0, W_self0, b_self0, W_att0, b_att0,
                                      W_nb1, b_nb1, W_self1, b_self1, W_att1, b_att1, &scal[1]);
    finalize_kernel<<<1, 1, 0, stream>>>(scal, out);
}

// Round 14
// 204.260 us; speedup vs baseline: 1.9233x; 1.0131x over previous
//
#include <hip/hip_runtime.h>
#include <hip/hip_bf16.h>

#define N_TOT   150000
#define N_USER  100000
#define E_TOT   1000000
#define B_TOT   4096
#define D_DIM   64

#define NSCAN_PAD   150016          // N_TOT+1 rounded up to multiple of 8
#define BKT_SHIFT   10
#define BKT_ROWS    (1 << BKT_SHIFT)                 // 1024 rows per bucket
#define NBKT        ((N_TOT + BKT_ROWS - 1) / BKT_ROWS)   // 147
#define BKT_CAP     8192
#define BIN_CHUNK   4096
#define NBIN_BLOCKS ((E_TOT + BIN_CHUNK - 1) / BIN_CHUNK) // 245
#define COL_MASK    0x3FFFF         // 18 bits (N_TOT < 262144)

typedef short short8v  __attribute__((ext_vector_type(8)));
typedef float float4v  __attribute__((ext_vector_type(4)));

// ---- bf16 / f16 helpers (bit ops; accumulation always f32) ----
__device__ __forceinline__ float b2f(unsigned int lo16)
{
    union { unsigned int u; float f; } c; c.u = lo16 << 16; return c.f;
}
__device__ __forceinline__ unsigned short f2b(float f)
{
    union { float f; unsigned int u; } c; c.f = f;
    unsigned int u = c.u + 0x7FFFu + ((c.u >> 16) & 1u);   // RNE
    return (unsigned short)(u >> 16);
}
__device__ __forceinline__ unsigned short f2h(float f)
{
    union { _Float16 h; unsigned short u; } c; c.h = (_Float16)f; return c.u;
}
__device__ __forceinline__ float h2f(unsigned short u)
{
    union { unsigned short u; _Float16 h; } c; c.u = u; return (float)c.h;
}
__device__ __forceinline__ int   f_as_i(float f) { union { float f; int i; } c; c.f = f; return c.i; }
__device__ __forceinline__ float i_as_f(int i)   { union { int i; float f; } c; c.i = i; return c.f; }

// ---------------------------------------------------------------------------
// Fused prep: blocks [0,1024) convert features f32->bf16 (grid-stride);
// blocks [1024,1032) pack the 4 weight matrices into MFMA B-frag bf16 order:
// wpk[m][kb][nt][lane][j] = W_m[32*kb + (lane>>4)*8 + j][16*nt + (lane&15)]
// ---------------------------------------------------------------------------
__global__ void prep_kernel(const float4* __restrict__ in, ushort4* __restrict__ out, int n4,
                            const float* __restrict__ Wn0, const float* __restrict__ Ws0,
                            const float* __restrict__ Wn1, const float* __restrict__ Ws1,
                            unsigned short* __restrict__ wpk)
{
    if (blockIdx.x < 1024) {
        for (int i = blockIdx.x * 256 + threadIdx.x; i < n4; i += 1024 * 256) {
            float4 v = in[i];
            ushort4 o;
            o.x = f2b(v.x); o.y = f2b(v.y); o.z = f2b(v.z); o.w = f2b(v.w);
            out[i] = o;
        }
        return;
    }
    int f = (blockIdx.x - 1024) * 256 + threadIdx.x;   // [0, 2048)
    if (f >= 2048) return;
    const float* W[4] = {Wn0, Ws0, Wn1, Ws1};
    int m   = f >> 9;
    int rem = f & 511;
    int kb  = rem >> 8;
    int nt  = (rem >> 6) & 3;
    int l   = rem & 63;
    const float* Wm = W[m];
    int kbase = 32 * kb + ((l >> 4) << 3);
    int n     = 16 * nt + (l & 15);
    unsigned short o[8];
    #pragma unroll
    for (int j = 0; j < 8; ++j) o[j] = f2b(Wm[(kbase + j) * 64 + n]);
    ushort4* dst = (ushort4*)(wpk + (size_t)f * 8);
    dst[0] = make_ushort4(o[0], o[1], o[2], o[3]);
    dst[1] = make_ushort4(o[4], o[5], o[6], o[7]);
}

// ---------------------------------------------------------------------------
// Node scalars via MFMA: one wave per 16 nodes.
// ---------------------------------------------------------------------------
__global__ __launch_bounds__(256)
void node_scalars_mfma_kernel(const unsigned short* __restrict__ xb,
                              const unsigned short* __restrict__ wpack, // [2][2][4][64][8]
                              const float* __restrict__ bn, const float* __restrict__ bs,
                              const float* __restrict__ Wa,
                              float* __restrict__ a_nb, float* __restrict__ a_self,
                              int nNodes)
{
    const int lane = threadIdx.x & 63;
    const int wid  = (blockIdx.x * blockDim.x + threadIdx.x) >> 6;
    const int nodeBase = wid * 16;
    if (nodeBase >= nNodes) return;

    short8v bfrag[2][2][4];
    #pragma unroll
    for (int m = 0; m < 2; ++m)
        #pragma unroll
        for (int kb = 0; kb < 2; ++kb)
            #pragma unroll
            for (int nt = 0; nt < 4; ++nt)
                bfrag[m][kb][nt] =
                    *(const short8v*)(wpack + (size_t)((((m * 2 + kb) * 4 + nt) * 64 + lane)) * 8);

    const size_t rowOff = (size_t)(nodeBase + (lane & 15)) * 64 + ((lane >> 4) << 3);
    short8v a0 = *(const short8v*)(xb + rowOff);
    short8v a1 = *(const short8v*)(xb + rowOff + 32);

    float4v acc[2][4];
    #pragma unroll
    for (int m = 0; m < 2; ++m)
        #pragma unroll
        for (int nt = 0; nt < 4; ++nt) {
            float4v z = {0.f, 0.f, 0.f, 0.f};
            z = __builtin_amdgcn_mfma_f32_16x16x32_bf16(a0, bfrag[m][0][nt], z, 0, 0, 0);
            z = __builtin_amdgcn_mfma_f32_16x16x32_bf16(a1, bfrag[m][1][nt], z, 0, 0, 0);
            acc[m][nt] = z;
        }

    const int j = lane & 15;
    float pn[4] = {0.f, 0.f, 0.f, 0.f};
    float ps[4] = {0.f, 0.f, 0.f, 0.f};
    #pragma unroll
    for (int nt = 0; nt < 4; ++nt) {
        float bnv = bn[nt * 16 + j], bsv = bs[nt * 16 + j];
        float wan = Wa[nt * 16 + j], was = Wa[64 + nt * 16 + j];
        #pragma unroll
        for (int r = 0; r < 4; ++r) {
            pn[r] = fmaf(fmaxf(acc[0][nt][r] + bnv, 0.f), wan, pn[r]);
            ps[r] = fmaf(fmaxf(acc[1][nt][r] + bsv, 0.f), was, ps[r]);
        }
    }
    #pragma unroll
    for (int off = 1; off < 16; off <<= 1) {
        #pragma unroll
        for (int r = 0; r < 4; ++r) {
            pn[r] += __shfl_xor(pn[r], off);
            ps[r] += __shfl_xor(ps[r], off);
        }
    }
    if (j == 0) {
        const int g = lane >> 4;
        #pragma unroll
        for (int r = 0; r < 4; ++r) {
            int node = nodeBase + g * 4 + r;
            a_nb[node]   = pn[r];
            a_self[node] = ps[r];
        }
    }
}

// ---------------------------------------------------------------------------
// Phase 1: bin edges into buckets; record packed to 8B:
//   {(row_local<<18)|col, f16x2 noise}. noise = log(u/(1-u)) computed here.
// ---------------------------------------------------------------------------
__global__ __launch_bounds__(256)
void bin_kernel(const int* __restrict__ row, const int* __restrict__ col,
                const float* __restrict__ u0, const float* __restrict__ u1,
                int* __restrict__ bcnt, int2* __restrict__ tmp, int nE)
{
    __shared__ int cnt[NBKT];
    __shared__ int base[NBKT];
    for (int i = threadIdx.x; i < NBKT; i += 256) cnt[i] = 0;
    __syncthreads();

    const int e0 = blockIdx.x * BIN_CHUNK + threadIdx.x;
    int r[16], w0[16], pk[16];
    #pragma unroll
    for (int k = 0; k < 16; ++k) {
        int e = e0 + k * 256;
        r[k] = (e < nE) ? row[e] : -1;
        if (r[k] >= 0) {
            int rl = r[k] & (BKT_ROWS - 1);
            w0[k] = (rl << 18) | col[e];
            float ua = u0[e], ub = u1[e];
            float n0 = __logf(__fdividef(ua, 1.0f - ua));
            float n1 = __logf(__fdividef(ub, 1.0f - ub));
            pk[k] = (int)(((unsigned int)f2h(n1) << 16) | (unsigned int)f2h(n0));
            atomicAdd(&cnt[r[k] >> BKT_SHIFT], 1);
        }
    }
    __syncthreads();

    for (int i = threadIdx.x; i < NBKT; i += 256) {
        int cc = cnt[i];
        base[i] = cc ? atomicAdd(&bcnt[i], cc) : 0;
        cnt[i] = 0;
    }
    __syncthreads();

    #pragma unroll
    for (int k = 0; k < 16; ++k) {
        if (r[k] >= 0) {
            int b   = r[k] >> BKT_SHIFT;
            int loc = atomicAdd(&cnt[b], 1);
            tmp[(size_t)b * BKT_CAP + base[b] + loc] = make_int2(w0[k], pk[k]);
        }
    }
}

__global__ void bucket_scan_kernel(const int* __restrict__ bcnt, int* __restrict__ bbase,
                                   int* __restrict__ start)
{
    __shared__ int sh[256];
    int t = threadIdx.x;
    int v = (t < NBKT) ? bcnt[t] : 0;
    sh[t] = v;
    __syncthreads();
    for (int off = 1; off < 256; off <<= 1) {
        int x = sh[t];
        if (t >= off) x += sh[t - off];
        __syncthreads();
        sh[t] = x;
        __syncthreads();
    }
    if (t <= NBKT) bbase[t] = (t == 0) ? 0 : sh[t - 1];
    if (t == 0) start[N_TOT] = E_TOT;
}

// ---------------------------------------------------------------------------
// Phase 2: one block per bucket; LDS counting-sort -> start[] + CSR rec[]
// (int2 {col, packed_noise} = 8B/edge).
// ---------------------------------------------------------------------------
__global__ __launch_bounds__(256)
void scatter2_kernel(const int2* __restrict__ tmp, const int* __restrict__ bcnt,
                     const int* __restrict__ bbase,
                     int* __restrict__ start, int2* __restrict__ rec)
{
    __shared__ int pref[BKT_ROWS];
    __shared__ int wsum[256];

    const int b     = blockIdx.x;
    const int rlo   = b << BKT_SHIFT;
    const int nrows = min(BKT_ROWS, N_TOT - rlo);
    const int cntb  = bcnt[b];
    const int baseb = bbase[b];
    const int t     = threadIdx.x;
    const int2* __restrict__ bkt = tmp + (size_t)b * BKT_CAP;

    for (int i = t; i < BKT_ROWS; i += 256) pref[i] = 0;
    __syncthreads();

    for (int j = t; j < cntb; j += 256)
        atomicAdd(&pref[(unsigned int)bkt[j].x >> 18], 1);
    __syncthreads();

    const int base4 = t * 4;
    int v0 = pref[base4], v1 = pref[base4 + 1], v2 = pref[base4 + 2], v3 = pref[base4 + 3];
    int s = v0 + v1 + v2 + v3;
    wsum[t] = s;
    __syncthreads();
    for (int off = 1; off < 256; off <<= 1) {
        int x = wsum[t];
        if (t >= off) x += wsum[t - off];
        __syncthreads();
        wsum[t] = x;
        __syncthreads();
    }
    const int pre = wsum[t] - s;
    const int p0 = pre, p1 = pre + v0, p2 = pre + v0 + v1, p3 = pre + v0 + v1 + v2;

    if (base4     < nrows) start[rlo + base4]     = baseb + p0;
    if (base4 + 1 < nrows) start[rlo + base4 + 1] = baseb + p1;
    if (base4 + 2 < nrows) start[rlo + base4 + 2] = baseb + p2;
    if (base4 + 3 < nrows) start[rlo + base4 + 3] = baseb + p3;

    pref[base4] = p0; pref[base4 + 1] = p1; pref[base4 + 2] = p2; pref[base4 + 3] = p3;
    __syncthreads();

    for (int j = t; j < cntb; j += 256) {
        int2 q  = bkt[j];
        int loc = atomicAdd(&pref[(unsigned int)q.x >> 18], 1);
        rec[baseb + loc] = make_int2(q.x & COL_MASK, q.y);
    }
}

// ---------------------------------------------------------------------------
// Edge pass A, node-parallel: noise precomputed (f16), __expf sigmoids.
// Writes COMPACTED {m, col} records (only m>0) + fused int2 range + dis.
// ---------------------------------------------------------------------------
__global__ __launch_bounds__(256)
void edge_pass_a_kernel(const int2* __restrict__ rec, const int* __restrict__ start,
                        const int uSel,
                        const float* __restrict__ a_nb, const float* __restrict__ a_self,
                        const float* __restrict__ ba_p, const float* __restrict__ temp_p,
                        float2* __restrict__ wc, int2* __restrict__ range,
                        float* __restrict__ dis,
                        float* __restrict__ l0_accum, int nNodes)
{
    const float ba   = ba_p[0];
    const float t    = temp_p[0];
    const float invt = 1.0f / t;
    const float lt   = logf(0.45f / 1.05f);   // log(-GAMMA/ZETA)
    const float shift = t * lt;

    const int r = blockIdx.x * 256 + threadIdx.x;
    float l0local = 0.0f;

    if (r < nNodes) {
        const int js = start[r], je = start[r + 1];
        const float la_base = a_nb[r] + ba;
        float rs = 0.0f;
        int k = js;
        for (int j = js; j < je; ++j) {
            int2 q = rec[j];                     // {col, packed_noise}
            int c = q.x;
            float la = la_base + a_self[c];
            unsigned int pk = (unsigned int)q.y;
            float noise = h2f((unsigned short)(uSel ? (pk >> 16) : (pk & 0xFFFFu)));
            float gate  = 1.0f / (1.0f + __expf(-(noise + la) * invt));
            float m = fminf(fmaxf(gate * 1.5f - 0.45f, 0.0f), 1.0f);
            rs += m;
            l0local += 1.0f / (1.0f + __expf(-(la - shift)));
            if (m > 0.0f) { wc[k] = make_float2(m, i_as_f(c)); ++k; }
        }
        range[r] = make_int2(js, k);
        dis[r] = fminf(1.0f / sqrtf(rs + 1e-6f), 10.0f);
    }

    __shared__ float red[256];
    red[threadIdx.x] = l0local;
    __syncthreads();
    for (int s = 128; s > 0; s >>= 1) {
        if (threadIdx.x < s) red[threadIdx.x] += red[threadIdx.x + s];
        __syncthreads();
    }
    if (threadIdx.x == 0) unsafeAtomicAdd(l0_accum, red[0]);
}

// ---------------------------------------------------------------------------
// Edge gather v5: QUARTER-WAVE per node, ushort4 per lane, 4-deep unroll
// (4 independent x-row loads in flight per chain).
// ---------------------------------------------------------------------------
__global__ void edge_gather_kernel(const float2* __restrict__ wc, const int2* __restrict__ range,
                                   const float* __restrict__ dis,
                                   const unsigned short* __restrict__ xb,
                                   unsigned short* __restrict__ xnb, int nNodes)
{
    const int lane = threadIdx.x & 63;
    const int qtr  = lane >> 4;        // 0..3
    const int sub  = lane & 15;        // dims sub*4 .. sub*4+3
    const int wave   = (blockIdx.x * blockDim.x + threadIdx.x) >> 6;
    const int nWaves = (gridDim.x * blockDim.x) >> 6;
    const int nQuads = (nNodes + 3) >> 2;

    for (int p = wave; p < nQuads; p += nWaves) {
        const int r = 4 * p + qtr;
        const bool valid = r < nNodes;
        const int rr = valid ? r : nNodes - 1;
        int2 rg  = range[rr];
        float dr = dis[rr];
        int j  = rg.x;
        int je = valid ? rg.y : rg.x;
        float a0 = 0.f, a1 = 0.f, a2 = 0.f, a3 = 0.f;
        for (; j + 4 <= je; j += 4) {
            float2 w0 = wc[j], w1 = wc[j + 1], w2 = wc[j + 2], w3 = wc[j + 3];
            int c0 = f_as_i(w0.y), c1 = f_as_i(w1.y), c2 = f_as_i(w2.y), c3 = f_as_i(w3.y);
            float s0 = w0.x * dis[c0], s1 = w1.x * dis[c1];
            float s2 = w2.x * dis[c2], s3 = w3.x * dis[c3];
            uint2 q0 = *(const uint2*)(xb + (size_t)c0 * 64 + sub * 4);
            uint2 q1 = *(const uint2*)(xb + (size_t)c1 * 64 + sub * 4);
            uint2 q2 = *(const uint2*)(xb + (size_t)c2 * 64 + sub * 4);
            uint2 q3 = *(const uint2*)(xb + (size_t)c3 * 64 + sub * 4);
            a0 = fmaf(s0, b2f(q0.x & 0xFFFFu), a0);
            a1 = fmaf(s0, b2f(q0.x >> 16),     a1);
            a2 = fmaf(s0, b2f(q0.y & 0xFFFFu), a2);
            a3 = fmaf(s0, b2f(q0.y >> 16),     a3);
            a0 = fmaf(s1, b2f(q1.x & 0xFFFFu), a0);
            a1 = fmaf(s1, b2f(q1.x >> 16),     a1);
            a2 = fmaf(s1, b2f(q1.y & 0xFFFFu), a2);
            a3 = fmaf(s1, b2f(q1.y >> 16),     a3);
            a0 = fmaf(s2, b2f(q2.x & 0xFFFFu), a0);
            a1 = fmaf(s2, b2f(q2.x >> 16),     a1);
            a2 = fmaf(s2, b2f(q2.y & 0xFFFFu), a2);
            a3 = fmaf(s2, b2f(q2.y >> 16),     a3);
            a0 = fmaf(s3, b2f(q3.x & 0xFFFFu), a0);
            a1 = fmaf(s3, b2f(q3.x >> 16),     a1);
            a2 = fmaf(s3, b2f(q3.y & 0xFFFFu), a2);
            a3 = fmaf(s3, b2f(q3.y >> 16),     a3);
        }
        for (; j < je; ++j) {
            float2 w0 = wc[j];
            int c0 = f_as_i(w0.y);
            float s0 = w0.x * dis[c0];
            uint2 q0 = *(const uint2*)(xb + (size_t)c0 * 64 + sub * 4);
            a0 = fmaf(s0, b2f(q0.x & 0xFFFFu), a0);
            a1 = fmaf(s0, b2f(q0.x >> 16),     a1);
            a2 = fmaf(s0, b2f(q0.y & 0xFFFFu), a2);
            a3 = fmaf(s0, b2f(q0.y >> 16),     a3);
        }
        if (valid) {
            uint2 o;
            o.x = ((unsigned int)f2b(a1 * dr) << 16) | (unsigned int)f2b(a0 * dr);
            o.y = ((unsigned int)f2b(a3 * dr) << 16) | (unsigned int)f2b(a2 * dr);
            *(uint2*)(xnb + (size_t)r * 64 + sub * 4) = o;
        }
    }
}

// ---------------------------------------------------------------------------
// BPR loss: xs = features(f32) + x1(bf16) + x2(bf16)
// ---------------------------------------------------------------------------
__global__ void bpr_kernel(const float* __restrict__ f,
                           const unsigned short* __restrict__ x1b,
                           const unsigned short* __restrict__ x2b,
                           const int* __restrict__ users, const int* __restrict__ items,
                           const int* __restrict__ negs,
                           float* __restrict__ bpr_accum, int B)
{
    const int lane   = threadIdx.x & 63;
    const int wave   = (blockIdx.x * blockDim.x + threadIdx.x) >> 6;
    const int nWaves = (gridDim.x * blockDim.x) >> 6;

    float local = 0.0f;
    for (int b = wave; b < B; b += nWaves) {
        size_t ui = (size_t)users[b] * 64 + lane;
        size_t pi = (size_t)(N_USER + items[b]) * 64 + lane;
        size_t ni = (size_t)(N_USER + negs[b]) * 64 + lane;
        float a = f[ui] + b2f(x1b[ui]) + b2f(x2b[ui]);
        float p = f[pi] + b2f(x1b[pi]) + b2f(x2b[pi]);
        float n = f[ni] + b2f(x1b[ni]) + b2f(x2b[ni]);
        float ps = a * p, ns = a * n;
        #pragma unroll
        for (int off = 32; off; off >>= 1) {
            ps += __shfl_xor(ps, off);
            ns += __shfl_xor(ns, off);
        }
        if (lane == 0) {
            float s = 1.0f / (1.0f + expf(-(ps - ns)));
            local += -logf(s + 1e-5f);
        }
    }
    if (lane == 0) unsafeAtomicAdd(bpr_accum, local);
}

// ---------------------------------------------------------------------------
// L2 regularization on params
// ---------------------------------------------------------------------------
__global__ void reg_kernel(const float* __restrict__ w0, const float* __restrict__ b0,
                           const float* __restrict__ w1, const float* __restrict__ b1,
                           const float* __restrict__ wa0, const float* __restrict__ ba0,
                           const float* __restrict__ w2, const float* __restrict__ b2,
                           const float* __restrict__ w3, const float* __restrict__ b3,
                           const float* __restrict__ wa1, const float* __restrict__ ba1,
                           float* __restrict__ accum)
{
    int t = threadIdx.x;
    float s = 0.0f;
    for (int i = t; i < 4096; i += 256)
        s += w0[i]*w0[i] + w1[i]*w1[i] + w2[i]*w2[i] + w3[i]*w3[i];
    for (int i = t; i < 64; i += 256)
        s += b0[i]*b0[i] + b1[i]*b1[i] + b2[i]*b2[i] + b3[i]*b3[i];
    for (int i = t; i < 128; i += 256)
        s += wa0[i]*wa0[i] + wa1[i]*wa1[i];
    if (t == 0) s += ba0[0]*ba0[0] + ba1[0]*ba1[0];

    __shared__ float red[256];
    red[t] = s;
    __syncthreads();
    for (int st = 128; st > 0; st >>= 1) {
        if (t < st) red[t] += red[t + st];
        __syncthreads();
    }
    if (t == 0) accum[0] = red[0];
}

__global__ void finalize_kernel(const float* __restrict__ scal, float* __restrict__ out)
{
    float bpr = scal[0] / (float)B_TOT;
    float reg = scal[1] * 1e-4f;
    float l0  = (scal[2] + scal[3]) * (1e-4f / (float)E_TOT);
    out[0] = bpr + reg + l0;
}

extern "C" void kernel_launch(void* const* d_in, const int* in_sizes, int n_in,
                              void* d_out, int out_size, void* d_ws, size_t ws_size,
                              hipStream_t stream)
{
    const float* features = (const float*)d_in[0];
    const int*   row      = (const int*)d_in[1];
    const int*   col      = (const int*)d_in[2];
    const int*   users    = (const int*)d_in[3];
    const int*   items    = (const int*)d_in[4];
    const int*   negs     = (const int*)d_in[5];
    const float* u0       = (const float*)d_in[6];
    const float* u1       = (const float*)d_in[7];
    const float* temp     = (const float*)d_in[8];
    const float* W_nb0    = (const float*)d_in[9];
    const float* b_nb0    = (const float*)d_in[10];
    const float* W_self0  = (const float*)d_in[11];
    const float* b_self0  = (const float*)d_in[12];
    const float* W_att0   = (const float*)d_in[13];
    const float* b_att0   = (const float*)d_in[14];
    const float* W_nb1    = (const float*)d_in[15];
    const float* b_nb1    = (const float*)d_in[16];
    const float* W_self1  = (const float*)d_in[17];
    const float* b_self1  = (const float*)d_in[18];
    const float* W_att1   = (const float*)d_in[19];
    const float* b_att1   = (const float*)d_in[20];
    float* out = (float*)d_out;

    // ---- Workspace layout (4B element offsets), ~80 MB total ----
    float* ws = (float*)d_ws;
    unsigned short* fb  = (unsigned short*)ws;               // N*64 bf16
    unsigned short* x1b = (unsigned short*)(ws + 4800000);   // N*64 bf16
    unsigned short* x2b = (unsigned short*)(ws + 9600000);   // N*64 bf16
    // zeroed block: scal + bcnt
    float* scal  = ws + 14400000;                 // 16
    int*   bcnt  = (int*)(scal + 16);             // NBKT (pad 160)
    // end zeroed block
    int*   bbase = bcnt + 160;                    // NBKT+1 (pad 160)
    int*   start = bbase + 160;                   // NSCAN_PAD
    int2*  tmp   = (int2*)(start + NSCAN_PAD);    // NBKT*BKT_CAP int2 (9.6MB), 8B-aligned
    float2* wc   = (float2*)tmp;                  // ALIAS: E float2 (8MB) — tmp dead after scatter2
    int2*  rec   = tmp + (size_t)NBKT * BKT_CAP;  // E int2 (8MB)
    int2*  range = rec + E_TOT;                   // N_TOT int2
    float* dis   = (float*)(range + N_TOT);       // N_TOT
    float* a_nb  = dis + N_TOT;                   // N_TOT
    float* a_self= a_nb + N_TOT;                  // N_TOT
    unsigned short* wpk =
        (unsigned short*)(((uintptr_t)(a_self + N_TOT) + 15) & ~(uintptr_t)15);  // 32KB

    hipMemsetAsync(scal, 0, (16 + 160) * sizeof(float), stream);

    const int nNodeBlocks = (N_TOT + 255) / 256;   // 586
    const int nMfmaBlocks = (N_TOT / 16 + 3) / 4;  // 2344

    // ---- fused: features -> bf16 + weights -> packed bf16 frags ----
    prep_kernel<<<1032, 256, 0, stream>>>((const float4*)features, (ushort4*)fb, N_TOT * 16,
                                          W_nb0, W_self0, W_nb1, W_self1, wpk);

    // ---- CSR build: bin (8B packed recs) -> scan -> counting-sort ----
    bin_kernel<<<NBIN_BLOCKS, 256, 0, stream>>>(row, col, u0, u1, bcnt, tmp, E_TOT);
    bucket_scan_kernel<<<1, 256, 0, stream>>>(bcnt, bbase, start);
    scatter2_kernel<<<NBKT, 256, 0, stream>>>(tmp, bcnt, bbase, start, rec);

    // ---- Layer 0 ----
    node_scalars_mfma_kernel<<<nMfmaBlocks, 256, 0, stream>>>(fb, wpk, b_nb0, b_self0, W_att0,
                                                              a_nb, a_self, N_TOT);
    edge_pass_a_kernel<<<nNodeBlocks, 256, 0, stream>>>(rec, start, 0, a_nb, a_self,
                                                        b_att0, temp, wc, range, dis,
                                                        &scal[2], N_TOT);
    edge_gather_kernel<<<2048, 256, 0, stream>>>(wc, range, dis, fb, x1b, N_TOT);

    // ---- Layer 1 ----
    node_scalars_mfma_kernel<<<nMfmaBlocks, 256, 0, stream>>>(x1b, wpk + 8192, b_nb1, b_self1,
                                                              W_att1, a_nb, a_self, N_TOT);
    edge_pass_a_kernel<<<nNodeBlocks, 256, 0, stream>>>(rec, start, 1, a_nb, a_self,
                                                        b_att1, temp, wc, range, dis,
                                                        &scal[3], N_TOT);
    edge_gather_kernel<<<2048, 256, 0, stream>>>(wc, range, dis, x1b, x2b, N_TOT);

    // ---- Losses ----
    bpr_kernel<<<64, 256, 0, stream>>>(features, x1b, x2b, users, items, negs, &scal[0], B_TOT);
    reg_kernel<<<1, 256, 0, stream>>>(W_nb0, b_nb0, W_self0, b_self0, W_att0, b_att0,
                                      W_nb1, b_nb1, W_self1, b_self1, W_att1, b_att1, &scal[1]);
    finalize_kernel<<<1, 1, 0, stream>>>(scal, out);
}

// Round 15
// 184.676 us; speedup vs baseline: 2.1273x; 1.1060x over previous
//
#include <hip/hip_runtime.h>
#include <hip/hip_bf16.h>

#define N_TOT   150000
#define N_USER  100000
#define E_TOT   1000000
#define B_TOT   4096
#define D_DIM   64

#define NSCAN_PAD   150016          // N_TOT+1 rounded up to multiple of 8
#define BKT_SHIFT   10
#define BKT_ROWS    (1 << BKT_SHIFT)                 // 1024 rows per bucket
#define NBKT        ((N_TOT + BKT_ROWS - 1) / BKT_ROWS)   // 147
#define BKT_CAP     8192
#define BIN_CHUNK   4096
#define NBIN_BLOCKS ((E_TOT + BIN_CHUNK - 1) / BIN_CHUNK) // 245
#define COL_MASK    0x3FFFF         // 18 bits (N_TOT < 262144)

typedef short short8v  __attribute__((ext_vector_type(8)));
typedef float float4v  __attribute__((ext_vector_type(4)));

// ---- bf16 / f16 helpers (bit ops; accumulation always f32) ----
__device__ __forceinline__ float b2f(unsigned int lo16)
{
    union { unsigned int u; float f; } c; c.u = lo16 << 16; return c.f;
}
__device__ __forceinline__ unsigned short f2b(float f)
{
    union { float f; unsigned int u; } c; c.f = f;
    unsigned int u = c.u + 0x7FFFu + ((c.u >> 16) & 1u);   // RNE
    return (unsigned short)(u >> 16);
}
__device__ __forceinline__ unsigned short f2h(float f)
{
    union { _Float16 h; unsigned short u; } c; c.h = (_Float16)f; return c.u;
}
__device__ __forceinline__ float h2f(unsigned short u)
{
    union { unsigned short u; _Float16 h; } c; c.u = u; return (float)c.h;
}
__device__ __forceinline__ int   f_as_i(float f) { union { float f; int i; } c; c.f = f; return c.i; }
__device__ __forceinline__ float i_as_f(int i)   { union { int i; float f; } c; c.i = i; return c.f; }

// ---------------------------------------------------------------------------
// Fused prep: blocks [0,1024) convert features f32->bf16 (grid-stride);
// blocks [1024,1032) pack the 4 weight matrices into MFMA B-frag bf16 order.
// ---------------------------------------------------------------------------
__global__ void prep_kernel(const float4* __restrict__ in, ushort4* __restrict__ out, int n4,
                            const float* __restrict__ Wn0, const float* __restrict__ Ws0,
                            const float* __restrict__ Wn1, const float* __restrict__ Ws1,
                            unsigned short* __restrict__ wpk)
{
    if (blockIdx.x < 1024) {
        for (int i = blockIdx.x * 256 + threadIdx.x; i < n4; i += 1024 * 256) {
            float4 v = in[i];
            ushort4 o;
            o.x = f2b(v.x); o.y = f2b(v.y); o.z = f2b(v.z); o.w = f2b(v.w);
            out[i] = o;
        }
        return;
    }
    int f = (blockIdx.x - 1024) * 256 + threadIdx.x;   // [0, 2048)
    if (f >= 2048) return;
    const float* W[4] = {Wn0, Ws0, Wn1, Ws1};
    int m   = f >> 9;
    int rem = f & 511;
    int kb  = rem >> 8;
    int nt  = (rem >> 6) & 3;
    int l   = rem & 63;
    const float* Wm = W[m];
    int kbase = 32 * kb + ((l >> 4) << 3);
    int n     = 16 * nt + (l & 15);
    unsigned short o[8];
    #pragma unroll
    for (int j = 0; j < 8; ++j) o[j] = f2b(Wm[(kbase + j) * 64 + n]);
    ushort4* dst = (ushort4*)(wpk + (size_t)f * 8);
    dst[0] = make_ushort4(o[0], o[1], o[2], o[3]);
    dst[1] = make_ushort4(o[4], o[5], o[6], o[7]);
}

// ---------------------------------------------------------------------------
// Node scalars via MFMA: one wave per 16 nodes.
// ---------------------------------------------------------------------------
__global__ __launch_bounds__(256)
void node_scalars_mfma_kernel(const unsigned short* __restrict__ xb,
                              const unsigned short* __restrict__ wpack, // [2][2][4][64][8]
                              const float* __restrict__ bn, const float* __restrict__ bs,
                              const float* __restrict__ Wa,
                              float* __restrict__ a_nb, float* __restrict__ a_self,
                              int nNodes)
{
    const int lane = threadIdx.x & 63;
    const int wid  = (blockIdx.x * blockDim.x + threadIdx.x) >> 6;
    const int nodeBase = wid * 16;
    if (nodeBase >= nNodes) return;

    short8v bfrag[2][2][4];
    #pragma unroll
    for (int m = 0; m < 2; ++m)
        #pragma unroll
        for (int kb = 0; kb < 2; ++kb)
            #pragma unroll
            for (int nt = 0; nt < 4; ++nt)
                bfrag[m][kb][nt] =
                    *(const short8v*)(wpack + (size_t)((((m * 2 + kb) * 4 + nt) * 64 + lane)) * 8);

    const size_t rowOff = (size_t)(nodeBase + (lane & 15)) * 64 + ((lane >> 4) << 3);
    short8v a0 = *(const short8v*)(xb + rowOff);
    short8v a1 = *(const short8v*)(xb + rowOff + 32);

    float4v acc[2][4];
    #pragma unroll
    for (int m = 0; m < 2; ++m)
        #pragma unroll
        for (int nt = 0; nt < 4; ++nt) {
            float4v z = {0.f, 0.f, 0.f, 0.f};
            z = __builtin_amdgcn_mfma_f32_16x16x32_bf16(a0, bfrag[m][0][nt], z, 0, 0, 0);
            z = __builtin_amdgcn_mfma_f32_16x16x32_bf16(a1, bfrag[m][1][nt], z, 0, 0, 0);
            acc[m][nt] = z;
        }

    const int j = lane & 15;
    float pn[4] = {0.f, 0.f, 0.f, 0.f};
    float ps[4] = {0.f, 0.f, 0.f, 0.f};
    #pragma unroll
    for (int nt = 0; nt < 4; ++nt) {
        float bnv = bn[nt * 16 + j], bsv = bs[nt * 16 + j];
        float wan = Wa[nt * 16 + j], was = Wa[64 + nt * 16 + j];
        #pragma unroll
        for (int r = 0; r < 4; ++r) {
            pn[r] = fmaf(fmaxf(acc[0][nt][r] + bnv, 0.f), wan, pn[r]);
            ps[r] = fmaf(fmaxf(acc[1][nt][r] + bsv, 0.f), was, ps[r]);
        }
    }
    #pragma unroll
    for (int off = 1; off < 16; off <<= 1) {
        #pragma unroll
        for (int r = 0; r < 4; ++r) {
            pn[r] += __shfl_xor(pn[r], off);
            ps[r] += __shfl_xor(ps[r], off);
        }
    }
    if (j == 0) {
        const int g = lane >> 4;
        #pragma unroll
        for (int r = 0; r < 4; ++r) {
            int node = nodeBase + g * 4 + r;
            a_nb[node]   = pn[r];
            a_self[node] = ps[r];
        }
    }
}

// ---------------------------------------------------------------------------
// Phase 1: bin edges into buckets; record packed to 8B:
//   {(row_local<<18)|col, f16x2 noise}. noise = log(u/(1-u)) computed here.
// ---------------------------------------------------------------------------
__global__ __launch_bounds__(256)
void bin_kernel(const int* __restrict__ row, const int* __restrict__ col,
                const float* __restrict__ u0, const float* __restrict__ u1,
                int* __restrict__ bcnt, int2* __restrict__ tmp, int nE)
{
    __shared__ int cnt[NBKT];
    __shared__ int base[NBKT];
    for (int i = threadIdx.x; i < NBKT; i += 256) cnt[i] = 0;
    __syncthreads();

    const int e0 = blockIdx.x * BIN_CHUNK + threadIdx.x;
    int r[16], w0[16], pk[16];
    #pragma unroll
    for (int k = 0; k < 16; ++k) {
        int e = e0 + k * 256;
        r[k] = (e < nE) ? row[e] : -1;
        if (r[k] >= 0) {
            int rl = r[k] & (BKT_ROWS - 1);
            w0[k] = (rl << 18) | col[e];
            float ua = u0[e], ub = u1[e];
            float n0 = __logf(__fdividef(ua, 1.0f - ua));
            float n1 = __logf(__fdividef(ub, 1.0f - ub));
            pk[k] = (int)(((unsigned int)f2h(n1) << 16) | (unsigned int)f2h(n0));
            atomicAdd(&cnt[r[k] >> BKT_SHIFT], 1);
        }
    }
    __syncthreads();

    for (int i = threadIdx.x; i < NBKT; i += 256) {
        int cc = cnt[i];
        base[i] = cc ? atomicAdd(&bcnt[i], cc) : 0;
        cnt[i] = 0;
    }
    __syncthreads();

    #pragma unroll
    for (int k = 0; k < 16; ++k) {
        if (r[k] >= 0) {
            int b   = r[k] >> BKT_SHIFT;
            int loc = atomicAdd(&cnt[b], 1);
            tmp[(size_t)b * BKT_CAP + base[b] + loc] = make_int2(w0[k], pk[k]);
        }
    }
}

// ---------------------------------------------------------------------------
// Phase 2: one block per bucket. Recomputes the 147-entry bucket prefix in
// LDS (replaces the old bucket_scan dispatch), then LDS counting-sort ->
// start[] + CSR rec[] (int2 {col, packed_noise} = 8B/edge).
// ---------------------------------------------------------------------------
__global__ __launch_bounds__(256)
void scatter2_kernel(const int2* __restrict__ tmp, const int* __restrict__ bcnt,
                     int* __restrict__ start, int2* __restrict__ rec)
{
    __shared__ int pref[BKT_ROWS];
    __shared__ int wsum[256];
    __shared__ int sc[256];

    const int b     = blockIdx.x;
    const int rlo   = b << BKT_SHIFT;
    const int nrows = min(BKT_ROWS, N_TOT - rlo);
    const int t     = threadIdx.x;

    // bucket-prefix scan (147 entries) in-block
    int v = (t < NBKT) ? bcnt[t] : 0;
    sc[t] = v;
    __syncthreads();
    for (int off = 1; off < 256; off <<= 1) {
        int x = sc[t];
        if (t >= off) x += sc[t - off];
        __syncthreads();
        sc[t] = x;
        __syncthreads();
    }
    const int cntb  = bcnt[b];
    const int baseb = (b == 0) ? 0 : sc[b - 1];
    if (b == 0 && t == 0) start[N_TOT] = E_TOT;

    const int2* __restrict__ bkt = tmp + (size_t)b * BKT_CAP;

    for (int i = t; i < BKT_ROWS; i += 256) pref[i] = 0;
    __syncthreads();

    for (int j = t; j < cntb; j += 256)
        atomicAdd(&pref[(unsigned int)bkt[j].x >> 18], 1);
    __syncthreads();

    const int base4 = t * 4;
    int v0 = pref[base4], v1 = pref[base4 + 1], v2 = pref[base4 + 2], v3 = pref[base4 + 3];
    int s = v0 + v1 + v2 + v3;
    wsum[t] = s;
    __syncthreads();
    for (int off = 1; off < 256; off <<= 1) {
        int x = wsum[t];
        if (t >= off) x += wsum[t - off];
        __syncthreads();
        wsum[t] = x;
        __syncthreads();
    }
    const int pre = wsum[t] - s;
    const int p0 = pre, p1 = pre + v0, p2 = pre + v0 + v1, p3 = pre + v0 + v1 + v2;

    if (base4     < nrows) start[rlo + base4]     = baseb + p0;
    if (base4 + 1 < nrows) start[rlo + base4 + 1] = baseb + p1;
    if (base4 + 2 < nrows) start[rlo + base4 + 2] = baseb + p2;
    if (base4 + 3 < nrows) start[rlo + base4 + 3] = baseb + p3;

    pref[base4] = p0; pref[base4 + 1] = p1; pref[base4 + 2] = p2; pref[base4 + 3] = p3;
    __syncthreads();

    for (int j = t; j < cntb; j += 256) {
        int2 q  = bkt[j];
        int loc = atomicAdd(&pref[(unsigned int)q.x >> 18], 1);
        rec[baseb + loc] = make_int2(q.x & COL_MASK, q.y);
    }
}

// ---------------------------------------------------------------------------
// Edge pass A, node-parallel: noise precomputed (f16), __expf sigmoids.
// Writes COMPACTED {m, col} records (only m>0) + fused int2 range + dis.
// ---------------------------------------------------------------------------
__global__ __launch_bounds__(256)
void edge_pass_a_kernel(const int2* __restrict__ rec, const int* __restrict__ start,
                        const int uSel,
                        const float* __restrict__ a_nb, const float* __restrict__ a_self,
                        const float* __restrict__ ba_p, const float* __restrict__ temp_p,
                        float2* __restrict__ wc, int2* __restrict__ range,
                        float* __restrict__ dis,
                        float* __restrict__ l0_accum, int nNodes)
{
    const float ba   = ba_p[0];
    const float t    = temp_p[0];
    const float invt = 1.0f / t;
    const float lt   = logf(0.45f / 1.05f);   // log(-GAMMA/ZETA)
    const float shift = t * lt;

    const int r = blockIdx.x * 256 + threadIdx.x;
    float l0local = 0.0f;

    if (r < nNodes) {
        const int js = start[r], je = start[r + 1];
        const float la_base = a_nb[r] + ba;
        float rs = 0.0f;
        int k = js;
        for (int j = js; j < je; ++j) {
            int2 q = rec[j];                     // {col, packed_noise}
            int c = q.x;
            float la = la_base + a_self[c];
            unsigned int pk = (unsigned int)q.y;
            float noise = h2f((unsigned short)(uSel ? (pk >> 16) : (pk & 0xFFFFu)));
            float gate  = 1.0f / (1.0f + __expf(-(noise + la) * invt));
            float m = fminf(fmaxf(gate * 1.5f - 0.45f, 0.0f), 1.0f);
            rs += m;
            l0local += 1.0f / (1.0f + __expf(-(la - shift)));
            if (m > 0.0f) { wc[k] = make_float2(m, i_as_f(c)); ++k; }
        }
        range[r] = make_int2(js, k);
        dis[r] = fminf(1.0f / sqrtf(rs + 1e-6f), 10.0f);
    }

    __shared__ float red[256];
    red[threadIdx.x] = l0local;
    __syncthreads();
    for (int s = 128; s > 0; s >>= 1) {
        if (threadIdx.x < s) red[threadIdx.x] += red[threadIdx.x + s];
        __syncthreads();
    }
    if (threadIdx.x == 0) unsafeAtomicAdd(l0_accum, red[0]);
}

// ---------------------------------------------------------------------------
// Edge gather v6: EIGHTH-WAVE per node, ushort8 (8 dims, 16B) per lane.
// 8 independent per-node chains per wave, 4-deep unroll -> up to 32
// row-loads in flight; rows 8p..8p+7 adjacent -> 1KB contiguous store.
// ---------------------------------------------------------------------------
__global__ void edge_gather_kernel(const float2* __restrict__ wc, const int2* __restrict__ range,
                                   const float* __restrict__ dis,
                                   const unsigned short* __restrict__ xb,
                                   unsigned short* __restrict__ xnb, int nNodes)
{
    const int lane = threadIdx.x & 63;
    const int oct  = lane >> 3;        // 0..7
    const int sub  = lane & 7;         // dims sub*8 .. sub*8+7
    const int wave   = (blockIdx.x * blockDim.x + threadIdx.x) >> 6;
    const int nWaves = (gridDim.x * blockDim.x) >> 6;
    const int nOcts  = (nNodes + 7) >> 3;

    for (int p = wave; p < nOcts; p += nWaves) {
        const int r = 8 * p + oct;
        const bool valid = r < nNodes;
        const int rr = valid ? r : nNodes - 1;
        int2 rg  = range[rr];
        float dr = dis[rr];
        int j  = rg.x;
        int je = valid ? rg.y : rg.x;
        float a0 = 0.f, a1 = 0.f, a2 = 0.f, a3 = 0.f;
        float a4 = 0.f, a5 = 0.f, a6 = 0.f, a7 = 0.f;
        for (; j + 4 <= je; j += 4) {
            float2 w0 = wc[j], w1 = wc[j + 1], w2 = wc[j + 2], w3 = wc[j + 3];
            int c0 = f_as_i(w0.y), c1 = f_as_i(w1.y), c2 = f_as_i(w2.y), c3 = f_as_i(w3.y);
            float s0 = w0.x * dis[c0], s1 = w1.x * dis[c1];
            float s2 = w2.x * dis[c2], s3 = w3.x * dis[c3];
            uint4 q0 = *(const uint4*)(xb + (size_t)c0 * 64 + sub * 8);
            uint4 q1 = *(const uint4*)(xb + (size_t)c1 * 64 + sub * 8);
            uint4 q2 = *(const uint4*)(xb + (size_t)c2 * 64 + sub * 8);
            uint4 q3 = *(const uint4*)(xb + (size_t)c3 * 64 + sub * 8);
            a0 = fmaf(s0, b2f(q0.x & 0xFFFFu), a0); a1 = fmaf(s0, b2f(q0.x >> 16), a1);
            a2 = fmaf(s0, b2f(q0.y & 0xFFFFu), a2); a3 = fmaf(s0, b2f(q0.y >> 16), a3);
            a4 = fmaf(s0, b2f(q0.z & 0xFFFFu), a4); a5 = fmaf(s0, b2f(q0.z >> 16), a5);
            a6 = fmaf(s0, b2f(q0.w & 0xFFFFu), a6); a7 = fmaf(s0, b2f(q0.w >> 16), a7);
            a0 = fmaf(s1, b2f(q1.x & 0xFFFFu), a0); a1 = fmaf(s1, b2f(q1.x >> 16), a1);
            a2 = fmaf(s1, b2f(q1.y & 0xFFFFu), a2); a3 = fmaf(s1, b2f(q1.y >> 16), a3);
            a4 = fmaf(s1, b2f(q1.z & 0xFFFFu), a4); a5 = fmaf(s1, b2f(q1.z >> 16), a5);
            a6 = fmaf(s1, b2f(q1.w & 0xFFFFu), a6); a7 = fmaf(s1, b2f(q1.w >> 16), a7);
            a0 = fmaf(s2, b2f(q2.x & 0xFFFFu), a0); a1 = fmaf(s2, b2f(q2.x >> 16), a1);
            a2 = fmaf(s2, b2f(q2.y & 0xFFFFu), a2); a3 = fmaf(s2, b2f(q2.y >> 16), a3);
            a4 = fmaf(s2, b2f(q2.z & 0xFFFFu), a4); a5 = fmaf(s2, b2f(q2.z >> 16), a5);
            a6 = fmaf(s2, b2f(q2.w & 0xFFFFu), a6); a7 = fmaf(s2, b2f(q2.w >> 16), a7);
            a0 = fmaf(s3, b2f(q3.x & 0xFFFFu), a0); a1 = fmaf(s3, b2f(q3.x >> 16), a1);
            a2 = fmaf(s3, b2f(q3.y & 0xFFFFu), a2); a3 = fmaf(s3, b2f(q3.y >> 16), a3);
            a4 = fmaf(s3, b2f(q3.z & 0xFFFFu), a4); a5 = fmaf(s3, b2f(q3.z >> 16), a5);
            a6 = fmaf(s3, b2f(q3.w & 0xFFFFu), a6); a7 = fmaf(s3, b2f(q3.w >> 16), a7);
        }
        for (; j < je; ++j) {
            float2 w0 = wc[j];
            int c0 = f_as_i(w0.y);
            float s0 = w0.x * dis[c0];
            uint4 q0 = *(const uint4*)(xb + (size_t)c0 * 64 + sub * 8);
            a0 = fmaf(s0, b2f(q0.x & 0xFFFFu), a0); a1 = fmaf(s0, b2f(q0.x >> 16), a1);
            a2 = fmaf(s0, b2f(q0.y & 0xFFFFu), a2); a3 = fmaf(s0, b2f(q0.y >> 16), a3);
            a4 = fmaf(s0, b2f(q0.z & 0xFFFFu), a4); a5 = fmaf(s0, b2f(q0.z >> 16), a5);
            a6 = fmaf(s0, b2f(q0.w & 0xFFFFu), a6); a7 = fmaf(s0, b2f(q0.w >> 16), a7);
        }
        if (valid) {
            uint4 o;
            o.x = ((unsigned int)f2b(a1 * dr) << 16) | (unsigned int)f2b(a0 * dr);
            o.y = ((unsigned int)f2b(a3 * dr) << 16) | (unsigned int)f2b(a2 * dr);
            o.z = ((unsigned int)f2b(a5 * dr) << 16) | (unsigned int)f2b(a4 * dr);
            o.w = ((unsigned int)f2b(a7 * dr) << 16) | (unsigned int)f2b(a6 * dr);
            *(uint4*)(xnb + (size_t)r * 64 + sub * 8) = o;
        }
    }
}

// ---------------------------------------------------------------------------
// Fused losses: blocks 0..63 = BPR partial sums; block 64 = L2 reg.
// ---------------------------------------------------------------------------
__global__ void loss_kernel(const float* __restrict__ f,
                            const unsigned short* __restrict__ x1b,
                            const unsigned short* __restrict__ x2b,
                            const int* __restrict__ users, const int* __restrict__ items,
                            const int* __restrict__ negs,
                            const float* __restrict__ w0, const float* __restrict__ b0,
                            const float* __restrict__ w1, const float* __restrict__ b1,
                            const float* __restrict__ wa0, const float* __restrict__ ba0,
                            const float* __restrict__ w2, const float* __restrict__ b2,
                            const float* __restrict__ w3, const float* __restrict__ b3,
                            const float* __restrict__ wa1, const float* __restrict__ ba1,
                            float* __restrict__ scal, int B)
{
    const int t = threadIdx.x;
    if (blockIdx.x == 64) {
        // ---- L2 regularization ----
        float s = 0.0f;
        for (int i = t; i < 4096; i += 256)
            s += w0[i]*w0[i] + w1[i]*w1[i] + w2[i]*w2[i] + w3[i]*w3[i];
        for (int i = t; i < 64; i += 256)
            s += b0[i]*b0[i] + b1[i]*b1[i] + b2[i]*b2[i] + b3[i]*b3[i];
        for (int i = t; i < 128; i += 256)
            s += wa0[i]*wa0[i] + wa1[i]*wa1[i];
        if (t == 0) s += ba0[0]*ba0[0] + ba1[0]*ba1[0];

        __shared__ float red[256];
        red[t] = s;
        __syncthreads();
        for (int st = 128; st > 0; st >>= 1) {
            if (t < st) red[t] += red[t + st];
            __syncthreads();
        }
        if (t == 0) scal[1] = red[0];
        return;
    }

    // ---- BPR partial sums ----
    const int lane   = t & 63;
    const int wave   = (blockIdx.x * 256 + t) >> 6;
    const int nWaves = (64 * 256) >> 6;

    float local = 0.0f;
    for (int b = wave; b < B; b += nWaves) {
        size_t ui = (size_t)users[b] * 64 + lane;
        size_t pi = (size_t)(N_USER + items[b]) * 64 + lane;
        size_t ni = (size_t)(N_USER + negs[b]) * 64 + lane;
        float a = f[ui] + b2f(x1b[ui]) + b2f(x2b[ui]);
        float p = f[pi] + b2f(x1b[pi]) + b2f(x2b[pi]);
        float n = f[ni] + b2f(x1b[ni]) + b2f(x2b[ni]);
        float ps = a * p, ns = a * n;
        #pragma unroll
        for (int off = 32; off; off >>= 1) {
            ps += __shfl_xor(ps, off);
            ns += __shfl_xor(ns, off);
        }
        if (lane == 0) {
            float s = 1.0f / (1.0f + expf(-(ps - ns)));
            local += -logf(s + 1e-5f);
        }
    }
    if (lane == 0) unsafeAtomicAdd(&scal[0], local);
}

__global__ void finalize_kernel(const float* __restrict__ scal, float* __restrict__ out)
{
    float bpr = scal[0] / (float)B_TOT;
    float reg = scal[1] * 1e-4f;
    float l0  = (scal[2] + scal[3]) * (1e-4f / (float)E_TOT);
    out[0] = bpr + reg + l0;
}

extern "C" void kernel_launch(void* const* d_in, const int* in_sizes, int n_in,
                              void* d_out, int out_size, void* d_ws, size_t ws_size,
                              hipStream_t stream)
{
    const float* features = (const float*)d_in[0];
    const int*   row      = (const int*)d_in[1];
    const int*   col      = (const int*)d_in[2];
    const int*   users    = (const int*)d_in[3];
    const int*   items    = (const int*)d_in[4];
    const int*   negs     = (const int*)d_in[5];
    const float* u0       = (const float*)d_in[6];
    const float* u1       = (const float*)d_in[7];
    const float* temp     = (const float*)d_in[8];
    const float* W_nb0    = (const float*)d_in[9];
    const float* b_nb0    = (const float*)d_in[10];
    const float* W_self0  = (const float*)d_in[11];
    const float* b_self0  = (const float*)d_in[12];
    const float* W_att0   = (const float*)d_in[13];
    const float* b_att0   = (const float*)d_in[14];
    const float* W_nb1    = (const float*)d_in[15];
    const float* b_nb1    = (const float*)d_in[16];
    const float* W_self1  = (const float*)d_in[17];
    const float* b_self1  = (const float*)d_in[18];
    const float* W_att1   = (const float*)d_in[19];
    const float* b_att1   = (const float*)d_in[20];
    float* out = (float*)d_out;

    // ---- Workspace layout (4B element offsets), ~80 MB total ----
    float* ws = (float*)d_ws;
    unsigned short* fb  = (unsigned short*)ws;               // N*64 bf16
    unsigned short* x1b = (unsigned short*)(ws + 4800000);   // N*64 bf16
    unsigned short* x2b = (unsigned short*)(ws + 9600000);   // N*64 bf16
    // zeroed block: scal + bcnt
    float* scal  = ws + 14400000;                 // 16
    int*   bcnt  = (int*)(scal + 16);             // NBKT (pad 160)
    // end zeroed block
    int*   start = bcnt + 160;                    // NSCAN_PAD
    int2*  tmp   = (int2*)(start + NSCAN_PAD);    // NBKT*BKT_CAP int2 (9.6MB), 8B-aligned
    float2* wc   = (float2*)tmp;                  // ALIAS: E float2 (8MB) — tmp dead after scatter2
    int2*  rec   = tmp + (size_t)NBKT * BKT_CAP;  // E int2 (8MB)
    int2*  range = rec + E_TOT;                   // N_TOT int2
    float* dis   = (float*)(range + N_TOT);       // N_TOT
    float* a_nb  = dis + N_TOT;                   // N_TOT
    float* a_self= a_nb + N_TOT;                  // N_TOT
    unsigned short* wpk =
        (unsigned short*)(((uintptr_t)(a_self + N_TOT) + 15) & ~(uintptr_t)15);  // 32KB

    hipMemsetAsync(scal, 0, (16 + 160) * sizeof(float), stream);

    const int nNodeBlocks = (N_TOT + 255) / 256;   // 586
    const int nMfmaBlocks = (N_TOT / 16 + 3) / 4;  // 2344

    // ---- fused: features -> bf16 + weights -> packed bf16 frags ----
    prep_kernel<<<1032, 256, 0, stream>>>((const float4*)features, (ushort4*)fb, N_TOT * 16,
                                          W_nb0, W_self0, W_nb1, W_self1, wpk);

    // ---- CSR build: bin (8B packed recs) -> per-bucket scan + counting-sort ----
    bin_kernel<<<NBIN_BLOCKS, 256, 0, stream>>>(row, col, u0, u1, bcnt, tmp, E_TOT);
    scatter2_kernel<<<NBKT, 256, 0, stream>>>(tmp, bcnt, start, rec);

    // ---- Layer 0 ----
    node_scalars_mfma_kernel<<<nMfmaBlocks, 256, 0, stream>>>(fb, wpk, b_nb0, b_self0, W_att0,
                                                              a_nb, a_self, N_TOT);
    edge_pass_a_kernel<<<nNodeBlocks, 256, 0, stream>>>(rec, start, 0, a_nb, a_self,
                                                        b_att0, temp, wc, range, dis,
                                                        &scal[2], N_TOT);
    edge_gather_kernel<<<2048, 256, 0, stream>>>(wc, range, dis, fb, x1b, N_TOT);

    // ---- Layer 1 ----
    node_scalars_mfma_kernel<<<nMfmaBlocks, 256, 0, stream>>>(x1b, wpk + 8192, b_nb1, b_self1,
                                                              W_att1, a_nb, a_self, N_TOT);
    edge_pass_a_kernel<<<nNodeBlocks, 256, 0, stream>>>(rec, start, 1, a_nb, a_self,
                                                        b_att1, temp, wc, range, dis,
                                                        &scal[3], N_TOT);
    edge_gather_kernel<<<2048, 256, 0, stream>>>(wc, range, dis, x1b, x2b, N_TOT);

    // ---- Losses (bpr + reg fused) ----
    loss_kernel<<<65, 256, 0, stream>>>(features, x1b, x2b, users, items, negs,
                                        W_nb0, b_nb0, W_self0, b_self0, W_att0, b_att0,
                                        W_nb1, b_nb1, W_self1, b_self1, W_att1, b_att1,
                                        scal, B_TOT);
    finalize_kernel<<<1, 1, 0, stream>>>(scal, out);
}

// Round 16
// 173.319 us; speedup vs baseline: 2.2667x; 1.0655x over previous
//
#include <hip/hip_runtime.h>
#include <hip/hip_bf16.h>

#define N_TOT   150000
#define N_USER  100000
#define E_TOT   1000000
#define B_TOT   4096
#define D_DIM   64

#define NSCAN_PAD   150016          // N_TOT+1 rounded up to multiple of 8
#define BKT_SHIFT   10
#define BKT_ROWS    (1 << BKT_SHIFT)                 // 1024 rows per bucket
#define NBKT        ((N_TOT + BKT_ROWS - 1) / BKT_ROWS)   // 147
#define BKT_CAP     8192
#define BIN_CHUNK   4096
#define NBIN_BLOCKS ((E_TOT + BIN_CHUNK - 1) / BIN_CHUNK) // 245
#define COL_MASK    0x3FFFF         // 18 bits (N_TOT < 262144)

#define PREP_BLKS   1032            // 1024 tobf16 + 8 wpack
#define NS_BLKS     2344            // node_scalars: 9375 waves / 4 per block

typedef short short8v  __attribute__((ext_vector_type(8)));
typedef float float4v  __attribute__((ext_vector_type(4)));

// ---- bf16 / f16 helpers (bit ops; accumulation always f32) ----
__device__ __forceinline__ float b2f(unsigned int lo16)
{
    union { unsigned int u; float f; } c; c.u = lo16 << 16; return c.f;
}
__device__ __forceinline__ unsigned short f2b(float f)
{
    union { float f; unsigned int u; } c; c.f = f;
    unsigned int u = c.u + 0x7FFFu + ((c.u >> 16) & 1u);   // RNE
    return (unsigned short)(u >> 16);
}
__device__ __forceinline__ unsigned short f2h(float f)
{
    union { _Float16 h; unsigned short u; } c; c.h = (_Float16)f; return c.u;
}
__device__ __forceinline__ float h2f(unsigned short u)
{
    union { unsigned short u; _Float16 h; } c; c.u = u; return (float)c.h;
}
__device__ __forceinline__ int   f_as_i(float f) { union { float f; int i; } c; c.f = f; return c.i; }
__device__ __forceinline__ float i_as_f(int i)   { union { int i; float f; } c; c.i = i; return c.f; }

// ---------------------------------------------------------------------------
// Shared device bodies
// ---------------------------------------------------------------------------
__device__ __forceinline__
void node_scalars_body(int wid, const unsigned short* __restrict__ xb,
                       const unsigned short* __restrict__ wpack,
                       const float* __restrict__ bn, const float* __restrict__ bs,
                       const float* __restrict__ Wa,
                       float* __restrict__ a_nb, float* __restrict__ a_self,
                       int nNodes, int lane)
{
    const int nodeBase = wid * 16;
    if (nodeBase >= nNodes) return;

    short8v bfrag[2][2][4];
    #pragma unroll
    for (int m = 0; m < 2; ++m)
        #pragma unroll
        for (int kb = 0; kb < 2; ++kb)
            #pragma unroll
            for (int nt = 0; nt < 4; ++nt)
                bfrag[m][kb][nt] =
                    *(const short8v*)(wpack + (size_t)((((m * 2 + kb) * 4 + nt) * 64 + lane)) * 8);

    const size_t rowOff = (size_t)(nodeBase + (lane & 15)) * 64 + ((lane >> 4) << 3);
    short8v a0 = *(const short8v*)(xb + rowOff);
    short8v a1 = *(const short8v*)(xb + rowOff + 32);

    float4v acc[2][4];
    #pragma unroll
    for (int m = 0; m < 2; ++m)
        #pragma unroll
        for (int nt = 0; nt < 4; ++nt) {
            float4v z = {0.f, 0.f, 0.f, 0.f};
            z = __builtin_amdgcn_mfma_f32_16x16x32_bf16(a0, bfrag[m][0][nt], z, 0, 0, 0);
            z = __builtin_amdgcn_mfma_f32_16x16x32_bf16(a1, bfrag[m][1][nt], z, 0, 0, 0);
            acc[m][nt] = z;
        }

    const int j = lane & 15;
    float pn[4] = {0.f, 0.f, 0.f, 0.f};
    float ps[4] = {0.f, 0.f, 0.f, 0.f};
    #pragma unroll
    for (int nt = 0; nt < 4; ++nt) {
        float bnv = bn[nt * 16 + j], bsv = bs[nt * 16 + j];
        float wan = Wa[nt * 16 + j], was = Wa[64 + nt * 16 + j];
        #pragma unroll
        for (int r = 0; r < 4; ++r) {
            pn[r] = fmaf(fmaxf(acc[0][nt][r] + bnv, 0.f), wan, pn[r]);
            ps[r] = fmaf(fmaxf(acc[1][nt][r] + bsv, 0.f), was, ps[r]);
        }
    }
    #pragma unroll
    for (int off = 1; off < 16; off <<= 1) {
        #pragma unroll
        for (int r = 0; r < 4; ++r) {
            pn[r] += __shfl_xor(pn[r], off);
            ps[r] += __shfl_xor(ps[r], off);
        }
    }
    if (j == 0) {
        const int g = lane >> 4;
        #pragma unroll
        for (int r = 0; r < 4; ++r) {
            int node = nodeBase + g * 4 + r;
            a_nb[node]   = pn[r];
            a_self[node] = ps[r];
        }
    }
}

// ---------------------------------------------------------------------------
// F1: fused prep + bin.
//   blocks [0,1024)            : features f32 -> bf16
//   blocks [1024,1032)         : pack weights into MFMA B-frag order
//   blocks [1032, 1032+245)    : bin edges, 8B packed recs + f16 noise
// ---------------------------------------------------------------------------
__global__ __launch_bounds__(256)
void prep_bin_kernel(const float4* __restrict__ in, ushort4* __restrict__ outb, int n4,
                     const float* __restrict__ Wn0, const float* __restrict__ Ws0,
                     const float* __restrict__ Wn1, const float* __restrict__ Ws1,
                     unsigned short* __restrict__ wpk,
                     const int* __restrict__ row, const int* __restrict__ col,
                     const float* __restrict__ u0, const float* __restrict__ u1,
                     int* __restrict__ bcnt, int2* __restrict__ tmp, int nE)
{
    __shared__ int cnt[NBKT];
    __shared__ int base[NBKT];

    if (blockIdx.x < 1024) {
        for (int i = blockIdx.x * 256 + threadIdx.x; i < n4; i += 1024 * 256) {
            float4 v = in[i];
            ushort4 o;
            o.x = f2b(v.x); o.y = f2b(v.y); o.z = f2b(v.z); o.w = f2b(v.w);
            outb[i] = o;
        }
        return;
    }
    if (blockIdx.x < PREP_BLKS) {
        int f = (blockIdx.x - 1024) * 256 + threadIdx.x;   // [0, 2048)
        if (f >= 2048) return;
        const float* W[4] = {Wn0, Ws0, Wn1, Ws1};
        int m   = f >> 9;
        int rem = f & 511;
        int kb  = rem >> 8;
        int nt  = (rem >> 6) & 3;
        int l   = rem & 63;
        const float* Wm = W[m];
        int kbase = 32 * kb + ((l >> 4) << 3);
        int n     = 16 * nt + (l & 15);
        unsigned short o[8];
        #pragma unroll
        for (int jj = 0; jj < 8; ++jj) o[jj] = f2b(Wm[(kbase + jj) * 64 + n]);
        ushort4* dst = (ushort4*)(wpk + (size_t)f * 8);
        dst[0] = make_ushort4(o[0], o[1], o[2], o[3]);
        dst[1] = make_ushort4(o[4], o[5], o[6], o[7]);
        return;
    }

    // ---- bin ----
    const int bb = blockIdx.x - PREP_BLKS;    // [0, NBIN_BLOCKS)
    for (int i = threadIdx.x; i < NBKT; i += 256) cnt[i] = 0;
    __syncthreads();

    const int e0 = bb * BIN_CHUNK + threadIdx.x;
    int r[16], w0[16], pk[16];
    #pragma unroll
    for (int k = 0; k < 16; ++k) {
        int e = e0 + k * 256;
        r[k] = (e < nE) ? row[e] : -1;
        if (r[k] >= 0) {
            int rl = r[k] & (BKT_ROWS - 1);
            w0[k] = (rl << 18) | col[e];
            float ua = u0[e], ub = u1[e];
            float n0 = __logf(__fdividef(ua, 1.0f - ua));
            float n1 = __logf(__fdividef(ub, 1.0f - ub));
            pk[k] = (int)(((unsigned int)f2h(n1) << 16) | (unsigned int)f2h(n0));
            atomicAdd(&cnt[r[k] >> BKT_SHIFT], 1);
        }
    }
    __syncthreads();

    for (int i = threadIdx.x; i < NBKT; i += 256) {
        int cc = cnt[i];
        base[i] = cc ? atomicAdd(&bcnt[i], cc) : 0;
        cnt[i] = 0;
    }
    __syncthreads();

    #pragma unroll
    for (int k = 0; k < 16; ++k) {
        if (r[k] >= 0) {
            int b   = r[k] >> BKT_SHIFT;
            int loc = atomicAdd(&cnt[b], 1);
            tmp[(size_t)b * BKT_CAP + base[b] + loc] = make_int2(w0[k], pk[k]);
        }
    }
}

// ---------------------------------------------------------------------------
// F2: fused scatter2 + node_scalars(layer0).
//   blocks [0,147)             : per-bucket scan + counting-sort -> start/rec
//   blocks [147, 147+NS_BLKS)  : node scalars (MFMA) on fb
// ---------------------------------------------------------------------------
__global__ __launch_bounds__(256)
void scatter_ns0_kernel(const int2* __restrict__ tmp, const int* __restrict__ bcnt,
                        int* __restrict__ start, int2* __restrict__ rec,
                        const unsigned short* __restrict__ fb,
                        const unsigned short* __restrict__ wpk0,
                        const float* __restrict__ bn, const float* __restrict__ bs,
                        const float* __restrict__ Wa,
                        float* __restrict__ a_nb, float* __restrict__ a_self)
{
    __shared__ int pref[BKT_ROWS];
    __shared__ int wsum[256];
    __shared__ int sc[256];

    if (blockIdx.x >= NBKT) {
        const int lane = threadIdx.x & 63;
        const int wid  = ((blockIdx.x - NBKT) * 256 + threadIdx.x) >> 6;
        node_scalars_body(wid, fb, wpk0, bn, bs, Wa, a_nb, a_self, N_TOT, lane);
        return;
    }

    const int b     = blockIdx.x;
    const int rlo   = b << BKT_SHIFT;
    const int nrows = min(BKT_ROWS, N_TOT - rlo);
    const int t     = threadIdx.x;

    // bucket-prefix scan (147 entries) in-block
    int v = (t < NBKT) ? bcnt[t] : 0;
    sc[t] = v;
    __syncthreads();
    for (int off = 1; off < 256; off <<= 1) {
        int x = sc[t];
        if (t >= off) x += sc[t - off];
        __syncthreads();
        sc[t] = x;
        __syncthreads();
    }
    const int cntb  = bcnt[b];
    const int baseb = (b == 0) ? 0 : sc[b - 1];
    if (b == 0 && t == 0) start[N_TOT] = E_TOT;

    const int2* __restrict__ bkt = tmp + (size_t)b * BKT_CAP;

    for (int i = t; i < BKT_ROWS; i += 256) pref[i] = 0;
    __syncthreads();

    for (int j = t; j < cntb; j += 256)
        atomicAdd(&pref[(unsigned int)bkt[j].x >> 18], 1);
    __syncthreads();

    const int base4 = t * 4;
    int v0 = pref[base4], v1 = pref[base4 + 1], v2 = pref[base4 + 2], v3 = pref[base4 + 3];
    int s = v0 + v1 + v2 + v3;
    wsum[t] = s;
    __syncthreads();
    for (int off = 1; off < 256; off <<= 1) {
        int x = wsum[t];
        if (t >= off) x += wsum[t - off];
        __syncthreads();
        wsum[t] = x;
        __syncthreads();
    }
    const int pre = wsum[t] - s;
    const int p0 = pre, p1 = pre + v0, p2 = pre + v0 + v1, p3 = pre + v0 + v1 + v2;

    if (base4     < nrows) start[rlo + base4]     = baseb + p0;
    if (base4 + 1 < nrows) start[rlo + base4 + 1] = baseb + p1;
    if (base4 + 2 < nrows) start[rlo + base4 + 2] = baseb + p2;
    if (base4 + 3 < nrows) start[rlo + base4 + 3] = baseb + p3;

    pref[base4] = p0; pref[base4 + 1] = p1; pref[base4 + 2] = p2; pref[base4 + 3] = p3;
    __syncthreads();

    for (int j = t; j < cntb; j += 256) {
        int2 q  = bkt[j];
        int loc = atomicAdd(&pref[(unsigned int)q.x >> 18], 1);
        rec[baseb + loc] = make_int2(q.x & COL_MASK, q.y);
    }
}

// ---------------------------------------------------------------------------
// Node scalars standalone (layer 1)
// ---------------------------------------------------------------------------
__global__ __launch_bounds__(256)
void node_scalars_mfma_kernel(const unsigned short* __restrict__ xb,
                              const unsigned short* __restrict__ wpack,
                              const float* __restrict__ bn, const float* __restrict__ bs,
                              const float* __restrict__ Wa,
                              float* __restrict__ a_nb, float* __restrict__ a_self,
                              int nNodes)
{
    const int lane = threadIdx.x & 63;
    const int wid  = (blockIdx.x * blockDim.x + threadIdx.x) >> 6;
    node_scalars_body(wid, xb, wpack, bn, bs, Wa, a_nb, a_self, nNodes, lane);
}

// ---------------------------------------------------------------------------
// Edge pass A, node-parallel: noise precomputed (f16), __expf sigmoids.
// Writes COMPACTED {m, col} records (only m>0) + fused int2 range + dis.
// ---------------------------------------------------------------------------
__global__ __launch_bounds__(256)
void edge_pass_a_kernel(const int2* __restrict__ rec, const int* __restrict__ start,
                        const int uSel,
                        const float* __restrict__ a_nb, const float* __restrict__ a_self,
                        const float* __restrict__ ba_p, const float* __restrict__ temp_p,
                        float2* __restrict__ wc, int2* __restrict__ range,
                        float* __restrict__ dis,
                        float* __restrict__ l0_accum, int nNodes)
{
    const float ba   = ba_p[0];
    const float t    = temp_p[0];
    const float invt = 1.0f / t;
    const float lt   = logf(0.45f / 1.05f);   // log(-GAMMA/ZETA)
    const float shift = t * lt;

    const int r = blockIdx.x * 256 + threadIdx.x;
    float l0local = 0.0f;

    if (r < nNodes) {
        const int js = start[r], je = start[r + 1];
        const float la_base = a_nb[r] + ba;
        float rs = 0.0f;
        int k = js;
        for (int j = js; j < je; ++j) {
            int2 q = rec[j];                     // {col, packed_noise}
            int c = q.x;
            float la = la_base + a_self[c];
            unsigned int pk = (unsigned int)q.y;
            float noise = h2f((unsigned short)(uSel ? (pk >> 16) : (pk & 0xFFFFu)));
            float gate  = 1.0f / (1.0f + __expf(-(noise + la) * invt));
            float m = fminf(fmaxf(gate * 1.5f - 0.45f, 0.0f), 1.0f);
            rs += m;
            l0local += 1.0f / (1.0f + __expf(-(la - shift)));
            if (m > 0.0f) { wc[k] = make_float2(m, i_as_f(c)); ++k; }
        }
        range[r] = make_int2(js, k);
        dis[r] = fminf(1.0f / sqrtf(rs + 1e-6f), 10.0f);
    }

    __shared__ float red[256];
    red[threadIdx.x] = l0local;
    __syncthreads();
    for (int s = 128; s > 0; s >>= 1) {
        if (threadIdx.x < s) red[threadIdx.x] += red[threadIdx.x + s];
        __syncthreads();
    }
    if (threadIdx.x == 0) unsafeAtomicAdd(l0_accum, red[0]);
}

// ---------------------------------------------------------------------------
// Edge gather v6: EIGHTH-WAVE per node, ushort8 (8 dims, 16B) per lane.
// ---------------------------------------------------------------------------
__global__ void edge_gather_kernel(const float2* __restrict__ wc, const int2* __restrict__ range,
                                   const float* __restrict__ dis,
                                   const unsigned short* __restrict__ xb,
                                   unsigned short* __restrict__ xnb, int nNodes)
{
    const int lane = threadIdx.x & 63;
    const int oct  = lane >> 3;        // 0..7
    const int sub  = lane & 7;         // dims sub*8 .. sub*8+7
    const int wave   = (blockIdx.x * blockDim.x + threadIdx.x) >> 6;
    const int nWaves = (gridDim.x * blockDim.x) >> 6;
    const int nOcts  = (nNodes + 7) >> 3;

    for (int p = wave; p < nOcts; p += nWaves) {
        const int r = 8 * p + oct;
        const bool valid = r < nNodes;
        const int rr = valid ? r : nNodes - 1;
        int2 rg  = range[rr];
        float dr = dis[rr];
        int j  = rg.x;
        int je = valid ? rg.y : rg.x;
        float a0 = 0.f, a1 = 0.f, a2 = 0.f, a3 = 0.f;
        float a4 = 0.f, a5 = 0.f, a6 = 0.f, a7 = 0.f;
        for (; j + 4 <= je; j += 4) {
            float2 w0 = wc[j], w1 = wc[j + 1], w2 = wc[j + 2], w3 = wc[j + 3];
            int c0 = f_as_i(w0.y), c1 = f_as_i(w1.y), c2 = f_as_i(w2.y), c3 = f_as_i(w3.y);
            float s0 = w0.x * dis[c0], s1 = w1.x * dis[c1];
            float s2 = w2.x * dis[c2], s3 = w3.x * dis[c3];
            uint4 q0 = *(const uint4*)(xb + (size_t)c0 * 64 + sub * 8);
            uint4 q1 = *(const uint4*)(xb + (size_t)c1 * 64 + sub * 8);
            uint4 q2 = *(const uint4*)(xb + (size_t)c2 * 64 + sub * 8);
            uint4 q3 = *(const uint4*)(xb + (size_t)c3 * 64 + sub * 8);
            a0 = fmaf(s0, b2f(q0.x & 0xFFFFu), a0); a1 = fmaf(s0, b2f(q0.x >> 16), a1);
            a2 = fmaf(s0, b2f(q0.y & 0xFFFFu), a2); a3 = fmaf(s0, b2f(q0.y >> 16), a3);
            a4 = fmaf(s0, b2f(q0.z & 0xFFFFu), a4); a5 = fmaf(s0, b2f(q0.z >> 16), a5);
            a6 = fmaf(s0, b2f(q0.w & 0xFFFFu), a6); a7 = fmaf(s0, b2f(q0.w >> 16), a7);
            a0 = fmaf(s1, b2f(q1.x & 0xFFFFu), a0); a1 = fmaf(s1, b2f(q1.x >> 16), a1);
            a2 = fmaf(s1, b2f(q1.y & 0xFFFFu), a2); a3 = fmaf(s1, b2f(q1.y >> 16), a3);
            a4 = fmaf(s1, b2f(q1.z & 0xFFFFu), a4); a5 = fmaf(s1, b2f(q1.z >> 16), a5);
            a6 = fmaf(s1, b2f(q1.w & 0xFFFFu), a6); a7 = fmaf(s1, b2f(q1.w >> 16), a7);
            a0 = fmaf(s2, b2f(q2.x & 0xFFFFu), a0); a1 = fmaf(s2, b2f(q2.x >> 16), a1);
            a2 = fmaf(s2, b2f(q2.y & 0xFFFFu), a2); a3 = fmaf(s2, b2f(q2.y >> 16), a3);
            a4 = fmaf(s2, b2f(q2.z & 0xFFFFu), a4); a5 = fmaf(s2, b2f(q2.z >> 16), a5);
            a6 = fmaf(s2, b2f(q2.w & 0xFFFFu), a6); a7 = fmaf(s2, b2f(q2.w >> 16), a7);
            a0 = fmaf(s3, b2f(q3.x & 0xFFFFu), a0); a1 = fmaf(s3, b2f(q3.x >> 16), a1);
            a2 = fmaf(s3, b2f(q3.y & 0xFFFFu), a2); a3 = fmaf(s3, b2f(q3.y >> 16), a3);
            a4 = fmaf(s3, b2f(q3.z & 0xFFFFu), a4); a5 = fmaf(s3, b2f(q3.z >> 16), a5);
            a6 = fmaf(s3, b2f(q3.w & 0xFFFFu), a6); a7 = fmaf(s3, b2f(q3.w >> 16), a7);
        }
        for (; j < je; ++j) {
            float2 w0 = wc[j];
            int c0 = f_as_i(w0.y);
            float s0 = w0.x * dis[c0];
            uint4 q0 = *(const uint4*)(xb + (size_t)c0 * 64 + sub * 8);
            a0 = fmaf(s0, b2f(q0.x & 0xFFFFu), a0); a1 = fmaf(s0, b2f(q0.x >> 16), a1);
            a2 = fmaf(s0, b2f(q0.y & 0xFFFFu), a2); a3 = fmaf(s0, b2f(q0.y >> 16), a3);
            a4 = fmaf(s0, b2f(q0.z & 0xFFFFu), a4); a5 = fmaf(s0, b2f(q0.z >> 16), a5);
            a6 = fmaf(s0, b2f(q0.w & 0xFFFFu), a6); a7 = fmaf(s0, b2f(q0.w >> 16), a7);
        }
        if (valid) {
            uint4 o;
            o.x = ((unsigned int)f2b(a1 * dr) << 16) | (unsigned int)f2b(a0 * dr);
            o.y = ((unsigned int)f2b(a3 * dr) << 16) | (unsigned int)f2b(a2 * dr);
            o.z = ((unsigned int)f2b(a5 * dr) << 16) | (unsigned int)f2b(a4 * dr);
            o.w = ((unsigned int)f2b(a7 * dr) << 16) | (unsigned int)f2b(a6 * dr);
            *(uint4*)(xnb + (size_t)r * 64 + sub * 8) = o;
        }
    }
}

// ---------------------------------------------------------------------------
// Fused losses: blocks 0..63 = BPR partial sums; block 64 = L2 reg.
// ---------------------------------------------------------------------------
__global__ void loss_kernel(const float* __restrict__ f,
                            const unsigned short* __restrict__ x1b,
                            const unsigned short* __restrict__ x2b,
                            const int* __restrict__ users, const int* __restrict__ items,
                            const int* __restrict__ negs,
                            const float* __restrict__ w0, const float* __restrict__ b0,
                            const float* __restrict__ w1, const float* __restrict__ b1,
                            const float* __restrict__ wa0, const float* __restrict__ ba0,
                            const float* __restrict__ w2, const float* __restrict__ b2,
                            const float* __restrict__ w3, const float* __restrict__ b3,
                            const float* __restrict__ wa1, const float* __restrict__ ba1,
                            float* __restrict__ scal, int B)
{
    const int t = threadIdx.x;
    if (blockIdx.x == 64) {
        float s = 0.0f;
        for (int i = t; i < 4096; i += 256)
            s += w0[i]*w0[i] + w1[i]*w1[i] + w2[i]*w2[i] + w3[i]*w3[i];
        for (int i = t; i < 64; i += 256)
            s += b0[i]*b0[i] + b1[i]*b1[i] + b2[i]*b2[i] + b3[i]*b3[i];
        for (int i = t; i < 128; i += 256)
            s += wa0[i]*wa0[i] + wa1[i]*wa1[i];
        if (t == 0) s += ba0[0]*ba0[0] + ba1[0]*ba1[0];

        __shared__ float red[256];
        red[t] = s;
        __syncthreads();
        for (int st = 128; st > 0; st >>= 1) {
            if (t < st) red[t] += red[t + st];
            __syncthreads();
        }
        if (t == 0) scal[1] = red[0];
        return;
    }

    const int lane   = t & 63;
    const int wave   = (blockIdx.x * 256 + t) >> 6;
    const int nWaves = (64 * 256) >> 6;

    float local = 0.0f;
    for (int b = wave; b < B; b += nWaves) {
        size_t ui = (size_t)users[b] * 64 + lane;
        size_t pi = (size_t)(N_USER + items[b]) * 64 + lane;
        size_t ni = (size_t)(N_USER + negs[b]) * 64 + lane;
        float a = f[ui] + b2f(x1b[ui]) + b2f(x2b[ui]);
        float p = f[pi] + b2f(x1b[pi]) + b2f(x2b[pi]);
        float n = f[ni] + b2f(x1b[ni]) + b2f(x2b[ni]);
        float ps = a * p, ns = a * n;
        #pragma unroll
        for (int off = 32; off; off >>= 1) {
            ps += __shfl_xor(ps, off);
            ns += __shfl_xor(ns, off);
        }
        if (lane == 0) {
            float s = 1.0f / (1.0f + expf(-(ps - ns)));
            local += -logf(s + 1e-5f);
        }
    }
    if (lane == 0) unsafeAtomicAdd(&scal[0], local);
}

__global__ void finalize_kernel(const float* __restrict__ scal, float* __restrict__ out)
{
    float bpr = scal[0] / (float)B_TOT;
    float reg = scal[1] * 1e-4f;
    float l0  = (scal[2] + scal[3]) * (1e-4f / (float)E_TOT);
    out[0] = bpr + reg + l0;
}

extern "C" void kernel_launch(void* const* d_in, const int* in_sizes, int n_in,
                              void* d_out, int out_size, void* d_ws, size_t ws_size,
                              hipStream_t stream)
{
    const float* features = (const float*)d_in[0];
    const int*   row      = (const int*)d_in[1];
    const int*   col      = (const int*)d_in[2];
    const int*   users    = (const int*)d_in[3];
    const int*   items    = (const int*)d_in[4];
    const int*   negs     = (const int*)d_in[5];
    const float* u0       = (const float*)d_in[6];
    const float* u1       = (const float*)d_in[7];
    const float* temp     = (const float*)d_in[8];
    const float* W_nb0    = (const float*)d_in[9];
    const float* b_nb0    = (const float*)d_in[10];
    const float* W_self0  = (const float*)d_in[11];
    const float* b_self0  = (const float*)d_in[12];
    const float* W_att0   = (const float*)d_in[13];
    const float* b_att0   = (const float*)d_in[14];
    const float* W_nb1    = (const float*)d_in[15];
    const float* b_nb1    = (const float*)d_in[16];
    const float* W_self1  = (const float*)d_in[17];
    const float* b_self1  = (const float*)d_in[18];
    const float* W_att1   = (const float*)d_in[19];
    const float* b_att1   = (const float*)d_in[20];
    float* out = (float*)d_out;

    // ---- Workspace layout (4B element offsets), ~80 MB total ----
    float* ws = (float*)d_ws;
    unsigned short* fb  = (unsigned short*)ws;               // N*64 bf16
    unsigned short* x1b = (unsigned short*)(ws + 4800000);   // N*64 bf16
    unsigned short* x2b = (unsigned short*)(ws + 9600000);   // N*64 bf16
    // zeroed block: scal + bcnt
    float* scal  = ws + 14400000;                 // 16
    int*   bcnt  = (int*)(scal + 16);             // NBKT (pad 160)
    // end zeroed block
    int*   start = bcnt + 160;                    // NSCAN_PAD
    int2*  tmp   = (int2*)(start + NSCAN_PAD);    // NBKT*BKT_CAP int2 (9.6MB), 8B-aligned
    float2* wc   = (float2*)tmp;                  // ALIAS: E float2 (8MB) — tmp dead after scatter
    int2*  rec   = tmp + (size_t)NBKT * BKT_CAP;  // E int2 (8MB)
    int2*  range = rec + E_TOT;                   // N_TOT int2
    float* dis   = (float*)(range + N_TOT);       // N_TOT
    float* a_nb  = dis + N_TOT;                   // N_TOT
    float* a_self= a_nb + N_TOT;                  // N_TOT
    unsigned short* wpk =
        (unsigned short*)(((uintptr_t)(a_self + N_TOT) + 15) & ~(uintptr_t)15);  // 32KB

    hipMemsetAsync(scal, 0, (16 + 160) * sizeof(float), stream);

    const int nNodeBlocks = (N_TOT + 255) / 256;   // 586

    // ---- F1: fused prep(tobf16+wpack) + bin ----
    prep_bin_kernel<<<PREP_BLKS + NBIN_BLOCKS, 256, 0, stream>>>(
        (const float4*)features, (ushort4*)fb, N_TOT * 16,
        W_nb0, W_self0, W_nb1, W_self1, wpk,
        row, col, u0, u1, bcnt, tmp, E_TOT);

    // ---- F2: fused scatter2 + node_scalars(layer0) ----
    scatter_ns0_kernel<<<NBKT + NS_BLKS, 256, 0, stream>>>(
        tmp, bcnt, start, rec, fb, wpk, b_nb0, b_self0, W_att0, a_nb, a_self);

    // ---- Layer 0 edge passes ----
    edge_pass_a_kernel<<<nNodeBlocks, 256, 0, stream>>>(rec, start, 0, a_nb, a_self,
                                                        b_att0, temp, wc, range, dis,
                                                        &scal[2], N_TOT);
    edge_gather_kernel<<<2048, 256, 0, stream>>>(wc, range, dis, fb, x1b, N_TOT);

    // ---- Layer 1 ----
    node_scalars_mfma_kernel<<<NS_BLKS, 256, 0, stream>>>(x1b, wpk + 8192, b_nb1, b_self1,
                                                          W_att1, a_nb, a_self, N_TOT);
    edge_pass_a_kernel<<<nNodeBlocks, 256, 0, stream>>>(rec, start, 1, a_nb, a_self,
                                                        b_att1, temp, wc, range, dis,
                                                        &scal[3], N_TOT);
    edge_gather_kernel<<<2048, 256, 0, stream>>>(wc, range, dis, x1b, x2b, N_TOT);

    // ---- Losses (bpr + reg fused) ----
    loss_kernel<<<65, 256, 0, stream>>>(features, x1b, x2b, users, items, negs,
                                        W_nb0, b_nb0, W_self0, b_self0, W_att0, b_att0,
                                        W_nb1, b_nb1, W_self1, b_self1, W_att1, b_att1,
                                        scal, B_TOT);
    finalize_kernel<<<1, 1, 0, stream>>>(scal, out);
}